// Round 1
// 555.707 us; speedup vs baseline: 1.0391x; 1.0391x over previous
//
#include <hip/hip_runtime.h>
#include <math.h>

// Shapes: B=8, C=256, H=W=64, HQ=WQ=32, L=1024, NH=8, hd=8, dv=32
//
// Workspace (float units):
//   Wpf9 bf16[9][256][512] @ 0        (589824 f)
//   Wpo9 bf16[9][256][256] @ 589824   (294912 f)
//   region2 @ 884736 (POS scratch, later aliased by CHA scratch)
//   fused_pad bf16[8][66*66][512] @ 16613376 (8921088 f)
//   Wqkv_p bf16[384][1024] @ 25534464 (196608 f)

typedef __attribute__((ext_vector_type(8))) short bf16x8;
typedef __attribute__((ext_vector_type(4))) float f32x4;

__device__ __forceinline__ ushort f2bf(float f) {
  union { float f; unsigned u; } v; v.f = f;
  unsigned r = (v.u + 0x7FFFu + ((v.u >> 16) & 1u)) >> 16;
  return (ushort)r;
}

// -------- weight pre-pack: W[oc][cin][3][3] fp32 -> [t][oc][cin] bf16 -------
template <int CIN>
__global__ __launch_bounds__(256) void k_prepack9(
    const float* __restrict__ W, ushort* __restrict__ out)
{
  const int i = blockIdx.x * 256 + threadIdx.x;   // over 9*256*CIN
  const int t = i / (256 * CIN);
  const int r = i - t * (256 * CIN);
  const int oc = r / CIN;
  const int c = r - oc * CIN;
  out[i] = f2bf(W[((size_t)oc * CIN + c) * 9 + t]);
}

// -------- concat Wq/Wk/Wv -> bf16 [384][1024] -------------------------------
__global__ __launch_bounds__(256) void k_cast_wqkv(
    const float* __restrict__ Wq, const float* __restrict__ Wk,
    const float* __restrict__ Wv, ushort* __restrict__ out)
{
  const int i = blockIdx.x * 256 + threadIdx.x;   // over 384*1024
  const int o = i >> 10, k = i & 1023;
  float v;
  if (o < 64)       v = Wq[(size_t)o * 1024 + k];
  else if (o < 128) v = Wk[(size_t)(o - 64) * 1024 + k];
  else              v = Wv[(size_t)(o - 128) * 1024 + k];
  out[i] = f2bf(v);
}

// -------- patchify x (2x2 stride-2 im2col) -> bf16 Ap[b][l][1024] -----------
__global__ __launch_bounds__(256) void k_pack_pos(
    const float* __restrict__ x, ushort* __restrict__ Ap)
{
  const int t = blockIdx.x * 256 + threadIdx.x;   // 524288 threads
  const int j4 = t & 7;          // group of 4 output cols
  const int i  = (t >> 3) & 31;  // output row
  const int c  = (t >> 8) & 255;
  const int b  = t >> 16;
  const float* xb = x + (((size_t)b * 256 + c) << 12) + (2 * i) * 64 + 8 * j4;
  union { float4 v[2]; float f[8]; } r0, r1;
  r0.v[0] = *(const float4*)(xb);
  r0.v[1] = *(const float4*)(xb + 4);
  r1.v[0] = *(const float4*)(xb + 64);
  r1.v[1] = *(const float4*)(xb + 68);
  #pragma unroll
  for (int jj = 0; jj < 4; ++jj) {
    const int l = i * 32 + j4 * 4 + jj;
    union { ushort u[4]; uint2 d; } pk;
    pk.u[0] = f2bf(r0.f[2 * jj]);
    pk.u[1] = f2bf(r0.f[2 * jj + 1]);
    pk.u[2] = f2bf(r1.f[2 * jj]);
    pk.u[3] = f2bf(r1.f[2 * jj + 1]);
    *(uint2*)(Ap + ((((size_t)b << 10) + l) << 10) + c * 4) = pk.d;
  }
}

// ---- P1: POS q/k/v projection as bf16 MFMA GEMM [384x1024]x[1024xL] --------
__global__ __launch_bounds__(256) void k_pos_qkv_mfma(
    const ushort* __restrict__ Ap, const ushort* __restrict__ Wqkv,
    const float* __restrict__ bq, const float* __restrict__ bk,
    const float* __restrict__ bv,
    ushort* __restrict__ Qb, ushort* __restrict__ Kb, ushort* __restrict__ Vtb)
{
  const int n0 = blockIdx.x * 128, oc0 = blockIdx.y * 128, b = blockIdx.z;
  const int tid = threadIdx.x, lane = tid & 63, w = tid >> 6;
  __shared__ ushort As[128][32], Bs[128][32];
  const ushort* Abw = Wqkv + (size_t)oc0 * 1024;
  const ushort* Bb  = Ap + (((size_t)b << 10) + n0) * 1024;
  const int wr = w >> 1, wc = w & 1;
  f32x4 acc[4][4];
  #pragma unroll
  for (int mi = 0; mi < 4; ++mi)
    #pragma unroll
    for (int ni = 0; ni < 4; ++ni) {
      f32x4 z = {0.f, 0.f, 0.f, 0.f};
      acc[mi][ni] = z;
    }
  for (int kc = 0; kc < 1024; kc += 32) {
    __syncthreads();
    #pragma unroll
    for (int q = 0; q < 2; ++q) {
      int idx = w * 128 + q * 64 + lane;
      int row = idx >> 2, seg = idx & 3;
      const ushort* srcA = Abw + (size_t)row * 1024 + kc + seg * 8;
      const ushort* srcB = Bb + (size_t)row * 1024 + kc + seg * 8;
      char* dstA = (char*)&As[0][0] + w * 2048 + q * 1024;
      char* dstB = (char*)&Bs[0][0] + w * 2048 + q * 1024;
      __builtin_amdgcn_global_load_lds(
          (const __attribute__((address_space(1))) unsigned*)srcA,
          (__attribute__((address_space(3))) unsigned*)dstA, 16, 0, 0);
      __builtin_amdgcn_global_load_lds(
          (const __attribute__((address_space(1))) unsigned*)srcB,
          (__attribute__((address_space(3))) unsigned*)dstB, 16, 0, 0);
    }
    __syncthreads();
    bf16x8 af[4], bfv[4];
    #pragma unroll
    for (int mi = 0; mi < 4; ++mi)
      af[mi] = *(const bf16x8*)&As[wr * 64 + mi * 16 + (lane & 15)][(lane >> 4) * 8];
    #pragma unroll
    for (int ni = 0; ni < 4; ++ni)
      bfv[ni] = *(const bf16x8*)&Bs[wc * 64 + ni * 16 + (lane & 15)][(lane >> 4) * 8];
    #pragma unroll
    for (int mi = 0; mi < 4; ++mi)
      #pragma unroll
      for (int ni = 0; ni < 4; ++ni)
        acc[mi][ni] = __builtin_amdgcn_mfma_f32_16x16x32_bf16(
            af[mi], bfv[ni], acc[mi][ni], 0, 0, 0);
  }
  // epilogue: scatter into flash layouts (Q scaled, bias added)
  #pragma unroll
  for (int mi = 0; mi < 4; ++mi) {
    const int oc = oc0 + wr * 64 + mi * 16 + (lane >> 4) * 4;  // mult of 4
    if (oc >= 384) continue;
    if (oc < 64) {
      const int hh = oc >> 3, e = oc & 7;
      float4 bb = *(const float4*)(bq + oc);
      #pragma unroll
      for (int ni = 0; ni < 4; ++ni) {
        const int l = n0 + wc * 64 + ni * 16 + (lane & 15);
        union { ushort u[4]; uint2 d; } pk;
        pk.u[0] = f2bf((acc[mi][ni][0] + bb.x) * 0.35355339059327373f);
        pk.u[1] = f2bf((acc[mi][ni][1] + bb.y) * 0.35355339059327373f);
        pk.u[2] = f2bf((acc[mi][ni][2] + bb.z) * 0.35355339059327373f);
        pk.u[3] = f2bf((acc[mi][ni][3] + bb.w) * 0.35355339059327373f);
        *(uint2*)(Qb + (((((size_t)b * 8 + hh) << 10) + l) << 5) + e) = pk.d;
      }
    } else if (oc < 128) {
      const int o2 = oc - 64, hh = o2 >> 3, e = o2 & 7;
      float4 bb = *(const float4*)(bk + o2);
      #pragma unroll
      for (int ni = 0; ni < 4; ++ni) {
        const int l = n0 + wc * 64 + ni * 16 + (lane & 15);
        union { ushort u[4]; uint2 d; } pk;
        pk.u[0] = f2bf(acc[mi][ni][0] + bb.x);
        pk.u[1] = f2bf(acc[mi][ni][1] + bb.y);
        pk.u[2] = f2bf(acc[mi][ni][2] + bb.z);
        pk.u[3] = f2bf(acc[mi][ni][3] + bb.w);
        *(uint2*)(Kb + (((((size_t)b * 8 + hh) << 10) + l) << 5) + e) = pk.d;
      }
    } else {
      const int o2 = oc - 128, hh = o2 >> 5, dd = o2 & 31;
      float4 bb = *(const float4*)(bv + o2);
      #pragma unroll
      for (int ni = 0; ni < 4; ++ni) {
        const int l = n0 + wc * 64 + ni * 16 + (lane & 15);
        ushort* vb = Vtb + ((((size_t)b * 8 + hh) * 32 + dd) << 10) + l;
        vb[0]      = f2bf(acc[mi][ni][0] + bb.x);
        vb[1024]   = f2bf(acc[mi][ni][1] + bb.y);
        vb[2048]   = f2bf(acc[mi][ni][2] + bb.z);
        vb[3072]   = f2bf(acc[mi][ni][3] + bb.w);
      }
    }
  }
}

// ---- P2: flash POS attention, bf16 MFMA, no barriers -----------------------
__global__ __launch_bounds__(256) void k_pos_flash(
    const ushort* __restrict__ Qb, const ushort* __restrict__ Kb,
    const ushort* __restrict__ Vtb, ushort* __restrict__ op_pad)
{
  const int qt = blockIdx.x, h = blockIdx.y, b = blockIdx.z;
  const int bh = b * 8 + h;
  const int tid = threadIdx.x, lane = tid & 63, wq = tid >> 6;
  const int c = lane & 15, g = lane >> 4;
  __shared__ __align__(16) ushort Ps[4][32][72];   // wave-private P tiles
  const int qbase = qt * 128 + wq * 32;
  bf16x8 qf[2];
  #pragma unroll
  for (int nt = 0; nt < 2; ++nt)
    qf[nt] = *(const bf16x8*)(Qb + (((size_t)bh << 10) + qbase + nt * 16 + c) * 32 + g * 8);
  f32x4 o[2][2];
  #pragma unroll
  for (int mt = 0; mt < 2; ++mt)
    #pragma unroll
    for (int nt = 0; nt < 2; ++nt) {
      f32x4 z = {0.f, 0.f, 0.f, 0.f};
      o[mt][nt] = z;
    }
  float m[2] = {-1e30f, -1e30f}, l[2] = {0.f, 0.f};
  const ushort* Kbh = Kb + ((size_t)bh << 15);
  const ushort* Vbh = Vtb + ((size_t)bh << 15);

  for (int kt = 0; kt < 16; ++kt) {
    const int kb0 = kt * 64;
    bf16x8 kf[4];
    #pragma unroll
    for (int mt = 0; mt < 4; ++mt)
      kf[mt] = *(const bf16x8*)(Kbh + (size_t)(kb0 + mt * 16 + c) * 32 + g * 8);
    f32x4 s[4][2];
    #pragma unroll
    for (int mt = 0; mt < 4; ++mt)
      #pragma unroll
      for (int nt = 0; nt < 2; ++nt) {
        f32x4 z = {0.f, 0.f, 0.f, 0.f};
        s[mt][nt] = __builtin_amdgcn_mfma_f32_16x16x32_bf16(kf[mt], qf[nt], z, 0, 0, 0);
      }
    #pragma unroll
    for (int nt = 0; nt < 2; ++nt) {
      float tmax = -1e30f;
      #pragma unroll
      for (int mt = 0; mt < 4; ++mt)
        #pragma unroll
        for (int r = 0; r < 4; ++r)
          tmax = fmaxf(tmax, s[mt][nt][r]);
      tmax = fmaxf(tmax, __shfl_xor(tmax, 16, 64));
      tmax = fmaxf(tmax, __shfl_xor(tmax, 32, 64));
      const float mn = fmaxf(m[nt], tmax);
      const float alpha = __expf(m[nt] - mn);
      m[nt] = mn;
      float rs = 0.f;
      #pragma unroll
      for (int mt = 0; mt < 4; ++mt) {
        union { ushort u[4]; uint2 d; } pk;
        #pragma unroll
        for (int r = 0; r < 4; ++r) {
          float p = __expf(s[mt][nt][r] - mn);
          rs += p;
          pk.u[r] = f2bf(p);
        }
        *(uint2*)&Ps[wq][nt * 16 + c][mt * 16 + g * 4] = pk.d;
      }
      rs += __shfl_xor(rs, 16, 64);
      rs += __shfl_xor(rs, 32, 64);
      l[nt] = l[nt] * alpha + rs;
      #pragma unroll
      for (int mt = 0; mt < 2; ++mt)
        #pragma unroll
        for (int r = 0; r < 4; ++r)
          o[mt][nt][r] *= alpha;
    }
    #pragma unroll
    for (int kc = 0; kc < 2; ++kc) {
      bf16x8 vf[2], pf[2];
      #pragma unroll
      for (int mt = 0; mt < 2; ++mt)
        vf[mt] = *(const bf16x8*)(Vbh + (size_t)(mt * 16 + c) * 1024 + kb0 + kc * 32 + g * 8);
      #pragma unroll
      for (int nt = 0; nt < 2; ++nt)
        pf[nt] = *(const bf16x8*)&Ps[wq][nt * 16 + c][kc * 32 + g * 8];
      #pragma unroll
      for (int mt = 0; mt < 2; ++mt)
        #pragma unroll
        for (int nt = 0; nt < 2; ++nt)
          o[mt][nt] = __builtin_amdgcn_mfma_f32_16x16x32_bf16(vf[mt], pf[nt], o[mt][nt], 0, 0, 0);
    }
  }
  #pragma unroll
  for (int nt = 0; nt < 2; ++nt) {
    const float linv = 1.f / l[nt];
    const int q = qbase + nt * 16 + c;
    const int y = q >> 5, x = q & 31;
    ushort* dst = op_pad + ((size_t)b * 1156 + (y + 1) * 34 + (x + 1)) * 256 + h * 32;
    #pragma unroll
    for (int mt = 0; mt < 2; ++mt) {
      union { ushort u[4]; uint2 d; } pk;
      #pragma unroll
      for (int r = 0; r < 4; ++r)
        pk.u[r] = f2bf(o[mt][nt][r] * linv);
      *(uint2*)(dst + mt * 16 + g * 4) = pk.d;
    }
  }
}

// ------ 3x3 conv as 9 shifted GEMMs over padded NHWC, bf16 MFMA -------------
// (kept for the Wo conv; small grid, not the hot spot)
template <int CIN, int S, int PW, int OUT_NHWC>
__global__ __launch_bounds__(256) void k_conv9_mfma(
    const ushort* __restrict__ in, const ushort* __restrict__ W9,
    const float* __restrict__ bias, float* __restrict__ out)
{
  const int n0 = blockIdx.x * 128, oc0 = blockIdx.y * 128, b = blockIdx.z;
  const int tid = threadIdx.x, lane = tid & 63, w = tid >> 6;
  __shared__ ushort As[128][32], Bs[128][32];
  const int wr = w >> 1, wc = w & 1;
  f32x4 acc[4][4];
  #pragma unroll
  for (int mi = 0; mi < 4; ++mi)
    #pragma unroll
    for (int ni = 0; ni < 4; ++ni) {
      f32x4 z = {0.f, 0.f, 0.f, 0.f};
      acc[mi][ni] = z;
    }
  int rowq[2], segq[2], basep[2];
  #pragma unroll
  for (int q = 0; q < 2; ++q) {
    int idx = w * 128 + q * 64 + lane;
    rowq[q] = idx >> 2;
    segq[q] = (idx & 3) * 8;
    int n = n0 + rowq[q];
    int y = n / S, x = n % S;
    basep[q] = y * PW + x;
  }
  const ushort* inb = in + (size_t)b * (PW * PW) * CIN;

  for (int t = 0; t < 9; ++t) {
    const int offp = (t / 3) * PW + (t % 3);
    const ushort* wt = W9 + (size_t)t * 256 * CIN;
    for (int kc = 0; kc < CIN; kc += 32) {
      __syncthreads();
      #pragma unroll
      for (int q = 0; q < 2; ++q) {
        const ushort* srcA = wt + (size_t)(oc0 + rowq[q]) * CIN + kc + segq[q];
        const ushort* srcB = inb + (size_t)(basep[q] + offp) * CIN + kc + segq[q];
        char* dstA = (char*)&As[0][0] + w * 2048 + q * 1024;
        char* dstB = (char*)&Bs[0][0] + w * 2048 + q * 1024;
        __builtin_amdgcn_global_load_lds(
            (const __attribute__((address_space(1))) unsigned*)srcA,
            (__attribute__((address_space(3))) unsigned*)dstA, 16, 0, 0);
        __builtin_amdgcn_global_load_lds(
            (const __attribute__((address_space(1))) unsigned*)srcB,
            (__attribute__((address_space(3))) unsigned*)dstB, 16, 0, 0);
      }
      __syncthreads();
      bf16x8 af[4], bfv[4];
      #pragma unroll
      for (int mi = 0; mi < 4; ++mi)
        af[mi] = *(const bf16x8*)&As[wr * 64 + mi * 16 + (lane & 15)][(lane >> 4) * 8];
      #pragma unroll
      for (int ni = 0; ni < 4; ++ni)
        bfv[ni] = *(const bf16x8*)&Bs[wc * 64 + ni * 16 + (lane & 15)][(lane >> 4) * 8];
      #pragma unroll
      for (int mi = 0; mi < 4; ++mi)
        #pragma unroll
        for (int ni = 0; ni < 4; ++ni)
          acc[mi][ni] = __builtin_amdgcn_mfma_f32_16x16x32_bf16(
              af[mi], bfv[ni], acc[mi][ni], 0, 0, 0);
    }
  }
  if (OUT_NHWC) {
    float* outb = out + (size_t)b * (S * S) * 256;
    #pragma unroll
    for (int mi = 0; mi < 4; ++mi) {
      const int oc = oc0 + wr * 64 + mi * 16 + (lane >> 4) * 4;
      float4 bb = *(const float4*)(bias + oc);
      #pragma unroll
      for (int ni = 0; ni < 4; ++ni) {
        const int n = n0 + wc * 64 + ni * 16 + (lane & 15);
        float4 v;
        v.x = acc[mi][ni][0] + bb.x;
        v.y = acc[mi][ni][1] + bb.y;
        v.z = acc[mi][ni][2] + bb.z;
        v.w = acc[mi][ni][3] + bb.w;
        *(float4*)(outb + (size_t)n * 256 + oc) = v;
      }
    }
  } else {
    float* outb = out + (size_t)b * 256 * (S * S);
    #pragma unroll
    for (int mi = 0; mi < 4; ++mi) {
      #pragma unroll
      for (int r = 0; r < 4; ++r) {
        int oc = oc0 + wr * 64 + mi * 16 + (lane >> 4) * 4 + r;
        float bb = bias[oc];
        #pragma unroll
        for (int ni = 0; ni < 4; ++ni) {
          int n = n0 + wc * 64 + ni * 16 + (lane & 15);
          outb[(size_t)oc * (S * S) + n] = acc[mi][ni][r] + bb;
        }
      }
    }
  }
}

// ------ fusion 3x3 conv, CIN=512: pipelined 128x256 tile, BK=64 -------------
// T3+T4: triple-buffered LDS, stage s+2 while computing s, counted vmcnt(6),
// raw s_barrier. T2: XOR swizzle (byte ^= (row&7)<<4) via pre-swizzled
// per-lane global src into linear-dest global_load_lds; same XOR on ds_read.
// T5: setprio around MFMA cluster. Grid 16x2x8 = 256 blocks = 1/CU.
#define STAGE_CONV(s_, bi_)                                                    \
  {                                                                            \
    const int t_ = (s_) >> 3, kc_ = ((s_) & 7) << 6;                           \
    const ushort* wt_ = W9 + t_ * 131072 + kc_;                                \
    const ushort* ib_ = inb + ((t_ / 3) * 66 + (t_ % 3)) * 512 + kc_;          \
    _Pragma("unroll")                                                          \
    for (int q_ = 0; q_ < 2; ++q_) {                                           \
      __builtin_amdgcn_global_load_lds(                                        \
          (const __attribute__((address_space(1))) unsigned*)(wt_ + aInv[q_]), \
          (__attribute__((address_space(3))) unsigned*)                        \
              ((char*)lds + (bi_) * 16384 + (w * 16 + q_ * 8) * 128),          \
          16, 0, 0);                                                           \
    }                                                                          \
    _Pragma("unroll")                                                          \
    for (int q_ = 0; q_ < 4; ++q_) {                                           \
      __builtin_amdgcn_global_load_lds(                                        \
          (const __attribute__((address_space(1))) unsigned*)(ib_ + bInv[q_]), \
          (__attribute__((address_space(3))) unsigned*)                        \
              ((char*)lds + 49152 + (bi_) * 32768 + (w * 32 + q_ * 8) * 128),  \
          16, 0, 0);                                                           \
    }                                                                          \
  }

__global__ __launch_bounds__(512, 2) void k_conv9_pipe(
    const ushort* __restrict__ in, const ushort* __restrict__ W9,
    const float* __restrict__ bias, float* __restrict__ out)
{
  const int n0 = blockIdx.x * 256, oc0 = blockIdx.y * 128, b = blockIdx.z;
  const int tid = threadIdx.x, lane = tid & 63, w = tid >> 6;
  const int wm = w >> 2, wn = w & 3;            // 2M x 4N waves, 64x64 each
  const int g = lane >> 4, c = lane & 15;
  // A bufs: 3 x [128][64] bf16 @ byte 0 ; B bufs: 3 x [256][64] bf16 @ 49152
  __shared__ __align__(16) ushort lds[73728];   // 144 KiB
  const ushort* inb = in + (size_t)b * 4356 * 512;

  // per-lane staging invariants (row owned by this lane per issue; source
  // column pre-XORed so linear LDS dest + XORed ds_read = conflict-free)
  const int l8 = lane >> 3, lx = lane & 7;
  int aInv[2], bInv[4];
  #pragma unroll
  for (int q = 0; q < 2; ++q) {
    const int row = w * 16 + q * 8 + l8;
    const int cx = (((lx << 4) ^ ((row & 7) << 4)) >> 1);
    aInv[q] = (oc0 + row) * 512 + cx;
  }
  #pragma unroll
  for (int q = 0; q < 4; ++q) {
    const int row = w * 32 + q * 8 + l8;
    const int n = n0 + row;
    const int y = n >> 6, x = n & 63;
    const int cx = (((lx << 4) ^ ((row & 7) << 4)) >> 1);
    bInv[q] = (y * 66 + x) * 512 + cx;
  }

  f32x4 acc[4][4];
  #pragma unroll
  for (int mi = 0; mi < 4; ++mi)
    #pragma unroll
    for (int ni = 0; ni < 4; ++ni) {
      f32x4 z = {0.f, 0.f, 0.f, 0.f};
      acc[mi][ni] = z;
    }

  STAGE_CONV(0, 0);
  STAGE_CONV(1, 1);

  int bi = 0;
  for (int s = 0; s < 72; ++s) {
    // own loads for step s complete; steps s+1 (and s+2 later) stay in flight
    if (s < 71) asm volatile("s_waitcnt vmcnt(6)" ::: "memory");
    else        asm volatile("s_waitcnt vmcnt(0)" ::: "memory");
    __builtin_amdgcn_s_barrier();

    const ushort* As  = lds + bi * 8192;
    const ushort* Bsl = lds + 24576 + bi * 16384;
    bf16x8 af[4][2], bfv[4][2];
    #pragma unroll
    for (int mi = 0; mi < 4; ++mi) {
      const int row = wm * 64 + mi * 16 + c;
      const int sx = (row & 7) << 3;
      #pragma unroll
      for (int kh = 0; kh < 2; ++kh)
        af[mi][kh] = *(const bf16x8*)(As + row * 64 + ((kh * 32 + g * 8) ^ sx));
    }
    #pragma unroll
    for (int ni = 0; ni < 4; ++ni) {
      const int row = wn * 64 + ni * 16 + c;
      const int sx = (row & 7) << 3;
      #pragma unroll
      for (int kh = 0; kh < 2; ++kh)
        bfv[ni][kh] = *(const bf16x8*)(Bsl + row * 64 + ((kh * 32 + g * 8) ^ sx));
    }
    // prefetch step s+2 into the buffer last read at step s-1
    int bi2 = bi + 2; if (bi2 >= 3) bi2 -= 3;
    if (s < 70) STAGE_CONV(s + 2, bi2);

    __builtin_amdgcn_s_setprio(1);
    #pragma unroll
    for (int mi = 0; mi < 4; ++mi)
      #pragma unroll
      for (int ni = 0; ni < 4; ++ni) {
        acc[mi][ni] = __builtin_amdgcn_mfma_f32_16x16x32_bf16(
            af[mi][0], bfv[ni][0], acc[mi][ni], 0, 0, 0);
        acc[mi][ni] = __builtin_amdgcn_mfma_f32_16x16x32_bf16(
            af[mi][1], bfv[ni][1], acc[mi][ni], 0, 0, 0);
      }
    __builtin_amdgcn_s_setprio(0);
    ++bi; if (bi == 3) bi = 0;
  }

  // epilogue: NCHW fp32 + bias (same fragment convention as k_conv9_mfma)
  float* outb = out + (size_t)b * 1048576;
  #pragma unroll
  for (int mi = 0; mi < 4; ++mi) {
    const int oc = oc0 + wm * 64 + mi * 16 + g * 4;
    float4 bb = *(const float4*)(bias + oc);
    #pragma unroll
    for (int ni = 0; ni < 4; ++ni) {
      const int n = n0 + wn * 64 + ni * 16 + c;
      outb[(size_t)(oc + 0) * 4096 + n] = acc[mi][ni][0] + bb.x;
      outb[(size_t)(oc + 1) * 4096 + n] = acc[mi][ni][1] + bb.y;
      outb[(size_t)(oc + 2) * 4096 + n] = acc[mi][ni][2] + bb.z;
      outb[(size_t)(oc + 3) * 4096 + n] = acc[mi][ni][3] + bb.w;
    }
  }
}

// ---- P4: bilinear x2 upsample + residual -> fused_pad[.., ch 0:256] --------
__global__ __launch_bounds__(256) void k_upsample_nhwc(
    const float* __restrict__ xpos, const float* __restrict__ opc,
    const float* __restrict__ gamma, ushort* __restrict__ fused)
{
  const int t = blockIdx.x * 256 + threadIdx.x;  // 8*4096*64
  const int c = (t & 63) * 4;
  const int pix = (t >> 6) & 4095;
  const int b = t >> 18;
  const int y = pix >> 6, xx = pix & 63;
  const int my = y >> 1;
  const int y0 = (y & 1) ? my : my - 1;
  const float fy = (y & 1) ? 0.25f : 0.75f;
  const int mx = xx >> 1;
  const int x0 = (xx & 1) ? mx : mx - 1;
  const float fx = (xx & 1) ? 0.25f : 0.75f;
  const int y0c = max(y0, 0), y1c = min(y0 + 1, 31);
  const int x0c = max(x0, 0), x1c = min(x0 + 1, 31);
  const float* base = opc + (size_t)b * 1024 * 256 + c;
  float4 v00 = *(const float4*)(base + (size_t)(y0c * 32 + x0c) * 256);
  float4 v01 = *(const float4*)(base + (size_t)(y0c * 32 + x1c) * 256);
  float4 v10 = *(const float4*)(base + (size_t)(y1c * 32 + x0c) * 256);
  float4 v11 = *(const float4*)(base + (size_t)(y1c * 32 + x1c) * 256);
  const float w00 = (1.f - fy) * (1.f - fx), w01 = (1.f - fy) * fx;
  const float w10 = fy * (1.f - fx), w11 = fy * fx;
  const float g = gamma[0];
  const float* xr = xpos + ((size_t)b * 256 + c) * 4096 + pix;
  union { ushort u[4]; uint2 q; } o;
  o.u[0] = f2bf(xr[0]          + g * (w00 * v00.x + w01 * v01.x + w10 * v10.x + w11 * v11.x));
  o.u[1] = f2bf(xr[4096]       + g * (w00 * v00.y + w01 * v01.y + w10 * v10.y + w11 * v11.y));
  o.u[2] = f2bf(xr[2 * 4096]   + g * (w00 * v00.z + w01 * v01.z + w10 * v10.z + w11 * v11.z));
  o.u[3] = f2bf(xr[3 * 4096]   + g * (w00 * v00.w + w01 * v01.w + w10 * v10.w + w11 * v11.w));
  *(uint2*)(fused + ((size_t)b * 4356 + (y + 1) * 66 + (xx + 1)) * 512 + c) = o.q;
}

// ------- C0: CHA q/k/v grouped 2x2 projections -> bf16 (half-batch) ---------
__global__ __launch_bounds__(256) void k_cha_proj(
    const float* __restrict__ x,
    const float* __restrict__ Wq, const float* __restrict__ bq,
    const float* __restrict__ Wk, const float* __restrict__ bk,
    const float* __restrict__ Wv, const float* __restrict__ bv,
    ushort* __restrict__ Qc, ushort* __restrict__ Kc, ushort* __restrict__ Vt)
{
  const int t = blockIdx.x * 256 + threadIdx.x;
  const int bl = t >> 16;
  const int g  = (t >> 8) & 255;
  const int lq = t & 255;
  const int i = lq >> 3, j4 = (lq & 7) << 2;
  const float* xb = x + (((size_t)bl * 256 + g) << 12) + (2 * i) * 64 + 2 * j4;
  union { float4 v[2]; float f[8]; } xr0, xr1;
  xr0.v[0] = *(const float4*)(xb);
  xr0.v[1] = *(const float4*)(xb + 4);
  xr1.v[0] = *(const float4*)(xb + 64);
  xr1.v[1] = *(const float4*)(xb + 68);
  const int bhl = bl * 8 + (g >> 5);
  const int c2b = (g & 31) * 8;
  const int l0 = i * 32 + j4;
  #pragma unroll
  for (int h = 0; h < 8; ++h) {
    float4 w4 = *(const float4*)(Wq + g * 32 + h * 4);
    float bb = bq[g * 8 + h];
    union { ushort u[4]; uint2 q; } o;
    #pragma unroll
    for (int jj = 0; jj < 4; ++jj) {
      float v = xr0.f[2 * jj] * w4.x + xr0.f[2 * jj + 1] * w4.y
              + xr1.f[2 * jj] * w4.z + xr1.f[2 * jj + 1] * w4.w + bb;
      o.u[jj] = f2bf(v * 0.03125f);
    }
    *(uint2*)(Qc + (((size_t)bhl * 256 + c2b + h) << 10) + l0) = o.q;
  }
  #pragma unroll
  for (int h = 0; h < 8; ++h) {
    float4 w4 = *(const float4*)(Wk + g * 32 + h * 4);
    float bb = bk[g * 8 + h];
    union { ushort u[4]; uint2 q; } o;
    #pragma unroll
    for (int jj = 0; jj < 4; ++jj) {
      float v = xr0.f[2 * jj] * w4.x + xr0.f[2 * jj + 1] * w4.y
              + xr1.f[2 * jj] * w4.z + xr1.f[2 * jj + 1] * w4.w + bb;
      o.u[jj] = f2bf(v);
    }
    *(uint2*)(Kc + (((size_t)bhl * 256 + c2b + h) << 10) + l0) = o.q;
  }
  ushort vo[4][8];
  #pragma unroll
  for (int h = 0; h < 8; ++h) {
    float4 w4 = *(const float4*)(Wv + g * 32 + h * 4);
    float bb = bv[g * 8 + h];
    #pragma unroll
    for (int jj = 0; jj < 4; ++jj) {
      float v = xr0.f[2 * jj] * w4.x + xr0.f[2 * jj + 1] * w4.y
              + xr1.f[2 * jj] * w4.z + xr1.f[2 * jj + 1] * w4.w + bb;
      vo[jj][h] = f2bf(v);
    }
  }
  #pragma unroll
  for (int jj = 0; jj < 4; ++jj)
    *(uint4*)(Vt + ((size_t)bhl << 18) + (size_t)(l0 + jj) * 256 + c2b) =
        *(uint4*)&vo[jj][0];
}

// ------- C1: scores = qc @ kc^T, bf16 MFMA, K=1024 (half-batch) -------------
__global__ __launch_bounds__(256) void k_cha_scores_mfma(
    const ushort* __restrict__ Qc, const ushort* __restrict__ Kc,
    float* __restrict__ S)
{
  const int c0 = blockIdx.x * 128, d0 = blockIdx.y * 128, bhl = blockIdx.z;
  const int tid = threadIdx.x, lane = tid & 63, w = tid >> 6;
  __shared__ ushort As[128][32], Bs[128][32];
  const ushort* Ab = Qc + ((size_t)bhl * 256 + c0) * 1024;
  const ushort* Bb = Kc + ((size_t)bhl * 256 + d0) * 1024;
  const int wr = w >> 1, wc = w & 1;
  f32x4 acc[4][4];
  #pragma unroll
  for (int mi = 0; mi < 4; ++mi)
    #pragma unroll
    for (int ni = 0; ni < 4; ++ni) {
      f32x4 z = {0.f, 0.f, 0.f, 0.f};
      acc[mi][ni] = z;
    }
  for (int kc = 0; kc < 1024; kc += 32) {
    __syncthreads();
    #pragma unroll
    for (int q = 0; q < 2; ++q) {
      int idx = w * 128 + q * 64 + lane;
      int row = idx >> 2, seg = idx & 3;
      const ushort* srcA = Ab + (size_t)row * 1024 + kc + seg * 8;
      const ushort* srcB = Bb + (size_t)row * 1024 + kc + seg * 8;
      char* dstA = (char*)&As[0][0] + w * 2048 + q * 1024;
      char* dstB = (char*)&Bs[0][0] + w * 2048 + q * 1024;
      __builtin_amdgcn_global_load_lds(
          (const __attribute__((address_space(1))) unsigned*)srcA,
          (__attribute__((address_space(3))) unsigned*)dstA, 16, 0, 0);
      __builtin_amdgcn_global_load_lds(
          (const __attribute__((address_space(1))) unsigned*)srcB,
          (__attribute__((address_space(3))) unsigned*)dstB, 16, 0, 0);
    }
    __syncthreads();
    bf16x8 af[4], bfv[4];
    #pragma unroll
    for (int mi = 0; mi < 4; ++mi)
      af[mi] = *(const bf16x8*)&As[wr * 64 + mi * 16 + (lane & 15)][(lane >> 4) * 8];
    #pragma unroll
    for (int ni = 0; ni < 4; ++ni)
      bfv[ni] = *(const bf16x8*)&Bs[wc * 64 + ni * 16 + (lane & 15)][(lane >> 4) * 8];
    #pragma unroll
    for (int mi = 0; mi < 4; ++mi)
      #pragma unroll
      for (int ni = 0; ni < 4; ++ni)
        acc[mi][ni] = __builtin_amdgcn_mfma_f32_16x16x32_bf16(
            af[mi], bfv[ni], acc[mi][ni], 0, 0, 0);
  }
  float* Sb = S + ((size_t)bhl << 16);
  #pragma unroll
  for (int mi = 0; mi < 4; ++mi)
    #pragma unroll
    for (int r = 0; r < 4; ++r) {
      int c = c0 + wr * 64 + mi * 16 + (lane >> 4) * 4 + r;
      #pragma unroll
      for (int ni = 0; ni < 4; ++ni) {
        int d = d0 + wc * 64 + ni * 16 + (lane & 15);
        Sb[(size_t)c * 256 + d] = acc[mi][ni][r];
      }
    }
}

// ------- C2: row softmax over 256 -> bf16 P ---------------------------------
__global__ __launch_bounds__(256) void k_softmax_p(
    const float* __restrict__ S, ushort* __restrict__ P)
{
  const int row = blockIdx.x * 4 + (threadIdx.x >> 6);
  const int lane = threadIdx.x & 63;
  const float* r = S + (size_t)row * 256;
  float4 v = *(const float4*)(r + lane * 4);
  float m = fmaxf(fmaxf(v.x, v.y), fmaxf(v.z, v.w));
  #pragma unroll
  for (int off = 32; off; off >>= 1) m = fmaxf(m, __shfl_xor(m, off, 64));
  v.x = __expf(v.x - m); v.y = __expf(v.y - m);
  v.z = __expf(v.z - m); v.w = __expf(v.w - m);
  float s = v.x + v.y + v.z + v.w;
  #pragma unroll
  for (int off = 32; off; off >>= 1) s += __shfl_xor(s, off, 64);
  const float inv = 1.f / s;
  union { ushort u[4]; uint2 q; } o;
  o.u[0] = f2bf(v.x * inv); o.u[1] = f2bf(v.y * inv);
  o.u[2] = f2bf(v.z * inv); o.u[3] = f2bf(v.w * inv);
  *(uint2*)(P + (size_t)row * 256 + lane * 4) = o.q;
}

// -- C3: oc = P @ vcT (MFMA) + grouped ConvT + residual -> fused_pad NHWC ----
__global__ __launch_bounds__(256) void k_cha_pv(
    const ushort* __restrict__ P, const ushort* __restrict__ Vt,
    const float* __restrict__ x,
    const float* __restrict__ Wt, const float* __restrict__ bt,
    const float* __restrict__ gamma, ushort* __restrict__ fused, int bbase)
{
  const int n0 = blockIdx.x * 128, c0 = blockIdx.y * 128, bhl = blockIdx.z;
  const int b = bbase + (bhl >> 3), h = bhl & 7;
  const int tid = threadIdx.x, lane = tid & 63, w = tid >> 6;
  __shared__ ushort As[128][32], Bs[128][32];
  __shared__ ushort Ot[512][16];
  __shared__ float wt_s[16][32];
  __shared__ float bt_s[16];
  const int gp_base = h * 32 + (c0 >> 3);
  {
    int e = tid;
    wt_s[e >> 5][e & 31] = Wt[(size_t)gp_base * 32 + e];
    e += 256;
    wt_s[e >> 5][e & 31] = Wt[(size_t)gp_base * 32 + e];
    if (tid < 16) bt_s[tid] = bt[gp_base + tid];
  }
  const ushort* Ab = P + (((size_t)bhl << 8) + c0) * 256;
  const ushort* Bb = Vt + ((size_t)bhl << 18) + (size_t)n0 * 256;
  const int wr = w >> 1, wc = w & 1;
  f32x4 acc[4][4];
  #pragma unroll
  for (int mi = 0; mi < 4; ++mi)
    #pragma unroll
    for (int ni = 0; ni < 4; ++ni) {
      f32x4 z = {0.f, 0.f, 0.f, 0.f};
      acc[mi][ni] = z;
    }
  for (int kc = 0; kc < 256; kc += 32) {
    __syncthreads();
    #pragma unroll
    for (int q = 0; q < 2; ++q) {
      int idx = w * 128 + q * 64 + lane;
      int row = idx >> 2, seg = idx & 3;
      const ushort* srcA = Ab + (size_t)row * 256 + kc + seg * 8;
      const ushort* srcB = Bb + (size_t)row * 256 + kc + seg * 8;
      char* dstA = (char*)&As[0][0] + w * 2048 + q * 1024;
      char* dstB = (char*)&Bs[0][0] + w * 2048 + q * 1024;
      __builtin_amdgcn_global_load_lds(
          (const __attribute__((address_space(1))) unsigned*)srcA,
          (__attribute__((address_space(3))) unsigned*)dstA, 16, 0, 0);
      __builtin_amdgcn_global_load_lds(
          (const __attribute__((address_space(1))) unsigned*)srcB,
          (__attribute__((address_space(3))) unsigned*)dstB, 16, 0, 0);
    }
    __syncthreads();
    bf16x8 af[4], bfv[4];
    #pragma unroll
    for (int mi = 0; mi < 4; ++mi)
      af[mi] = *(const bf16x8*)&As[wr * 64 + mi * 16 + (lane & 15)][(lane >> 4) * 8];
    #pragma unroll
    for (int ni = 0; ni < 4; ++ni)
      bfv[ni] = *(const bf16x8*)&Bs[wc * 64 + ni * 16 + (lane & 15)][(lane >> 4) * 8];
    #pragma unroll
    for (int mi = 0; mi < 4; ++mi)
      #pragma unroll
      for (int ni = 0; ni < 4; ++ni)
        acc[mi][ni] = __builtin_amdgcn_mfma_f32_16x16x32_bf16(
            af[mi], bfv[ni], acc[mi][ni], 0, 0, 0);
  }
  const float gm = gamma[0];
  const int col = lane & 15, q = lane >> 4;
  #pragma unroll
  for (int mi = 0; mi < 4; ++mi) {
    const int gloc = wr * 8 + mi * 2 + (q >> 1);
    const int gp = gp_base + gloc;
    const float btv = bt_s[gloc];
    #pragma unroll
    for (int ni = 0; ni < 4; ++ni) {
      float pa[4] = {0.f, 0.f, 0.f, 0.f};
      #pragma unroll
      for (int r = 0; r < 4; ++r) {
        const int i2 = (q & 1) * 4 + r;
        const float a = acc[mi][ni][r];
        pa[0] += a * wt_s[gloc][i2 * 4 + 0];
        pa[1] += a * wt_s[gloc][i2 * 4 + 1];
        pa[2] += a * wt_s[gloc][i2 * 4 + 2];
        pa[3] += a * wt_s[gloc][i2 * 4 + 3];
      }
      float v0 = pa[0] + __shfl_xor(pa[0], 16, 64);
      float v1 = pa[1] + __shfl_xor(pa[1], 16, 64);
      float v2 = pa[2] + __shfl_xor(pa[2], 16, 64);
      float v3 = pa[3] + __shfl_xor(pa[3], 16, 64);
      const int lloc = wc * 64 + ni * 16 + col;
      const int l = n0 + lloc;
      const int p = l >> 5, j = l & 31;
      const int y = 2 * p + (q & 1);
      const float va = (q & 1) ? v2 : v0;
      const float vb = (q & 1) ? v3 : v1;
      const float* xc = x + (((size_t)b * 256 + gp) << 12) + (y << 6) + 2 * j;
      const int lp = (lloc << 2) + (q & 1) * 2;
      Ot[lp][gloc]     = f2bf(xc[0] + gm * (va + btv));
      Ot[lp + 1][gloc] = f2bf(xc[1] + gm * (vb + btv));
    }
  }
  __syncthreads();
  #pragma unroll
  for (int pp2 = 0; pp2 < 2; ++pp2) {
    const int pixl = tid * 2 + pp2;
    const int lloc = pixl >> 2;
    const int l = n0 + lloc;
    const int p = l >> 5, j = l & 31;
    const int yy = 2 * p + ((pixl >> 1) & 1) + 1;
    const int xx = 2 * j + (pixl & 1) + 1;
    const uint4* src = (const uint4*)&Ot[pixl][0];
    uint4* dst = (uint4*)(fused + ((size_t)b * 4356 + yy * 66 + xx) * 512 + 256 + gp_base);
    dst[0] = src[0];
    dst[1] = src[1];
  }
}

extern "C" void kernel_launch(void* const* d_in, const int* in_sizes, int n_in,
                              void* d_out, int out_size, void* d_ws, size_t ws_size,
                              hipStream_t stream)
{
  (void)in_sizes; (void)n_in; (void)out_size; (void)ws_size;
  const float* qkv_pos   = (const float*)d_in[0];
  const float* qkv_cha   = (const float*)d_in[1];
  const float* Wq_pos    = (const float*)d_in[2];
  const float* bq_pos    = (const float*)d_in[3];
  const float* Wk_pos    = (const float*)d_in[4];
  const float* bk_pos    = (const float*)d_in[5];
  const float* Wv_pos    = (const float*)d_in[6];
  const float* bv_pos    = (const float*)d_in[7];
  const float* Wo_pos    = (const float*)d_in[8];
  const float* bo_pos    = (const float*)d_in[9];
  const float* gamma_pos = (const float*)d_in[10];
  const float* Wq_cha    = (const float*)d_in[11];
  const float* bq_cha    = (const float*)d_in[12];
  const float* Wk_cha    = (const float*)d_in[13];
  const float* bk_cha    = (const float*)d_in[14];
  const float* Wv_cha    = (const float*)d_in[15];
  const float* bv_cha    = (const float*)d_in[16];
  const float* Wt_cha    = (const float*)d_in[17];
  const float* bt_cha    = (const float*)d_in[18];
  const float* gamma_cha = (const float*)d_in[19];
  const float* Wf        = (const float*)d_in[20];
  const float* bf        = (const float*)d_in[21];
  float* out = (float*)d_out;

  float* ws = (float*)d_ws;
  ushort* Wpf9    = (ushort*)ws;
  ushort* Wpo9    = (ushort*)(ws + 589824);
  // POS scratch
  ushort* Qb      = (ushort*)(ws + 884736);    // [64][1024][32] bf16
  ushort* Kb      = (ushort*)(ws + 1933312);   // [64][1024][32] bf16
  ushort* Vtb     = (ushort*)(ws + 2981888);   // [64][32][1024] bf16
  ushort* op_pad  = (ushort*)(ws + 4030464);   // 2367488 ushorts
  float*  op_conv = ws + 5214208;              // NHWC fp32 [8][1024][256]
  ushort* Ap      = (ushort*)(ws + 7311360);   // [8][1024][1024] bf16
  // CHA scratch (aliases POS region after it is consumed)
  ushort* qcb     = (ushort*)(ws + 884736);
  ushort* kcb     = (ushort*)(ws + 5079040);
  ushort* vcT     = (ushort*)(ws + 9273344);
  float*  attn_c  = ws + 13467648;
  ushort* Pb      = (ushort*)(ws + 15564800);
  ushort* fusedb  = (ushort*)(ws + 16613376);  // NHWC padded [8][66*66][512]
  ushort* Wqkvp   = (ushort*)(ws + 25534464);  // [384][1024] bf16

  // zero padded buffers (conv borders) and Qb (hd pad lanes 8..31 must be 0)
  hipMemsetAsync(op_pad, 0, (size_t)2367488 * 2, stream);
  hipMemsetAsync(fusedb, 0, (size_t)17842176 * 2, stream);
  hipMemsetAsync(Qb, 0, (size_t)2097152 * 2, stream);
  // weight pre-packs
  k_prepack9<512><<<dim3(4608), 256, 0, stream>>>(Wf, Wpf9);
  k_prepack9<256><<<dim3(2304), 256, 0, stream>>>(Wo_pos, Wpo9);
  k_cast_wqkv<<<dim3(1536), 256, 0, stream>>>(Wq_pos, Wk_pos, Wv_pos, Wqkvp);
  // POS branch
  k_pack_pos<<<dim3(2048), 256, 0, stream>>>(qkv_pos, Ap);
  k_pos_qkv_mfma<<<dim3(8, 3, 8), 256, 0, stream>>>(Ap, Wqkvp,
      bq_pos, bk_pos, bv_pos, Qb, Kb, Vtb);
  k_pos_flash<<<dim3(8, 8, 8), 256, 0, stream>>>(Qb, Kb, Vtb, op_pad);
  k_conv9_mfma<256, 32, 34, 1><<<dim3(8, 2, 8), 256, 0, stream>>>(
      op_pad, Wpo9, bo_pos, op_conv);
  k_upsample_nhwc<<<dim3(8192), 256, 0, stream>>>(qkv_pos, op_conv, gamma_pos, fusedb);
  // CHA branch, two half-batches
  for (int half = 0; half < 2; ++half) {
    const float* xh = qkv_cha + (size_t)half * 4 * 256 * 4096;
    k_cha_proj<<<dim3(1024), 256, 0, stream>>>(xh, Wq_cha, bq_cha,
        Wk_cha, bk_cha, Wv_cha, bv_cha, qcb, kcb, vcT);
    k_cha_scores_mfma<<<dim3(2, 2, 32), 256, 0, stream>>>(qcb, kcb, attn_c);
    k_softmax_p<<<dim3(2048), 256, 0, stream>>>(attn_c, Pb);
    k_cha_pv<<<dim3(8, 2, 32), 256, 0, stream>>>(Pb, vcT, qkv_cha,
        Wt_cha, bt_cha, gamma_cha, fusedb, half * 4);
  }
  // fusion conv: pipelined 128x256 tile, 256 blocks = 1/CU
  k_conv9_pipe<<<dim3(16, 2, 8), 512, 0, stream>>>(fusedb, Wpf9, bf, out);
}

// Round 3
// 549.822 us; speedup vs baseline: 1.0502x; 1.0107x over previous
//
#include <hip/hip_runtime.h>
#include <math.h>

// Shapes: B=8, C=256, H=W=64, HQ=WQ=32, L=1024, NH=8, hd=8, dv=32
//
// Workspace (float units):
//   Wpf9 bf16[9][256][512] @ 0        (589824 f)
//   Wpo9 bf16[9][256][256] @ 589824   (294912 f)
//   region2 @ 884736 (POS scratch, later aliased by CHA scratch)
//   fused_pad bf16[8][66*66][512] @ 16613376 (8921088 f)
//   Wqkv_p bf16[384][1024] @ 25534464 (196608 f)

typedef __attribute__((ext_vector_type(8))) short bf16x8;
typedef __attribute__((ext_vector_type(4))) float f32x4;

__device__ __forceinline__ ushort f2bf(float f) {
  union { float f; unsigned u; } v; v.f = f;
  unsigned r = (v.u + 0x7FFFu + ((v.u >> 16) & 1u)) >> 16;
  return (ushort)r;
}

// -------- weight pre-pack: W[oc][cin][3][3] fp32 -> [t][oc][cin] bf16 -------
template <int CIN>
__global__ __launch_bounds__(256) void k_prepack9(
    const float* __restrict__ W, ushort* __restrict__ out)
{
  const int i = blockIdx.x * 256 + threadIdx.x;   // over 9*256*CIN
  const int t = i / (256 * CIN);
  const int r = i - t * (256 * CIN);
  const int oc = r / CIN;
  const int c = r - oc * CIN;
  out[i] = f2bf(W[((size_t)oc * CIN + c) * 9 + t]);
}

// -------- concat Wq/Wk/Wv -> bf16 [384][1024] -------------------------------
__global__ __launch_bounds__(256) void k_cast_wqkv(
    const float* __restrict__ Wq, const float* __restrict__ Wk,
    const float* __restrict__ Wv, ushort* __restrict__ out)
{
  const int i = blockIdx.x * 256 + threadIdx.x;   // over 384*1024
  const int o = i >> 10, k = i & 1023;
  float v;
  if (o < 64)       v = Wq[(size_t)o * 1024 + k];
  else if (o < 128) v = Wk[(size_t)(o - 64) * 1024 + k];
  else              v = Wv[(size_t)(o - 128) * 1024 + k];
  out[i] = f2bf(v);
}

// -------- patchify x (2x2 stride-2 im2col) -> bf16 Ap[b][l][1024] -----------
__global__ __launch_bounds__(256) void k_pack_pos(
    const float* __restrict__ x, ushort* __restrict__ Ap)
{
  const int t = blockIdx.x * 256 + threadIdx.x;   // 524288 threads
  const int j4 = t & 7;          // group of 4 output cols
  const int i  = (t >> 3) & 31;  // output row
  const int c  = (t >> 8) & 255;
  const int b  = t >> 16;
  const float* xb = x + (((size_t)b * 256 + c) << 12) + (2 * i) * 64 + 8 * j4;
  union { float4 v[2]; float f[8]; } r0, r1;
  r0.v[0] = *(const float4*)(xb);
  r0.v[1] = *(const float4*)(xb + 4);
  r1.v[0] = *(const float4*)(xb + 64);
  r1.v[1] = *(const float4*)(xb + 68);
  #pragma unroll
  for (int jj = 0; jj < 4; ++jj) {
    const int l = i * 32 + j4 * 4 + jj;
    union { ushort u[4]; uint2 d; } pk;
    pk.u[0] = f2bf(r0.f[2 * jj]);
    pk.u[1] = f2bf(r0.f[2 * jj + 1]);
    pk.u[2] = f2bf(r1.f[2 * jj]);
    pk.u[3] = f2bf(r1.f[2 * jj + 1]);
    *(uint2*)(Ap + ((((size_t)b << 10) + l) << 10) + c * 4) = pk.d;
  }
}

// ---- P1: POS q/k/v projection as bf16 MFMA GEMM [384x1024]x[1024xL] --------
__global__ __launch_bounds__(256) void k_pos_qkv_mfma(
    const ushort* __restrict__ Ap, const ushort* __restrict__ Wqkv,
    const float* __restrict__ bq, const float* __restrict__ bk,
    const float* __restrict__ bv,
    ushort* __restrict__ Qb, ushort* __restrict__ Kb, ushort* __restrict__ Vtb)
{
  const int n0 = blockIdx.x * 128, oc0 = blockIdx.y * 128, b = blockIdx.z;
  const int tid = threadIdx.x, lane = tid & 63, w = tid >> 6;
  __shared__ ushort As[128][32], Bs[128][32];
  const ushort* Abw = Wqkv + (size_t)oc0 * 1024;
  const ushort* Bb  = Ap + (((size_t)b << 10) + n0) * 1024;
  const int wr = w >> 1, wc = w & 1;
  f32x4 acc[4][4];
  #pragma unroll
  for (int mi = 0; mi < 4; ++mi)
    #pragma unroll
    for (int ni = 0; ni < 4; ++ni) {
      f32x4 z = {0.f, 0.f, 0.f, 0.f};
      acc[mi][ni] = z;
    }
  for (int kc = 0; kc < 1024; kc += 32) {
    __syncthreads();
    #pragma unroll
    for (int q = 0; q < 2; ++q) {
      int idx = w * 128 + q * 64 + lane;
      int row = idx >> 2, seg = idx & 3;
      const ushort* srcA = Abw + (size_t)row * 1024 + kc + seg * 8;
      const ushort* srcB = Bb + (size_t)row * 1024 + kc + seg * 8;
      char* dstA = (char*)&As[0][0] + w * 2048 + q * 1024;
      char* dstB = (char*)&Bs[0][0] + w * 2048 + q * 1024;
      __builtin_amdgcn_global_load_lds(
          (const __attribute__((address_space(1))) unsigned*)srcA,
          (__attribute__((address_space(3))) unsigned*)dstA, 16, 0, 0);
      __builtin_amdgcn_global_load_lds(
          (const __attribute__((address_space(1))) unsigned*)srcB,
          (__attribute__((address_space(3))) unsigned*)dstB, 16, 0, 0);
    }
    __syncthreads();
    bf16x8 af[4], bfv[4];
    #pragma unroll
    for (int mi = 0; mi < 4; ++mi)
      af[mi] = *(const bf16x8*)&As[wr * 64 + mi * 16 + (lane & 15)][(lane >> 4) * 8];
    #pragma unroll
    for (int ni = 0; ni < 4; ++ni)
      bfv[ni] = *(const bf16x8*)&Bs[wc * 64 + ni * 16 + (lane & 15)][(lane >> 4) * 8];
    #pragma unroll
    for (int mi = 0; mi < 4; ++mi)
      #pragma unroll
      for (int ni = 0; ni < 4; ++ni)
        acc[mi][ni] = __builtin_amdgcn_mfma_f32_16x16x32_bf16(
            af[mi], bfv[ni], acc[mi][ni], 0, 0, 0);
  }
  // epilogue: scatter into flash layouts (Q scaled, bias added)
  #pragma unroll
  for (int mi = 0; mi < 4; ++mi) {
    const int oc = oc0 + wr * 64 + mi * 16 + (lane >> 4) * 4;  // mult of 4
    if (oc >= 384) continue;
    if (oc < 64) {
      const int hh = oc >> 3, e = oc & 7;
      float4 bb = *(const float4*)(bq + oc);
      #pragma unroll
      for (int ni = 0; ni < 4; ++ni) {
        const int l = n0 + wc * 64 + ni * 16 + (lane & 15);
        union { ushort u[4]; uint2 d; } pk;
        pk.u[0] = f2bf((acc[mi][ni][0] + bb.x) * 0.35355339059327373f);
        pk.u[1] = f2bf((acc[mi][ni][1] + bb.y) * 0.35355339059327373f);
        pk.u[2] = f2bf((acc[mi][ni][2] + bb.z) * 0.35355339059327373f);
        pk.u[3] = f2bf((acc[mi][ni][3] + bb.w) * 0.35355339059327373f);
        *(uint2*)(Qb + (((((size_t)b * 8 + hh) << 10) + l) << 5) + e) = pk.d;
      }
    } else if (oc < 128) {
      const int o2 = oc - 64, hh = o2 >> 3, e = o2 & 7;
      float4 bb = *(const float4*)(bk + o2);
      #pragma unroll
      for (int ni = 0; ni < 4; ++ni) {
        const int l = n0 + wc * 64 + ni * 16 + (lane & 15);
        union { ushort u[4]; uint2 d; } pk;
        pk.u[0] = f2bf(acc[mi][ni][0] + bb.x);
        pk.u[1] = f2bf(acc[mi][ni][1] + bb.y);
        pk.u[2] = f2bf(acc[mi][ni][2] + bb.z);
        pk.u[3] = f2bf(acc[mi][ni][3] + bb.w);
        *(uint2*)(Kb + (((((size_t)b * 8 + hh) << 10) + l) << 5) + e) = pk.d;
      }
    } else {
      const int o2 = oc - 128, hh = o2 >> 5, dd = o2 & 31;
      float4 bb = *(const float4*)(bv + o2);
      #pragma unroll
      for (int ni = 0; ni < 4; ++ni) {
        const int l = n0 + wc * 64 + ni * 16 + (lane & 15);
        ushort* vb = Vtb + ((((size_t)b * 8 + hh) * 32 + dd) << 10) + l;
        vb[0]      = f2bf(acc[mi][ni][0] + bb.x);
        vb[1024]   = f2bf(acc[mi][ni][1] + bb.y);
        vb[2048]   = f2bf(acc[mi][ni][2] + bb.z);
        vb[3072]   = f2bf(acc[mi][ni][3] + bb.w);
      }
    }
  }
}

// ---- P2: flash POS attention, bf16 MFMA, no barriers -----------------------
__global__ __launch_bounds__(256) void k_pos_flash(
    const ushort* __restrict__ Qb, const ushort* __restrict__ Kb,
    const ushort* __restrict__ Vtb, ushort* __restrict__ op_pad)
{
  const int qt = blockIdx.x, h = blockIdx.y, b = blockIdx.z;
  const int bh = b * 8 + h;
  const int tid = threadIdx.x, lane = tid & 63, wq = tid >> 6;
  const int c = lane & 15, g = lane >> 4;
  __shared__ __align__(16) ushort Ps[4][32][72];   // wave-private P tiles
  const int qbase = qt * 128 + wq * 32;
  bf16x8 qf[2];
  #pragma unroll
  for (int nt = 0; nt < 2; ++nt)
    qf[nt] = *(const bf16x8*)(Qb + (((size_t)bh << 10) + qbase + nt * 16 + c) * 32 + g * 8);
  f32x4 o[2][2];
  #pragma unroll
  for (int mt = 0; mt < 2; ++mt)
    #pragma unroll
    for (int nt = 0; nt < 2; ++nt) {
      f32x4 z = {0.f, 0.f, 0.f, 0.f};
      o[mt][nt] = z;
    }
  float m[2] = {-1e30f, -1e30f}, l[2] = {0.f, 0.f};
  const ushort* Kbh = Kb + ((size_t)bh << 15);
  const ushort* Vbh = Vtb + ((size_t)bh << 15);

  for (int kt = 0; kt < 16; ++kt) {
    const int kb0 = kt * 64;
    bf16x8 kf[4];
    #pragma unroll
    for (int mt = 0; mt < 4; ++mt)
      kf[mt] = *(const bf16x8*)(Kbh + (size_t)(kb0 + mt * 16 + c) * 32 + g * 8);
    f32x4 s[4][2];
    #pragma unroll
    for (int mt = 0; mt < 4; ++mt)
      #pragma unroll
      for (int nt = 0; nt < 2; ++nt) {
        f32x4 z = {0.f, 0.f, 0.f, 0.f};
        s[mt][nt] = __builtin_amdgcn_mfma_f32_16x16x32_bf16(kf[mt], qf[nt], z, 0, 0, 0);
      }
    #pragma unroll
    for (int nt = 0; nt < 2; ++nt) {
      float tmax = -1e30f;
      #pragma unroll
      for (int mt = 0; mt < 4; ++mt)
        #pragma unroll
        for (int r = 0; r < 4; ++r)
          tmax = fmaxf(tmax, s[mt][nt][r]);
      tmax = fmaxf(tmax, __shfl_xor(tmax, 16, 64));
      tmax = fmaxf(tmax, __shfl_xor(tmax, 32, 64));
      const float mn = fmaxf(m[nt], tmax);
      const float alpha = __expf(m[nt] - mn);
      m[nt] = mn;
      float rs = 0.f;
      #pragma unroll
      for (int mt = 0; mt < 4; ++mt) {
        union { ushort u[4]; uint2 d; } pk;
        #pragma unroll
        for (int r = 0; r < 4; ++r) {
          float p = __expf(s[mt][nt][r] - mn);
          rs += p;
          pk.u[r] = f2bf(p);
        }
        *(uint2*)&Ps[wq][nt * 16 + c][mt * 16 + g * 4] = pk.d;
      }
      rs += __shfl_xor(rs, 16, 64);
      rs += __shfl_xor(rs, 32, 64);
      l[nt] = l[nt] * alpha + rs;
      #pragma unroll
      for (int mt = 0; mt < 2; ++mt)
        #pragma unroll
        for (int r = 0; r < 4; ++r)
          o[mt][nt][r] *= alpha;
    }
    #pragma unroll
    for (int kc = 0; kc < 2; ++kc) {
      bf16x8 vf[2], pf[2];
      #pragma unroll
      for (int mt = 0; mt < 2; ++mt)
        vf[mt] = *(const bf16x8*)(Vbh + (size_t)(mt * 16 + c) * 1024 + kb0 + kc * 32 + g * 8);
      #pragma unroll
      for (int nt = 0; nt < 2; ++nt)
        pf[nt] = *(const bf16x8*)&Ps[wq][nt * 16 + c][kc * 32 + g * 8];
      #pragma unroll
      for (int mt = 0; mt < 2; ++mt)
        #pragma unroll
        for (int nt = 0; nt < 2; ++nt)
          o[mt][nt] = __builtin_amdgcn_mfma_f32_16x16x32_bf16(vf[mt], pf[nt], o[mt][nt], 0, 0, 0);
    }
  }
  #pragma unroll
  for (int nt = 0; nt < 2; ++nt) {
    const float linv = 1.f / l[nt];
    const int q = qbase + nt * 16 + c;
    const int y = q >> 5, x = q & 31;
    ushort* dst = op_pad + ((size_t)b * 1156 + (y + 1) * 34 + (x + 1)) * 256 + h * 32;
    #pragma unroll
    for (int mt = 0; mt < 2; ++mt) {
      union { ushort u[4]; uint2 d; } pk;
      #pragma unroll
      for (int r = 0; r < 4; ++r)
        pk.u[r] = f2bf(o[mt][nt][r] * linv);
      *(uint2*)(dst + mt * 16 + g * 4) = pk.d;
    }
  }
}

// ------ 3x3 conv as 9 shifted GEMMs over padded NHWC, bf16 MFMA -------------
// (kept for the Wo conv; small grid, not the hot spot)
template <int CIN, int S, int PW, int OUT_NHWC>
__global__ __launch_bounds__(256) void k_conv9_mfma(
    const ushort* __restrict__ in, const ushort* __restrict__ W9,
    const float* __restrict__ bias, float* __restrict__ out)
{
  const int n0 = blockIdx.x * 128, oc0 = blockIdx.y * 128, b = blockIdx.z;
  const int tid = threadIdx.x, lane = tid & 63, w = tid >> 6;
  __shared__ ushort As[128][32], Bs[128][32];
  const int wr = w >> 1, wc = w & 1;
  f32x4 acc[4][4];
  #pragma unroll
  for (int mi = 0; mi < 4; ++mi)
    #pragma unroll
    for (int ni = 0; ni < 4; ++ni) {
      f32x4 z = {0.f, 0.f, 0.f, 0.f};
      acc[mi][ni] = z;
    }
  int rowq[2], segq[2], basep[2];
  #pragma unroll
  for (int q = 0; q < 2; ++q) {
    int idx = w * 128 + q * 64 + lane;
    rowq[q] = idx >> 2;
    segq[q] = (idx & 3) * 8;
    int n = n0 + rowq[q];
    int y = n / S, x = n % S;
    basep[q] = y * PW + x;
  }
  const ushort* inb = in + (size_t)b * (PW * PW) * CIN;

  for (int t = 0; t < 9; ++t) {
    const int offp = (t / 3) * PW + (t % 3);
    const ushort* wt = W9 + (size_t)t * 256 * CIN;
    for (int kc = 0; kc < CIN; kc += 32) {
      __syncthreads();
      #pragma unroll
      for (int q = 0; q < 2; ++q) {
        const ushort* srcA = wt + (size_t)(oc0 + rowq[q]) * CIN + kc + segq[q];
        const ushort* srcB = inb + (size_t)(basep[q] + offp) * CIN + kc + segq[q];
        char* dstA = (char*)&As[0][0] + w * 2048 + q * 1024;
        char* dstB = (char*)&Bs[0][0] + w * 2048 + q * 1024;
        __builtin_amdgcn_global_load_lds(
            (const __attribute__((address_space(1))) unsigned*)srcA,
            (__attribute__((address_space(3))) unsigned*)dstA, 16, 0, 0);
        __builtin_amdgcn_global_load_lds(
            (const __attribute__((address_space(1))) unsigned*)srcB,
            (__attribute__((address_space(3))) unsigned*)dstB, 16, 0, 0);
      }
      __syncthreads();
      bf16x8 af[4], bfv[4];
      #pragma unroll
      for (int mi = 0; mi < 4; ++mi)
        af[mi] = *(const bf16x8*)&As[wr * 64 + mi * 16 + (lane & 15)][(lane >> 4) * 8];
      #pragma unroll
      for (int ni = 0; ni < 4; ++ni)
        bfv[ni] = *(const bf16x8*)&Bs[wc * 64 + ni * 16 + (lane & 15)][(lane >> 4) * 8];
      #pragma unroll
      for (int mi = 0; mi < 4; ++mi)
        #pragma unroll
        for (int ni = 0; ni < 4; ++ni)
          acc[mi][ni] = __builtin_amdgcn_mfma_f32_16x16x32_bf16(
              af[mi], bfv[ni], acc[mi][ni], 0, 0, 0);
    }
  }
  if (OUT_NHWC) {
    float* outb = out + (size_t)b * (S * S) * 256;
    #pragma unroll
    for (int mi = 0; mi < 4; ++mi) {
      const int oc = oc0 + wr * 64 + mi * 16 + (lane >> 4) * 4;
      float4 bb = *(const float4*)(bias + oc);
      #pragma unroll
      for (int ni = 0; ni < 4; ++ni) {
        const int n = n0 + wc * 64 + ni * 16 + (lane & 15);
        float4 v;
        v.x = acc[mi][ni][0] + bb.x;
        v.y = acc[mi][ni][1] + bb.y;
        v.z = acc[mi][ni][2] + bb.z;
        v.w = acc[mi][ni][3] + bb.w;
        *(float4*)(outb + (size_t)n * 256 + oc) = v;
      }
    }
  } else {
    float* outb = out + (size_t)b * 256 * (S * S);
    #pragma unroll
    for (int mi = 0; mi < 4; ++mi) {
      #pragma unroll
      for (int r = 0; r < 4; ++r) {
        int oc = oc0 + wr * 64 + mi * 16 + (lane >> 4) * 4 + r;
        float bb = bias[oc];
        #pragma unroll
        for (int ni = 0; ni < 4; ++ni) {
          int n = n0 + wc * 64 + ni * 16 + (lane & 15);
          outb[(size_t)oc * (S * S) + n] = acc[mi][ni][r] + bb;
        }
      }
    }
  }
}

// ------ fusion 3x3 conv, CIN=512: pipelined 128x256 tile, BK=64 -------------
// T3+T4: triple-buffered LDS, counted vmcnt (never 0 in steady state).
// T2: XOR swizzle via pre-swizzled global src into linear-dest
// global_load_lds; same XOR on ds_read. T5: setprio around MFMA cluster.
// Round 2/3: register double-buffered fragments — phase p issues the
// ds_reads for phase p+1's fragments, then runs phase p's MFMA cluster on
// registers read last phase. lgkmcnt(0) after the cluster (cross-wave
// buffer-overwrite fence before the barrier); sched_barrier(0) pins the
// phase boundary (rule #18: hipcc can hoist reg-only MFMA past asm waits).
#define STAGE_CONV(s_, bi_)                                                    \
  {                                                                            \
    const int t_ = (s_) >> 3, kc_ = ((s_) & 7) << 6;                           \
    const ushort* wt_ = W9 + t_ * 131072 + kc_;                                \
    const ushort* ib_ = inb + ((t_ / 3) * 66 + (t_ % 3)) * 512 + kc_;          \
    _Pragma("unroll")                                                          \
    for (int q_ = 0; q_ < 2; ++q_) {                                           \
      __builtin_amdgcn_global_load_lds(                                        \
          (const __attribute__((address_space(1))) unsigned*)(wt_ + aInv[q_]), \
          (__attribute__((address_space(3))) unsigned*)                        \
              ((char*)lds + (bi_) * 16384 + (w * 16 + q_ * 8) * 128),          \
          16, 0, 0);                                                           \
    }                                                                          \
    _Pragma("unroll")                                                          \
    for (int q_ = 0; q_ < 4; ++q_) {                                           \
      __builtin_amdgcn_global_load_lds(                                        \
          (const __attribute__((address_space(1))) unsigned*)(ib_ + bInv[q_]), \
          (__attribute__((address_space(3))) unsigned*)                        \
              ((char*)lds + 49152 + (bi_) * 32768 + (w * 32 + q_ * 8) * 128),  \
          16, 0, 0);                                                           \
    }                                                                          \
  }

#define READ_FRAGS(rb_, AF_, BF_)                                              \
  {                                                                            \
    const ushort* As_ = lds + (rb_) * 8192 + (wm * 64 + c) * 64;               \
    const ushort* Bs_ = lds + 24576 + (rb_) * 16384 + (wn * 64 + c) * 64;      \
    _Pragma("unroll")                                                          \
    for (int mi_ = 0; mi_ < 4; ++mi_) {                                        \
      AF_[mi_][0] = *(const bf16x8*)(As_ + mi_ * 1024 + okh0);                 \
      AF_[mi_][1] = *(const bf16x8*)(As_ + mi_ * 1024 + okh1);                 \
    }                                                                          \
    _Pragma("unroll")                                                          \
    for (int ni_ = 0; ni_ < 4; ++ni_) {                                        \
      BF_[ni_][0] = *(const bf16x8*)(Bs_ + ni_ * 1024 + okh0);                 \
      BF_[ni_][1] = *(const bf16x8*)(Bs_ + ni_ * 1024 + okh1);                 \
    }                                                                          \
  }

#define MFMA_SET(AF_, BF_)                                                     \
  {                                                                            \
    __builtin_amdgcn_s_setprio(1);                                             \
    _Pragma("unroll")                                                          \
    for (int mi_ = 0; mi_ < 4; ++mi_)                                          \
      _Pragma("unroll")                                                        \
      for (int ni_ = 0; ni_ < 4; ++ni_) {                                      \
        acc[mi_][ni_] = __builtin_amdgcn_mfma_f32_16x16x32_bf16(               \
            AF_[mi_][0], BF_[ni_][0], acc[mi_][ni_], 0, 0, 0);                 \
        acc[mi_][ni_] = __builtin_amdgcn_mfma_f32_16x16x32_bf16(               \
            AF_[mi_][1], BF_[ni_][1], acc[mi_][ni_], 0, 0, 0);                 \
      }                                                                        \
    __builtin_amdgcn_s_setprio(0);                                             \
  }

#define PHASE_END(vm_)                                                         \
  {                                                                            \
    asm volatile("s_waitcnt lgkmcnt(0)" ::: "memory");                         \
    asm volatile("s_waitcnt vmcnt(" #vm_ ")" ::: "memory");                    \
    __builtin_amdgcn_sched_barrier(0);                                         \
    __builtin_amdgcn_s_barrier();                                              \
  }

__global__ __launch_bounds__(512, 2) void k_conv9_pipe(
    const ushort* __restrict__ in, const ushort* __restrict__ W9,
    const float* __restrict__ bias, float* __restrict__ out)
{
  const int n0 = blockIdx.x * 256, oc0 = blockIdx.y * 128, b = blockIdx.z;
  const int tid = threadIdx.x, lane = tid & 63, w = tid >> 6;
  const int wm = w >> 2, wn = w & 3;            // 2M x 4N waves, 64x64 each
  const int g = lane >> 4, c = lane & 15;
  // A bufs: 3 x [128][64] bf16 @ byte 0 ; B bufs: 3 x [256][64] bf16 @ 49152
  __shared__ __align__(16) ushort lds[73728];   // 144 KiB
  const ushort* inb = in + (size_t)b * 4356 * 512;

  // per-lane staging invariants (row owned by this lane per issue; source
  // column pre-XORed so linear LDS dest + XORed ds_read = conflict-free)
  const int l8 = lane >> 3, lx = lane & 7;
  int aInv[2], bInv[4];
  #pragma unroll
  for (int q = 0; q < 2; ++q) {
    const int row = w * 16 + q * 8 + l8;
    const int cx = (((lx << 4) ^ ((row & 7) << 4)) >> 1);
    aInv[q] = (oc0 + row) * 512 + cx;
  }
  #pragma unroll
  for (int q = 0; q < 4; ++q) {
    const int row = w * 32 + q * 8 + l8;
    const int n = n0 + row;
    const int y = n >> 6, x = n & 63;
    const int cx = (((lx << 4) ^ ((row & 7) << 4)) >> 1);
    bInv[q] = (y * 66 + x) * 512 + cx;
  }

  // fragment-read column terms: row&7 == c&7 for every mi/ni (mi*16, w*64
  // are 0 mod 8) -> single XOR term shared by all fragment reads
  const int sx = (c & 7) << 3;
  const int okh0 = (g * 8) ^ sx;
  const int okh1 = (32 + g * 8) ^ sx;

  f32x4 acc[4][4];
  #pragma unroll
  for (int mi = 0; mi < 4; ++mi)
    #pragma unroll
    for (int ni = 0; ni < 4; ++ni) {
      f32x4 z = {0.f, 0.f, 0.f, 0.f};
      acc[mi][ni] = z;
    }

  bf16x8 afE[4][2], bfE[4][2], afO[4][2], bfO[4][2];

  // prologue: stage 3 buffers; read frags(0) into E-set
  STAGE_CONV(0, 0);
  STAGE_CONV(1, 1);
  STAGE_CONV(2, 2);
  asm volatile("s_waitcnt vmcnt(12)" ::: "memory");   // stage(0) done
  __builtin_amdgcn_sched_barrier(0);
  __builtin_amdgcn_s_barrier();
  READ_FRAGS(0, afE, bfE);
  PHASE_END(6);                                       // stage(1) done

  int rb = 1;   // buffer holding frags for the NEXT phase
  for (int p = 0; p < 68; p += 2) {
    // phase p (even): load O-set for p+1, stage p+3, compute E-set
    READ_FRAGS(rb, afO, bfO);
    { int sb = rb + 2; if (sb >= 3) sb -= 3; STAGE_CONV(p + 3, sb); }
    MFMA_SET(afE, bfE);
    PHASE_END(6);
    ++rb; if (rb == 3) rb = 0;
    // phase p+1 (odd): load E-set for p+2, stage p+4, compute O-set
    READ_FRAGS(rb, afE, bfE);
    { int sb = rb + 2; if (sb >= 3) sb -= 3; STAGE_CONV(p + 4, sb); }
    MFMA_SET(afO, bfO);
    PHASE_END(6);
    ++rb; if (rb == 3) rb = 0;
  }
  // phase 68: read 69, stage 71, compute E
  READ_FRAGS(rb, afO, bfO);
  { int sb = rb + 2; if (sb >= 3) sb -= 3; STAGE_CONV(71, sb); }
  MFMA_SET(afE, bfE);
  PHASE_END(6);                                       // stage(70) done
  ++rb; if (rb == 3) rb = 0;
  // phase 69: read 70, compute O
  READ_FRAGS(rb, afE, bfE);
  MFMA_SET(afO, bfO);
  PHASE_END(0);                                       // stage(71) done
  ++rb; if (rb == 3) rb = 0;
  // phase 70: read 71, compute E
  READ_FRAGS(rb, afO, bfO);
  MFMA_SET(afE, bfE);
  asm volatile("s_waitcnt lgkmcnt(0)" ::: "memory");
  __builtin_amdgcn_sched_barrier(0);
  __builtin_amdgcn_s_barrier();
  // phase 71: compute O
  MFMA_SET(afO, bfO);

  // epilogue: NCHW fp32 + bias (same fragment convention as k_conv9_mfma)
  float* outb = out + (size_t)b * 1048576;
  #pragma unroll
  for (int mi = 0; mi < 4; ++mi) {
    const int oc = oc0 + wm * 64 + mi * 16 + g * 4;
    float4 bb = *(const float4*)(bias + oc);
    #pragma unroll
    for (int ni = 0; ni < 4; ++ni) {
      const int n = n0 + wn * 64 + ni * 16 + c;
      outb[(size_t)(oc + 0) * 4096 + n] = acc[mi][ni][0] + bb.x;
      outb[(size_t)(oc + 1) * 4096 + n] = acc[mi][ni][1] + bb.y;
      outb[(size_t)(oc + 2) * 4096 + n] = acc[mi][ni][2] + bb.z;
      outb[(size_t)(oc + 3) * 4096 + n] = acc[mi][ni][3] + bb.w;
    }
  }
}

// ---- P4: bilinear x2 upsample + residual -> fused_pad[.., ch 0:256] --------
__global__ __launch_bounds__(256) void k_upsample_nhwc(
    const float* __restrict__ xpos, const float* __restrict__ opc,
    const float* __restrict__ gamma, ushort* __restrict__ fused)
{
  const int t = blockIdx.x * 256 + threadIdx.x;  // 8*4096*64
  const int c = (t & 63) * 4;
  const int pix = (t >> 6) & 4095;
  const int b = t >> 18;
  const int y = pix >> 6, xx = pix & 63;
  const int my = y >> 1;
  const int y0 = (y & 1) ? my : my - 1;
  const float fy = (y & 1) ? 0.25f : 0.75f;
  const int mx = xx >> 1;
  const int x0 = (xx & 1) ? mx : mx - 1;
  const float fx = (xx & 1) ? 0.25f : 0.75f;
  const int y0c = max(y0, 0), y1c = min(y0 + 1, 31);
  const int x0c = max(x0, 0), x1c = min(x0 + 1, 31);
  const float* base = opc + (size_t)b * 1024 * 256 + c;
  float4 v00 = *(const float4*)(base + (size_t)(y0c * 32 + x0c) * 256);
  float4 v01 = *(const float4*)(base + (size_t)(y0c * 32 + x1c) * 256);
  float4 v10 = *(const float4*)(base + (size_t)(y1c * 32 + x0c) * 256);
  float4 v11 = *(const float4*)(base + (size_t)(y1c * 32 + x1c) * 256);
  const float w00 = (1.f - fy) * (1.f - fx), w01 = (1.f - fy) * fx;
  const float w10 = fy * (1.f - fx), w11 = fy * fx;
  const float g = gamma[0];
  const float* xr = xpos + ((size_t)b * 256 + c) * 4096 + pix;
  union { ushort u[4]; uint2 q; } o;
  o.u[0] = f2bf(xr[0]          + g * (w00 * v00.x + w01 * v01.x + w10 * v10.x + w11 * v11.x));
  o.u[1] = f2bf(xr[4096]       + g * (w00 * v00.y + w01 * v01.y + w10 * v10.y + w11 * v11.y));
  o.u[2] = f2bf(xr[2 * 4096]   + g * (w00 * v00.z + w01 * v01.z + w10 * v10.z + w11 * v11.z));
  o.u[3] = f2bf(xr[3 * 4096]   + g * (w00 * v00.w + w01 * v01.w + w10 * v10.w + w11 * v11.w));
  *(uint2*)(fused + ((size_t)b * 4356 + (y + 1) * 66 + (xx + 1)) * 512 + c) = o.q;
}

// ------- C0: CHA q/k/v grouped 2x2 projections -> bf16 (half-batch) ---------
__global__ __launch_bounds__(256) void k_cha_proj(
    const float* __restrict__ x,
    const float* __restrict__ Wq, const float* __restrict__ bq,
    const float* __restrict__ Wk, const float* __restrict__ bk,
    const float* __restrict__ Wv, const float* __restrict__ bv,
    ushort* __restrict__ Qc, ushort* __restrict__ Kc, ushort* __restrict__ Vt)
{
  const int t = blockIdx.x * 256 + threadIdx.x;
  const int bl = t >> 16;
  const int g  = (t >> 8) & 255;
  const int lq = t & 255;
  const int i = lq >> 3, j4 = (lq & 7) << 2;
  const float* xb = x + (((size_t)bl * 256 + g) << 12) + (2 * i) * 64 + 2 * j4;
  union { float4 v[2]; float f[8]; } xr0, xr1;
  xr0.v[0] = *(const float4*)(xb);
  xr0.v[1] = *(const float4*)(xb + 4);
  xr1.v[0] = *(const float4*)(xb + 64);
  xr1.v[1] = *(const float4*)(xb + 68);
  const int bhl = bl * 8 + (g >> 5);
  const int c2b = (g & 31) * 8;
  const int l0 = i * 32 + j4;
  #pragma unroll
  for (int h = 0; h < 8; ++h) {
    float4 w4 = *(const float4*)(Wq + g * 32 + h * 4);
    float bb = bq[g * 8 + h];
    union { ushort u[4]; uint2 q; } o;
    #pragma unroll
    for (int jj = 0; jj < 4; ++jj) {
      float v = xr0.f[2 * jj] * w4.x + xr0.f[2 * jj + 1] * w4.y
              + xr1.f[2 * jj] * w4.z + xr1.f[2 * jj + 1] * w4.w + bb;
      o.u[jj] = f2bf(v * 0.03125f);
    }
    *(uint2*)(Qc + (((size_t)bhl * 256 + c2b + h) << 10) + l0) = o.q;
  }
  #pragma unroll
  for (int h = 0; h < 8; ++h) {
    float4 w4 = *(const float4*)(Wk + g * 32 + h * 4);
    float bb = bk[g * 8 + h];
    union { ushort u[4]; uint2 q; } o;
    #pragma unroll
    for (int jj = 0; jj < 4; ++jj) {
      float v = xr0.f[2 * jj] * w4.x + xr0.f[2 * jj + 1] * w4.y
              + xr1.f[2 * jj] * w4.z + xr1.f[2 * jj + 1] * w4.w + bb;
      o.u[jj] = f2bf(v);
    }
    *(uint2*)(Kc + (((size_t)bhl * 256 + c2b + h) << 10) + l0) = o.q;
  }
  ushort vo[4][8];
  #pragma unroll
  for (int h = 0; h < 8; ++h) {
    float4 w4 = *(const float4*)(Wv + g * 32 + h * 4);
    float bb = bv[g * 8 + h];
    #pragma unroll
    for (int jj = 0; jj < 4; ++jj) {
      float v = xr0.f[2 * jj] * w4.x + xr0.f[2 * jj + 1] * w4.y
              + xr1.f[2 * jj] * w4.z + xr1.f[2 * jj + 1] * w4.w + bb;
      vo[jj][h] = f2bf(v);
    }
  }
  #pragma unroll
  for (int jj = 0; jj < 4; ++jj)
    *(uint4*)(Vt + ((size_t)bhl << 18) + (size_t)(l0 + jj) * 256 + c2b) =
        *(uint4*)&vo[jj][0];
}

// ------- C1: scores = qc @ kc^T, bf16 MFMA, K=1024 (half-batch) -------------
__global__ __launch_bounds__(256) void k_cha_scores_mfma(
    const ushort* __restrict__ Qc, const ushort* __restrict__ Kc,
    float* __restrict__ S)
{
  const int c0 = blockIdx.x * 128, d0 = blockIdx.y * 128, bhl = blockIdx.z;
  const int tid = threadIdx.x, lane = tid & 63, w = tid >> 6;
  __shared__ ushort As[128][32], Bs[128][32];
  const ushort* Ab = Qc + ((size_t)bhl * 256 + c0) * 1024;
  const ushort* Bb = Kc + ((size_t)bhl * 256 + d0) * 1024;
  const int wr = w >> 1, wc = w & 1;
  f32x4 acc[4][4];
  #pragma unroll
  for (int mi = 0; mi < 4; ++mi)
    #pragma unroll
    for (int ni = 0; ni < 4; ++ni) {
      f32x4 z = {0.f, 0.f, 0.f, 0.f};
      acc[mi][ni] = z;
    }
  for (int kc = 0; kc < 1024; kc += 32) {
    __syncthreads();
    #pragma unroll
    for (int q = 0; q < 2; ++q) {
      int idx = w * 128 + q * 64 + lane;
      int row = idx >> 2, seg = idx & 3;
      const ushort* srcA = Ab + (size_t)row * 1024 + kc + seg * 8;
      const ushort* srcB = Bb + (size_t)row * 1024 + kc + seg * 8;
      char* dstA = (char*)&As[0][0] + w * 2048 + q * 1024;
      char* dstB = (char*)&Bs[0][0] + w * 2048 + q * 1024;
      __builtin_amdgcn_global_load_lds(
          (const __attribute__((address_space(1))) unsigned*)srcA,
          (__attribute__((address_space(3))) unsigned*)dstA, 16, 0, 0);
      __builtin_amdgcn_global_load_lds(
          (const __attribute__((address_space(1))) unsigned*)srcB,
          (__attribute__((address_space(3))) unsigned*)dstB, 16, 0, 0);
    }
    __syncthreads();
    bf16x8 af[4], bfv[4];
    #pragma unroll
    for (int mi = 0; mi < 4; ++mi)
      af[mi] = *(const bf16x8*)&As[wr * 64 + mi * 16 + (lane & 15)][(lane >> 4) * 8];
    #pragma unroll
    for (int ni = 0; ni < 4; ++ni)
      bfv[ni] = *(const bf16x8*)&Bs[wc * 64 + ni * 16 + (lane & 15)][(lane >> 4) * 8];
    #pragma unroll
    for (int mi = 0; mi < 4; ++mi)
      #pragma unroll
      for (int ni = 0; ni < 4; ++ni)
        acc[mi][ni] = __builtin_amdgcn_mfma_f32_16x16x32_bf16(
            af[mi], bfv[ni], acc[mi][ni], 0, 0, 0);
  }
  float* Sb = S + ((size_t)bhl << 16);
  #pragma unroll
  for (int mi = 0; mi < 4; ++mi)
    #pragma unroll
    for (int r = 0; r < 4; ++r) {
      int c = c0 + wr * 64 + mi * 16 + (lane >> 4) * 4 + r;
      #pragma unroll
      for (int ni = 0; ni < 4; ++ni) {
        int d = d0 + wc * 64 + ni * 16 + (lane & 15);
        Sb[(size_t)c * 256 + d] = acc[mi][ni][r];
      }
    }
}

// ------- C2: row softmax over 256 -> bf16 P ---------------------------------
__global__ __launch_bounds__(256) void k_softmax_p(
    const float* __restrict__ S, ushort* __restrict__ P)
{
  const int row = blockIdx.x * 4 + (threadIdx.x >> 6);
  const int lane = threadIdx.x & 63;
  const float* r = S + (size_t)row * 256;
  float4 v = *(const float4*)(r + lane * 4);
  float m = fmaxf(fmaxf(v.x, v.y), fmaxf(v.z, v.w));
  #pragma unroll
  for (int off = 32; off; off >>= 1) m = fmaxf(m, __shfl_xor(m, off, 64));
  v.x = __expf(v.x - m); v.y = __expf(v.y - m);
  v.z = __expf(v.z - m); v.w = __expf(v.w - m);
  float s = v.x + v.y + v.z + v.w;
  #pragma unroll
  for (int off = 32; off; off >>= 1) s += __shfl_xor(s, off, 64);
  const float inv = 1.f / s;
  union { ushort u[4]; uint2 q; } o;
  o.u[0] = f2bf(v.x * inv); o.u[1] = f2bf(v.y * inv);
  o.u[2] = f2bf(v.z * inv); o.u[3] = f2bf(v.w * inv);
  *(uint2*)(P + (size_t)row * 256 + lane * 4) = o.q;
}

// -- C3: oc = P @ vcT (MFMA) + grouped ConvT + residual -> fused_pad NHWC ----
__global__ __launch_bounds__(256) void k_cha_pv(
    const ushort* __restrict__ P, const ushort* __restrict__ Vt,
    const float* __restrict__ x,
    const float* __restrict__ Wt, const float* __restrict__ bt,
    const float* __restrict__ gamma, ushort* __restrict__ fused, int bbase)
{
  const int n0 = blockIdx.x * 128, c0 = blockIdx.y * 128, bhl = blockIdx.z;
  const int b = bbase + (bhl >> 3), h = bhl & 7;
  const int tid = threadIdx.x, lane = tid & 63, w = tid >> 6;
  __shared__ ushort As[128][32], Bs[128][32];
  __shared__ ushort Ot[512][16];
  __shared__ float wt_s[16][32];
  __shared__ float bt_s[16];
  const int gp_base = h * 32 + (c0 >> 3);
  {
    int e = tid;
    wt_s[e >> 5][e & 31] = Wt[(size_t)gp_base * 32 + e];
    e += 256;
    wt_s[e >> 5][e & 31] = Wt[(size_t)gp_base * 32 + e];
    if (tid < 16) bt_s[tid] = bt[gp_base + tid];
  }
  const ushort* Ab = P + (((size_t)bhl << 8) + c0) * 256;
  const ushort* Bb = Vt + ((size_t)bhl << 18) + (size_t)n0 * 256;
  const int wr = w >> 1, wc = w & 1;
  f32x4 acc[4][4];
  #pragma unroll
  for (int mi = 0; mi < 4; ++mi)
    #pragma unroll
    for (int ni = 0; ni < 4; ++ni) {
      f32x4 z = {0.f, 0.f, 0.f, 0.f};
      acc[mi][ni] = z;
    }
  for (int kc = 0; kc < 256; kc += 32) {
    __syncthreads();
    #pragma unroll
    for (int q = 0; q < 2; ++q) {
      int idx = w * 128 + q * 64 + lane;
      int row = idx >> 2, seg = idx & 3;
      const ushort* srcA = Ab + (size_t)row * 256 + kc + seg * 8;
      const ushort* srcB = Bb + (size_t)row * 256 + kc + seg * 8;
      char* dstA = (char*)&As[0][0] + w * 2048 + q * 1024;
      char* dstB = (char*)&Bs[0][0] + w * 2048 + q * 1024;
      __builtin_amdgcn_global_load_lds(
          (const __attribute__((address_space(1))) unsigned*)srcA,
          (__attribute__((address_space(3))) unsigned*)dstA, 16, 0, 0);
      __builtin_amdgcn_global_load_lds(
          (const __attribute__((address_space(1))) unsigned*)srcB,
          (__attribute__((address_space(3))) unsigned*)dstB, 16, 0, 0);
    }
    __syncthreads();
    bf16x8 af[4], bfv[4];
    #pragma unroll
    for (int mi = 0; mi < 4; ++mi)
      af[mi] = *(const bf16x8*)&As[wr * 64 + mi * 16 + (lane & 15)][(lane >> 4) * 8];
    #pragma unroll
    for (int ni = 0; ni < 4; ++ni)
      bfv[ni] = *(const bf16x8*)&Bs[wc * 64 + ni * 16 + (lane & 15)][(lane >> 4) * 8];
    #pragma unroll
    for (int mi = 0; mi < 4; ++mi)
      #pragma unroll
      for (int ni = 0; ni < 4; ++ni)
        acc[mi][ni] = __builtin_amdgcn_mfma_f32_16x16x32_bf16(
            af[mi], bfv[ni], acc[mi][ni], 0, 0, 0);
  }
  const float gm = gamma[0];
  const int col = lane & 15, q = lane >> 4;
  #pragma unroll
  for (int mi = 0; mi < 4; ++mi) {
    const int gloc = wr * 8 + mi * 2 + (q >> 1);
    const int gp = gp_base + gloc;
    const float btv = bt_s[gloc];
    #pragma unroll
    for (int ni = 0; ni < 4; ++ni) {
      float pa[4] = {0.f, 0.f, 0.f, 0.f};
      #pragma unroll
      for (int r = 0; r < 4; ++r) {
        const int i2 = (q & 1) * 4 + r;
        const float a = acc[mi][ni][r];
        pa[0] += a * wt_s[gloc][i2 * 4 + 0];
        pa[1] += a * wt_s[gloc][i2 * 4 + 1];
        pa[2] += a * wt_s[gloc][i2 * 4 + 2];
        pa[3] += a * wt_s[gloc][i2 * 4 + 3];
      }
      float v0 = pa[0] + __shfl_xor(pa[0], 16, 64);
      float v1 = pa[1] + __shfl_xor(pa[1], 16, 64);
      float v2 = pa[2] + __shfl_xor(pa[2], 16, 64);
      float v3 = pa[3] + __shfl_xor(pa[3], 16, 64);
      const int lloc = wc * 64 + ni * 16 + col;
      const int l = n0 + lloc;
      const int p = l >> 5, j = l & 31;
      const int y = 2 * p + (q & 1);
      const float va = (q & 1) ? v2 : v0;
      const float vb = (q & 1) ? v3 : v1;
      const float* xc = x + (((size_t)b * 256 + gp) << 12) + (y << 6) + 2 * j;
      const int lp = (lloc << 2) + (q & 1) * 2;
      Ot[lp][gloc]     = f2bf(xc[0] + gm * (va + btv));
      Ot[lp + 1][gloc] = f2bf(xc[1] + gm * (vb + btv));
    }
  }
  __syncthreads();
  #pragma unroll
  for (int pp2 = 0; pp2 < 2; ++pp2) {
    const int pixl = tid * 2 + pp2;
    const int lloc = pixl >> 2;
    const int l = n0 + lloc;
    const int p = l >> 5, j = l & 31;
    const int yy = 2 * p + ((pixl >> 1) & 1) + 1;
    const int xx = 2 * j + (pixl & 1) + 1;
    const uint4* src = (const uint4*)&Ot[pixl][0];
    uint4* dst = (uint4*)(fused + ((size_t)b * 4356 + yy * 66 + xx) * 512 + 256 + gp_base);
    dst[0] = src[0];
    dst[1] = src[1];
  }
}

extern "C" void kernel_launch(void* const* d_in, const int* in_sizes, int n_in,
                              void* d_out, int out_size, void* d_ws, size_t ws_size,
                              hipStream_t stream)
{
  (void)in_sizes; (void)n_in; (void)out_size; (void)ws_size;
  const float* qkv_pos   = (const float*)d_in[0];
  const float* qkv_cha   = (const float*)d_in[1];
  const float* Wq_pos    = (const float*)d_in[2];
  const float* bq_pos    = (const float*)d_in[3];
  const float* Wk_pos    = (const float*)d_in[4];
  const float* bk_pos    = (const float*)d_in[5];
  const float* Wv_pos    = (const float*)d_in[6];
  const float* bv_pos    = (const float*)d_in[7];
  const float* Wo_pos    = (const float*)d_in[8];
  const float* bo_pos    = (const float*)d_in[9];
  const float* gamma_pos = (const float*)d_in[10];
  const float* Wq_cha    = (const float*)d_in[11];
  const float* bq_cha    = (const float*)d_in[12];
  const float* Wk_cha    = (const float*)d_in[13];
  const float* bk_cha    = (const float*)d_in[14];
  const float* Wv_cha    = (const float*)d_in[15];
  const float* bv_cha    = (const float*)d_in[16];
  const float* Wt_cha    = (const float*)d_in[17];
  const float* bt_cha    = (const float*)d_in[18];
  const float* gamma_cha = (const float*)d_in[19];
  const float* Wf        = (const float*)d_in[20];
  const float* bf        = (const float*)d_in[21];
  float* out = (float*)d_out;

  float* ws = (float*)d_ws;
  ushort* Wpf9    = (ushort*)ws;
  ushort* Wpo9    = (ushort*)(ws + 589824);
  // POS scratch
  ushort* Qb      = (ushort*)(ws + 884736);    // [64][1024][32] bf16
  ushort* Kb      = (ushort*)(ws + 1933312);   // [64][1024][32] bf16
  ushort* Vtb     = (ushort*)(ws + 2981888);   // [64][32][1024] bf16
  ushort* op_pad  = (ushort*)(ws + 4030464);   // 2367488 ushorts
  float*  op_conv = ws + 5214208;              // NHWC fp32 [8][1024][256]
  ushort* Ap      = (ushort*)(ws + 7311360);   // [8][1024][1024] bf16
  // CHA scratch (aliases POS region after it is consumed)
  ushort* qcb     = (ushort*)(ws + 884736);
  ushort* kcb     = (ushort*)(ws + 5079040);
  ushort* vcT     = (ushort*)(ws + 9273344);
  float*  attn_c  = ws + 13467648;
  ushort* Pb      = (ushort*)(ws + 15564800);
  ushort* fusedb  = (ushort*)(ws + 16613376);  // NHWC padded [8][66*66][512]
  ushort* Wqkvp   = (ushort*)(ws + 25534464);  // [384][1024] bf16

  // zero padded buffers (conv borders) and Qb (hd pad lanes 8..31 must be 0)
  hipMemsetAsync(op_pad, 0, (size_t)2367488 * 2, stream);
  hipMemsetAsync(fusedb, 0, (size_t)17842176 * 2, stream);
  hipMemsetAsync(Qb, 0, (size_t)2097152 * 2, stream);
  // weight pre-packs
  k_prepack9<512><<<dim3(4608), 256, 0, stream>>>(Wf, Wpf9);
  k_prepack9<256><<<dim3(2304), 256, 0, stream>>>(Wo_pos, Wpo9);
  k_cast_wqkv<<<dim3(1536), 256, 0, stream>>>(Wq_pos, Wk_pos, Wv_pos, Wqkvp);
  // POS branch
  k_pack_pos<<<dim3(2048), 256, 0, stream>>>(qkv_pos, Ap);
  k_pos_qkv_mfma<<<dim3(8, 3, 8), 256, 0, stream>>>(Ap, Wqkvp,
      bq_pos, bk_pos, bv_pos, Qb, Kb, Vtb);
  k_pos_flash<<<dim3(8, 8, 8), 256, 0, stream>>>(Qb, Kb, Vtb, op_pad);
  k_conv9_mfma<256, 32, 34, 1><<<dim3(8, 2, 8), 256, 0, stream>>>(
      op_pad, Wpo9, bo_pos, op_conv);
  k_upsample_nhwc<<<dim3(8192), 256, 0, stream>>>(qkv_pos, op_conv, gamma_pos, fusedb);
  // CHA branch, two half-batches
  for (int half = 0; half < 2; ++half) {
    const float* xh = qkv_cha + (size_t)half * 4 * 256 * 4096;
    k_cha_proj<<<dim3(1024), 256, 0, stream>>>(xh, Wq_cha, bq_cha,
        Wk_cha, bk_cha, Wv_cha, bv_cha, qcb, kcb, vcT);
    k_cha_scores_mfma<<<dim3(2, 2, 32), 256, 0, stream>>>(qcb, kcb, attn_c);
    k_softmax_p<<<dim3(2048), 256, 0, stream>>>(attn_c, Pb);
    k_cha_pv<<<dim3(8, 2, 32), 256, 0, stream>>>(Pb, vcT, qkv_cha,
        Wt_cha, bt_cha, gamma_cha, fusedb, half * 4);
  }
  // fusion conv: pipelined 128x256 tile, reg-dbuf frags, 256 blocks = 1/CU
  k_conv9_pipe<<<dim3(16, 2, 8), 512, 0, stream>>>(fusedb, Wpf9, bf, out);
}

// Round 4
// 538.765 us; speedup vs baseline: 1.0717x; 1.0205x over previous
//
#include <hip/hip_runtime.h>
#include <math.h>

// Shapes: B=8, C=256, H=W=64, HQ=WQ=32, L=1024, NH=8, hd=8, dv=32
//
// Workspace (float units):
//   Wpf9 bf16[9][256][512] @ 0        (589824 f)
//   Wpo9 bf16[9][256][256] @ 589824   (294912 f)
//   region2 @ 884736 (POS scratch, later aliased by CHA scratch)
//   fused_pad bf16[8][66*66][512] @ 16613376 (8921088 f)
//   Wqkv_p bf16[384][1024] @ 25534464 (196608 f)

typedef __attribute__((ext_vector_type(8))) short bf16x8;
typedef __attribute__((ext_vector_type(4))) float f32x4;

__device__ __forceinline__ ushort f2bf(float f) {
  union { float f; unsigned u; } v; v.f = f;
  unsigned r = (v.u + 0x7FFFu + ((v.u >> 16) & 1u)) >> 16;
  return (ushort)r;
}

// -------- weight pre-pack: W[oc][cin][3][3] fp32 -> [t][oc][cin] bf16 -------
template <int CIN>
__global__ __launch_bounds__(256) void k_prepack9(
    const float* __restrict__ W, ushort* __restrict__ out)
{
  const int i = blockIdx.x * 256 + threadIdx.x;   // over 9*256*CIN
  const int t = i / (256 * CIN);
  const int r = i - t * (256 * CIN);
  const int oc = r / CIN;
  const int c = r - oc * CIN;
  out[i] = f2bf(W[((size_t)oc * CIN + c) * 9 + t]);
}

// -------- concat Wq/Wk/Wv -> bf16 [384][1024] -------------------------------
__global__ __launch_bounds__(256) void k_cast_wqkv(
    const float* __restrict__ Wq, const float* __restrict__ Wk,
    const float* __restrict__ Wv, ushort* __restrict__ out)
{
  const int i = blockIdx.x * 256 + threadIdx.x;   // over 384*1024
  const int o = i >> 10, k = i & 1023;
  float v;
  if (o < 64)       v = Wq[(size_t)o * 1024 + k];
  else if (o < 128) v = Wk[(size_t)(o - 64) * 1024 + k];
  else              v = Wv[(size_t)(o - 128) * 1024 + k];
  out[i] = f2bf(v);
}

// -------- zero the 66x66 border ring of fused_pad (interior fully written) --
__global__ __launch_bounds__(256) void k_zero_border(ushort* __restrict__ fused)
{
  const int t = blockIdx.x * 256 + threadIdx.x;   // 8*260*64 = 133120 threads
  const int e = t & 63;            // uint4 slot within pixel (64 x 8 ushorts)
  const int pi = (t >> 6) % 260;   // ring pixel index
  const int b = t / 16640;         // 260*64
  int y, x;
  if (pi < 66)       { y = 0;            x = pi; }
  else if (pi < 132) { y = 65;           x = pi - 66; }
  else if (pi < 196) { y = pi - 132 + 1; x = 0; }
  else               { y = pi - 196 + 1; x = 65; }
  uint4 z = {0u, 0u, 0u, 0u};
  *(uint4*)(fused + ((size_t)b * 4356 + y * 66 + x) * 512 + e * 8) = z;
}

// -------- patchify x (2x2 stride-2 im2col) -> bf16 Ap[b][l][1024] -----------
__global__ __launch_bounds__(256) void k_pack_pos(
    const float* __restrict__ x, ushort* __restrict__ Ap)
{
  const int t = blockIdx.x * 256 + threadIdx.x;   // 524288 threads
  const int j4 = t & 7;          // group of 4 output cols
  const int i  = (t >> 3) & 31;  // output row
  const int c  = (t >> 8) & 255;
  const int b  = t >> 16;
  const float* xb = x + (((size_t)b * 256 + c) << 12) + (2 * i) * 64 + 8 * j4;
  union { float4 v[2]; float f[8]; } r0, r1;
  r0.v[0] = *(const float4*)(xb);
  r0.v[1] = *(const float4*)(xb + 4);
  r1.v[0] = *(const float4*)(xb + 64);
  r1.v[1] = *(const float4*)(xb + 68);
  #pragma unroll
  for (int jj = 0; jj < 4; ++jj) {
    const int l = i * 32 + j4 * 4 + jj;
    union { ushort u[4]; uint2 d; } pk;
    pk.u[0] = f2bf(r0.f[2 * jj]);
    pk.u[1] = f2bf(r0.f[2 * jj + 1]);
    pk.u[2] = f2bf(r1.f[2 * jj]);
    pk.u[3] = f2bf(r1.f[2 * jj + 1]);
    *(uint2*)(Ap + ((((size_t)b << 10) + l) << 10) + c * 4) = pk.d;
  }
}

// ---- P1: POS q/k/v projection as bf16 MFMA GEMM [384x1024]x[1024xL] --------
__global__ __launch_bounds__(256) void k_pos_qkv_mfma(
    const ushort* __restrict__ Ap, const ushort* __restrict__ Wqkv,
    const float* __restrict__ bq, const float* __restrict__ bk,
    const float* __restrict__ bv,
    ushort* __restrict__ Qb, ushort* __restrict__ Kb, ushort* __restrict__ Vtb)
{
  const int n0 = blockIdx.x * 128, oc0 = blockIdx.y * 128, b = blockIdx.z;
  const int tid = threadIdx.x, lane = tid & 63, w = tid >> 6;
  __shared__ ushort As[128][32], Bs[128][32];
  const ushort* Abw = Wqkv + (size_t)oc0 * 1024;
  const ushort* Bb  = Ap + (((size_t)b << 10) + n0) * 1024;
  const int wr = w >> 1, wc = w & 1;
  f32x4 acc[4][4];
  #pragma unroll
  for (int mi = 0; mi < 4; ++mi)
    #pragma unroll
    for (int ni = 0; ni < 4; ++ni) {
      f32x4 z = {0.f, 0.f, 0.f, 0.f};
      acc[mi][ni] = z;
    }
  for (int kc = 0; kc < 1024; kc += 32) {
    __syncthreads();
    #pragma unroll
    for (int q = 0; q < 2; ++q) {
      int idx = w * 128 + q * 64 + lane;
      int row = idx >> 2, seg = idx & 3;
      const ushort* srcA = Abw + (size_t)row * 1024 + kc + seg * 8;
      const ushort* srcB = Bb + (size_t)row * 1024 + kc + seg * 8;
      char* dstA = (char*)&As[0][0] + w * 2048 + q * 1024;
      char* dstB = (char*)&Bs[0][0] + w * 2048 + q * 1024;
      __builtin_amdgcn_global_load_lds(
          (const __attribute__((address_space(1))) unsigned*)srcA,
          (__attribute__((address_space(3))) unsigned*)dstA, 16, 0, 0);
      __builtin_amdgcn_global_load_lds(
          (const __attribute__((address_space(1))) unsigned*)srcB,
          (__attribute__((address_space(3))) unsigned*)dstB, 16, 0, 0);
    }
    __syncthreads();
    bf16x8 af[4], bfv[4];
    #pragma unroll
    for (int mi = 0; mi < 4; ++mi)
      af[mi] = *(const bf16x8*)&As[wr * 64 + mi * 16 + (lane & 15)][(lane >> 4) * 8];
    #pragma unroll
    for (int ni = 0; ni < 4; ++ni)
      bfv[ni] = *(const bf16x8*)&Bs[wc * 64 + ni * 16 + (lane & 15)][(lane >> 4) * 8];
    #pragma unroll
    for (int mi = 0; mi < 4; ++mi)
      #pragma unroll
      for (int ni = 0; ni < 4; ++ni)
        acc[mi][ni] = __builtin_amdgcn_mfma_f32_16x16x32_bf16(
            af[mi], bfv[ni], acc[mi][ni], 0, 0, 0);
  }
  // epilogue: scatter into flash layouts (Q scaled, bias added)
  #pragma unroll
  for (int mi = 0; mi < 4; ++mi) {
    const int oc = oc0 + wr * 64 + mi * 16 + (lane >> 4) * 4;  // mult of 4
    if (oc >= 384) continue;
    if (oc < 64) {
      const int hh = oc >> 3, e = oc & 7;
      float4 bb = *(const float4*)(bq + oc);
      #pragma unroll
      for (int ni = 0; ni < 4; ++ni) {
        const int l = n0 + wc * 64 + ni * 16 + (lane & 15);
        union { ushort u[4]; uint2 d; } pk;
        pk.u[0] = f2bf((acc[mi][ni][0] + bb.x) * 0.35355339059327373f);
        pk.u[1] = f2bf((acc[mi][ni][1] + bb.y) * 0.35355339059327373f);
        pk.u[2] = f2bf((acc[mi][ni][2] + bb.z) * 0.35355339059327373f);
        pk.u[3] = f2bf((acc[mi][ni][3] + bb.w) * 0.35355339059327373f);
        *(uint2*)(Qb + (((((size_t)b * 8 + hh) << 10) + l) << 5) + e) = pk.d;
      }
    } else if (oc < 128) {
      const int o2 = oc - 64, hh = o2 >> 3, e = o2 & 7;
      float4 bb = *(const float4*)(bk + o2);
      #pragma unroll
      for (int ni = 0; ni < 4; ++ni) {
        const int l = n0 + wc * 64 + ni * 16 + (lane & 15);
        union { ushort u[4]; uint2 d; } pk;
        pk.u[0] = f2bf(acc[mi][ni][0] + bb.x);
        pk.u[1] = f2bf(acc[mi][ni][1] + bb.y);
        pk.u[2] = f2bf(acc[mi][ni][2] + bb.z);
        pk.u[3] = f2bf(acc[mi][ni][3] + bb.w);
        *(uint2*)(Kb + (((((size_t)b * 8 + hh) << 10) + l) << 5) + e) = pk.d;
      }
    } else {
      const int o2 = oc - 128, hh = o2 >> 5, dd = o2 & 31;
      float4 bb = *(const float4*)(bv + o2);
      #pragma unroll
      for (int ni = 0; ni < 4; ++ni) {
        const int l = n0 + wc * 64 + ni * 16 + (lane & 15);
        ushort* vb = Vtb + ((((size_t)b * 8 + hh) * 32 + dd) << 10) + l;
        vb[0]      = f2bf(acc[mi][ni][0] + bb.x);
        vb[1024]   = f2bf(acc[mi][ni][1] + bb.y);
        vb[2048]   = f2bf(acc[mi][ni][2] + bb.z);
        vb[3072]   = f2bf(acc[mi][ni][3] + bb.w);
      }
    }
  }
}

// ---- P2: flash POS attention, bf16 MFMA, no barriers -----------------------
__global__ __launch_bounds__(256) void k_pos_flash(
    const ushort* __restrict__ Qb, const ushort* __restrict__ Kb,
    const ushort* __restrict__ Vtb, ushort* __restrict__ op_pad)
{
  const int qt = blockIdx.x, h = blockIdx.y, b = blockIdx.z;
  const int bh = b * 8 + h;
  const int tid = threadIdx.x, lane = tid & 63, wq = tid >> 6;
  const int c = lane & 15, g = lane >> 4;
  __shared__ __align__(16) ushort Ps[4][32][72];   // wave-private P tiles
  const int qbase = qt * 128 + wq * 32;
  bf16x8 qf[2];
  #pragma unroll
  for (int nt = 0; nt < 2; ++nt)
    qf[nt] = *(const bf16x8*)(Qb + (((size_t)bh << 10) + qbase + nt * 16 + c) * 32 + g * 8);
  f32x4 o[2][2];
  #pragma unroll
  for (int mt = 0; mt < 2; ++mt)
    #pragma unroll
    for (int nt = 0; nt < 2; ++nt) {
      f32x4 z = {0.f, 0.f, 0.f, 0.f};
      o[mt][nt] = z;
    }
  float m[2] = {-1e30f, -1e30f}, l[2] = {0.f, 0.f};
  const ushort* Kbh = Kb + ((size_t)bh << 15);
  const ushort* Vbh = Vtb + ((size_t)bh << 15);

  for (int kt = 0; kt < 16; ++kt) {
    const int kb0 = kt * 64;
    bf16x8 kf[4];
    #pragma unroll
    for (int mt = 0; mt < 4; ++mt)
      kf[mt] = *(const bf16x8*)(Kbh + (size_t)(kb0 + mt * 16 + c) * 32 + g * 8);
    f32x4 s[4][2];
    #pragma unroll
    for (int mt = 0; mt < 4; ++mt)
      #pragma unroll
      for (int nt = 0; nt < 2; ++nt) {
        f32x4 z = {0.f, 0.f, 0.f, 0.f};
        s[mt][nt] = __builtin_amdgcn_mfma_f32_16x16x32_bf16(kf[mt], qf[nt], z, 0, 0, 0);
      }
    #pragma unroll
    for (int nt = 0; nt < 2; ++nt) {
      float tmax = -1e30f;
      #pragma unroll
      for (int mt = 0; mt < 4; ++mt)
        #pragma unroll
        for (int r = 0; r < 4; ++r)
          tmax = fmaxf(tmax, s[mt][nt][r]);
      tmax = fmaxf(tmax, __shfl_xor(tmax, 16, 64));
      tmax = fmaxf(tmax, __shfl_xor(tmax, 32, 64));
      const float mn = fmaxf(m[nt], tmax);
      const float alpha = __expf(m[nt] - mn);
      m[nt] = mn;
      float rs = 0.f;
      #pragma unroll
      for (int mt = 0; mt < 4; ++mt) {
        union { ushort u[4]; uint2 d; } pk;
        #pragma unroll
        for (int r = 0; r < 4; ++r) {
          float p = __expf(s[mt][nt][r] - mn);
          rs += p;
          pk.u[r] = f2bf(p);
        }
        *(uint2*)&Ps[wq][nt * 16 + c][mt * 16 + g * 4] = pk.d;
      }
      rs += __shfl_xor(rs, 16, 64);
      rs += __shfl_xor(rs, 32, 64);
      l[nt] = l[nt] * alpha + rs;
      #pragma unroll
      for (int mt = 0; mt < 2; ++mt)
        #pragma unroll
        for (int r = 0; r < 4; ++r)
          o[mt][nt][r] *= alpha;
    }
    #pragma unroll
    for (int kc = 0; kc < 2; ++kc) {
      bf16x8 vf[2], pf[2];
      #pragma unroll
      for (int mt = 0; mt < 2; ++mt)
        vf[mt] = *(const bf16x8*)(Vbh + (size_t)(mt * 16 + c) * 1024 + kb0 + kc * 32 + g * 8);
      #pragma unroll
      for (int nt = 0; nt < 2; ++nt)
        pf[nt] = *(const bf16x8*)&Ps[wq][nt * 16 + c][kc * 32 + g * 8];
      #pragma unroll
      for (int mt = 0; mt < 2; ++mt)
        #pragma unroll
        for (int nt = 0; nt < 2; ++nt)
          o[mt][nt] = __builtin_amdgcn_mfma_f32_16x16x32_bf16(vf[mt], pf[nt], o[mt][nt], 0, 0, 0);
    }
  }
  #pragma unroll
  for (int nt = 0; nt < 2; ++nt) {
    const float linv = 1.f / l[nt];
    const int q = qbase + nt * 16 + c;
    const int y = q >> 5, x = q & 31;
    ushort* dst = op_pad + ((size_t)b * 1156 + (y + 1) * 34 + (x + 1)) * 256 + h * 32;
    #pragma unroll
    for (int mt = 0; mt < 2; ++mt) {
      union { ushort u[4]; uint2 d; } pk;
      #pragma unroll
      for (int r = 0; r < 4; ++r)
        pk.u[r] = f2bf(o[mt][nt][r] * linv);
      *(uint2*)(dst + mt * 16 + g * 4) = pk.d;
    }
  }
}

// ------ 3x3 conv as 9 shifted GEMMs over padded NHWC, bf16 MFMA -------------
// (kept for the Wo conv; small grid, not the hot spot)
template <int CIN, int S, int PW, int OUT_NHWC>
__global__ __launch_bounds__(256) void k_conv9_mfma(
    const ushort* __restrict__ in, const ushort* __restrict__ W9,
    const float* __restrict__ bias, float* __restrict__ out)
{
  const int n0 = blockIdx.x * 128, oc0 = blockIdx.y * 128, b = blockIdx.z;
  const int tid = threadIdx.x, lane = tid & 63, w = tid >> 6;
  __shared__ ushort As[128][32], Bs[128][32];
  const int wr = w >> 1, wc = w & 1;
  f32x4 acc[4][4];
  #pragma unroll
  for (int mi = 0; mi < 4; ++mi)
    #pragma unroll
    for (int ni = 0; ni < 4; ++ni) {
      f32x4 z = {0.f, 0.f, 0.f, 0.f};
      acc[mi][ni] = z;
    }
  int rowq[2], segq[2], basep[2];
  #pragma unroll
  for (int q = 0; q < 2; ++q) {
    int idx = w * 128 + q * 64 + lane;
    rowq[q] = idx >> 2;
    segq[q] = (idx & 3) * 8;
    int n = n0 + rowq[q];
    int y = n / S, x = n % S;
    basep[q] = y * PW + x;
  }
  const ushort* inb = in + (size_t)b * (PW * PW) * CIN;

  for (int t = 0; t < 9; ++t) {
    const int offp = (t / 3) * PW + (t % 3);
    const ushort* wt = W9 + (size_t)t * 256 * CIN;
    for (int kc = 0; kc < CIN; kc += 32) {
      __syncthreads();
      #pragma unroll
      for (int q = 0; q < 2; ++q) {
        const ushort* srcA = wt + (size_t)(oc0 + rowq[q]) * CIN + kc + segq[q];
        const ushort* srcB = inb + (size_t)(basep[q] + offp) * CIN + kc + segq[q];
        char* dstA = (char*)&As[0][0] + w * 2048 + q * 1024;
        char* dstB = (char*)&Bs[0][0] + w * 2048 + q * 1024;
        __builtin_amdgcn_global_load_lds(
            (const __attribute__((address_space(1))) unsigned*)srcA,
            (__attribute__((address_space(3))) unsigned*)dstA, 16, 0, 0);
        __builtin_amdgcn_global_load_lds(
            (const __attribute__((address_space(1))) unsigned*)srcB,
            (__attribute__((address_space(3))) unsigned*)dstB, 16, 0, 0);
      }
      __syncthreads();
      bf16x8 af[4], bfv[4];
      #pragma unroll
      for (int mi = 0; mi < 4; ++mi)
        af[mi] = *(const bf16x8*)&As[wr * 64 + mi * 16 + (lane & 15)][(lane >> 4) * 8];
      #pragma unroll
      for (int ni = 0; ni < 4; ++ni)
        bfv[ni] = *(const bf16x8*)&Bs[wc * 64 + ni * 16 + (lane & 15)][(lane >> 4) * 8];
      #pragma unroll
      for (int mi = 0; mi < 4; ++mi)
        #pragma unroll
        for (int ni = 0; ni < 4; ++ni)
          acc[mi][ni] = __builtin_amdgcn_mfma_f32_16x16x32_bf16(
              af[mi], bfv[ni], acc[mi][ni], 0, 0, 0);
    }
  }
  if (OUT_NHWC) {
    float* outb = out + (size_t)b * (S * S) * 256;
    #pragma unroll
    for (int mi = 0; mi < 4; ++mi) {
      const int oc = oc0 + wr * 64 + mi * 16 + (lane >> 4) * 4;
      float4 bb = *(const float4*)(bias + oc);
      #pragma unroll
      for (int ni = 0; ni < 4; ++ni) {
        const int n = n0 + wc * 64 + ni * 16 + (lane & 15);
        float4 v;
        v.x = acc[mi][ni][0] + bb.x;
        v.y = acc[mi][ni][1] + bb.y;
        v.z = acc[mi][ni][2] + bb.z;
        v.w = acc[mi][ni][3] + bb.w;
        *(float4*)(outb + (size_t)n * 256 + oc) = v;
      }
    }
  } else {
    float* outb = out + (size_t)b * 256 * (S * S);
    #pragma unroll
    for (int mi = 0; mi < 4; ++mi) {
      #pragma unroll
      for (int r = 0; r < 4; ++r) {
        int oc = oc0 + wr * 64 + mi * 16 + (lane >> 4) * 4 + r;
        float bb = bias[oc];
        #pragma unroll
        for (int ni = 0; ni < 4; ++ni) {
          int n = n0 + wc * 64 + ni * 16 + (lane & 15);
          outb[(size_t)oc * (S * S) + n] = acc[mi][ni][r] + bb;
        }
      }
    }
  }
}

// ------ fusion 3x3 conv, CIN=512: pipelined 128x256 tile, BK=64 -------------
// T3+T4: triple-buffered LDS, counted vmcnt (never 0 in steady state).
// T2: XOR swizzle via pre-swizzled global src into linear-dest
// global_load_lds; same XOR on ds_read. T5: setprio around MFMA cluster.
// Round 4: register double-buffered fragments, with sched_barrier(0) BETWEEN
// the {READ_FRAGS + STAGE} group and the MFMA cluster — r3 showed the machine
// scheduler reordered MFMAs before/among the ds_reads (dur identical to r1,
// VGPR only 120), serializing LDS-read + MFMA. The pin forces loads to issue
// first so the LDS pipe drains under the matrix pipe.
#define STAGE_CONV(s_, bi_)                                                    \
  {                                                                            \
    const int t_ = (s_) >> 3, kc_ = ((s_) & 7) << 6;                           \
    const ushort* wt_ = W9 + t_ * 131072 + kc_;                                \
    const ushort* ib_ = inb + ((t_ / 3) * 66 + (t_ % 3)) * 512 + kc_;          \
    _Pragma("unroll")                                                          \
    for (int q_ = 0; q_ < 2; ++q_) {                                           \
      __builtin_amdgcn_global_load_lds(                                        \
          (const __attribute__((address_space(1))) unsigned*)(wt_ + aInv[q_]), \
          (__attribute__((address_space(3))) unsigned*)                        \
              ((char*)lds + (bi_) * 16384 + (w * 16 + q_ * 8) * 128),          \
          16, 0, 0);                                                           \
    }                                                                          \
    _Pragma("unroll")                                                          \
    for (int q_ = 0; q_ < 4; ++q_) {                                           \
      __builtin_amdgcn_global_load_lds(                                        \
          (const __attribute__((address_space(1))) unsigned*)(ib_ + bInv[q_]), \
          (__attribute__((address_space(3))) unsigned*)                        \
              ((char*)lds + 49152 + (bi_) * 32768 + (w * 32 + q_ * 8) * 128),  \
          16, 0, 0);                                                           \
    }                                                                          \
  }

#define READ_FRAGS(rb_, AF_, BF_)                                              \
  {                                                                            \
    const ushort* As_ = lds + (rb_) * 8192 + (wm * 64 + c) * 64;               \
    const ushort* Bs_ = lds + 24576 + (rb_) * 16384 + (wn * 64 + c) * 64;      \
    _Pragma("unroll")                                                          \
    for (int mi_ = 0; mi_ < 4; ++mi_) {                                        \
      AF_[mi_][0] = *(const bf16x8*)(As_ + mi_ * 1024 + okh0);                 \
      AF_[mi_][1] = *(const bf16x8*)(As_ + mi_ * 1024 + okh1);                 \
    }                                                                          \
    _Pragma("unroll")                                                          \
    for (int ni_ = 0; ni_ < 4; ++ni_) {                                        \
      BF_[ni_][0] = *(const bf16x8*)(Bs_ + ni_ * 1024 + okh0);                 \
      BF_[ni_][1] = *(const bf16x8*)(Bs_ + ni_ * 1024 + okh1);                 \
    }                                                                          \
  }

#define MFMA_SET(AF_, BF_)                                                     \
  {                                                                            \
    __builtin_amdgcn_s_setprio(1);                                             \
    _Pragma("unroll")                                                          \
    for (int mi_ = 0; mi_ < 4; ++mi_)                                          \
      _Pragma("unroll")                                                        \
      for (int ni_ = 0; ni_ < 4; ++ni_) {                                      \
        acc[mi_][ni_] = __builtin_amdgcn_mfma_f32_16x16x32_bf16(               \
            AF_[mi_][0], BF_[ni_][0], acc[mi_][ni_], 0, 0, 0);                 \
        acc[mi_][ni_] = __builtin_amdgcn_mfma_f32_16x16x32_bf16(               \
            AF_[mi_][1], BF_[ni_][1], acc[mi_][ni_], 0, 0, 0);                 \
      }                                                                        \
    __builtin_amdgcn_s_setprio(0);                                             \
  }

#define PHASE_END(vm_)                                                         \
  {                                                                            \
    asm volatile("s_waitcnt lgkmcnt(0)" ::: "memory");                         \
    asm volatile("s_waitcnt vmcnt(" #vm_ ")" ::: "memory");                    \
    __builtin_amdgcn_sched_barrier(0);                                         \
    __builtin_amdgcn_s_barrier();                                              \
  }

// pin: loads of this phase issue BEFORE the MFMA cluster
#define LOADS_FIRST() __builtin_amdgcn_sched_barrier(0)

__global__ __launch_bounds__(512, 2) void k_conv9_pipe(
    const ushort* __restrict__ in, const ushort* __restrict__ W9,
    const float* __restrict__ bias, float* __restrict__ out)
{
  const int n0 = blockIdx.x * 256, oc0 = blockIdx.y * 128, b = blockIdx.z;
  const int tid = threadIdx.x, lane = tid & 63, w = tid >> 6;
  const int wm = w >> 2, wn = w & 3;            // 2M x 4N waves, 64x64 each
  const int g = lane >> 4, c = lane & 15;
  // A bufs: 3 x [128][64] bf16 @ byte 0 ; B bufs: 3 x [256][64] bf16 @ 49152
  __shared__ __align__(16) ushort lds[73728];   // 144 KiB
  const ushort* inb = in + (size_t)b * 4356 * 512;

  // per-lane staging invariants (row owned by this lane per issue; source
  // column pre-XORed so linear LDS dest + XORed ds_read = conflict-free)
  const int l8 = lane >> 3, lx = lane & 7;
  int aInv[2], bInv[4];
  #pragma unroll
  for (int q = 0; q < 2; ++q) {
    const int row = w * 16 + q * 8 + l8;
    const int cx = (((lx << 4) ^ ((row & 7) << 4)) >> 1);
    aInv[q] = (oc0 + row) * 512 + cx;
  }
  #pragma unroll
  for (int q = 0; q < 4; ++q) {
    const int row = w * 32 + q * 8 + l8;
    const int n = n0 + row;
    const int y = n >> 6, x = n & 63;
    const int cx = (((lx << 4) ^ ((row & 7) << 4)) >> 1);
    bInv[q] = (y * 66 + x) * 512 + cx;
  }

  // fragment-read column terms: row&7 == c&7 for every mi/ni (mi*16, w*64
  // are 0 mod 8) -> single XOR term shared by all fragment reads
  const int sx = (c & 7) << 3;
  const int okh0 = (g * 8) ^ sx;
  const int okh1 = (32 + g * 8) ^ sx;

  f32x4 acc[4][4];
  #pragma unroll
  for (int mi = 0; mi < 4; ++mi)
    #pragma unroll
    for (int ni = 0; ni < 4; ++ni) {
      f32x4 z = {0.f, 0.f, 0.f, 0.f};
      acc[mi][ni] = z;
    }

  bf16x8 afE[4][2], bfE[4][2], afO[4][2], bfO[4][2];

  // prologue: stage 3 buffers; read frags(0) into E-set
  STAGE_CONV(0, 0);
  STAGE_CONV(1, 1);
  STAGE_CONV(2, 2);
  asm volatile("s_waitcnt vmcnt(12)" ::: "memory");   // stage(0) done
  __builtin_amdgcn_sched_barrier(0);
  __builtin_amdgcn_s_barrier();
  READ_FRAGS(0, afE, bfE);
  PHASE_END(6);                                       // stage(1) done

  int rb = 1;   // buffer holding frags for the NEXT phase
  for (int p = 0; p < 68; p += 2) {
    // phase p (even): load O-set for p+1, stage p+3, compute E-set
    READ_FRAGS(rb, afO, bfO);
    { int sb = rb + 2; if (sb >= 3) sb -= 3; STAGE_CONV(p + 3, sb); }
    LOADS_FIRST();
    MFMA_SET(afE, bfE);
    PHASE_END(6);
    ++rb; if (rb == 3) rb = 0;
    // phase p+1 (odd): load E-set for p+2, stage p+4, compute O-set
    READ_FRAGS(rb, afE, bfE);
    { int sb = rb + 2; if (sb >= 3) sb -= 3; STAGE_CONV(p + 4, sb); }
    LOADS_FIRST();
    MFMA_SET(afO, bfO);
    PHASE_END(6);
    ++rb; if (rb == 3) rb = 0;
  }
  // phase 68: read 69, stage 71, compute E
  READ_FRAGS(rb, afO, bfO);
  { int sb = rb + 2; if (sb >= 3) sb -= 3; STAGE_CONV(71, sb); }
  LOADS_FIRST();
  MFMA_SET(afE, bfE);
  PHASE_END(6);                                       // stage(70) done
  ++rb; if (rb == 3) rb = 0;
  // phase 69: read 70, compute O
  READ_FRAGS(rb, afE, bfE);
  LOADS_FIRST();
  MFMA_SET(afO, bfO);
  PHASE_END(0);                                       // stage(71) done
  ++rb; if (rb == 3) rb = 0;
  // phase 70: read 71, compute E
  READ_FRAGS(rb, afO, bfO);
  LOADS_FIRST();
  MFMA_SET(afE, bfE);
  asm volatile("s_waitcnt lgkmcnt(0)" ::: "memory");
  __builtin_amdgcn_sched_barrier(0);
  __builtin_amdgcn_s_barrier();
  // phase 71: compute O
  MFMA_SET(afO, bfO);

  // epilogue: NCHW fp32 + bias (same fragment convention as k_conv9_mfma)
  float* outb = out + (size_t)b * 1048576;
  #pragma unroll
  for (int mi = 0; mi < 4; ++mi) {
    const int oc = oc0 + wm * 64 + mi * 16 + g * 4;
    float4 bb = *(const float4*)(bias + oc);
    #pragma unroll
    for (int ni = 0; ni < 4; ++ni) {
      const int n = n0 + wn * 64 + ni * 16 + c;
      outb[(size_t)(oc + 0) * 4096 + n] = acc[mi][ni][0] + bb.x;
      outb[(size_t)(oc + 1) * 4096 + n] = acc[mi][ni][1] + bb.y;
      outb[(size_t)(oc + 2) * 4096 + n] = acc[mi][ni][2] + bb.z;
      outb[(size_t)(oc + 3) * 4096 + n] = acc[mi][ni][3] + bb.w;
    }
  }
}

// ---- P4: bilinear x2 upsample + residual -> fused_pad[.., ch 0:256] --------
__global__ __launch_bounds__(256) void k_upsample_nhwc(
    const float* __restrict__ xpos, const float* __restrict__ opc,
    const float* __restrict__ gamma, ushort* __restrict__ fused)
{
  const int t = blockIdx.x * 256 + threadIdx.x;  // 8*4096*64
  const int c = (t & 63) * 4;
  const int pix = (t >> 6) & 4095;
  const int b = t >> 18;
  const int y = pix >> 6, xx = pix & 63;
  const int my = y >> 1;
  const int y0 = (y & 1) ? my : my - 1;
  const float fy = (y & 1) ? 0.25f : 0.75f;
  const int mx = xx >> 1;
  const int x0 = (xx & 1) ? mx : mx - 1;
  const float fx = (xx & 1) ? 0.25f : 0.75f;
  const int y0c = max(y0, 0), y1c = min(y0 + 1, 31);
  const int x0c = max(x0, 0), x1c = min(x0 + 1, 31);
  const float* base = opc + (size_t)b * 1024 * 256 + c;
  float4 v00 = *(const float4*)(base + (size_t)(y0c * 32 + x0c) * 256);
  float4 v01 = *(const float4*)(base + (size_t)(y0c * 32 + x1c) * 256);
  float4 v10 = *(const float4*)(base + (size_t)(y1c * 32 + x0c) * 256);
  float4 v11 = *(const float4*)(base + (size_t)(y1c * 32 + x1c) * 256);
  const float w00 = (1.f - fy) * (1.f - fx), w01 = (1.f - fy) * fx;
  const float w10 = fy * (1.f - fx), w11 = fy * fx;
  const float g = gamma[0];
  const float* xr = xpos + ((size_t)b * 256 + c) * 4096 + pix;
  union { ushort u[4]; uint2 q; } o;
  o.u[0] = f2bf(xr[0]          + g * (w00 * v00.x + w01 * v01.x + w10 * v10.x + w11 * v11.x));
  o.u[1] = f2bf(xr[4096]       + g * (w00 * v00.y + w01 * v01.y + w10 * v10.y + w11 * v11.y));
  o.u[2] = f2bf(xr[2 * 4096]   + g * (w00 * v00.z + w01 * v01.z + w10 * v10.z + w11 * v11.z));
  o.u[3] = f2bf(xr[3 * 4096]   + g * (w00 * v00.w + w01 * v01.w + w10 * v10.w + w11 * v11.w));
  *(uint2*)(fused + ((size_t)b * 4356 + (y + 1) * 66 + (xx + 1)) * 512 + c) = o.q;
}

// ------- C0: CHA q/k/v grouped 2x2 projections -> bf16 (half-batch) ---------
__global__ __launch_bounds__(256) void k_cha_proj(
    const float* __restrict__ x,
    const float* __restrict__ Wq, const float* __restrict__ bq,
    const float* __restrict__ Wk, const float* __restrict__ bk,
    const float* __restrict__ Wv, const float* __restrict__ bv,
    ushort* __restrict__ Qc, ushort* __restrict__ Kc, ushort* __restrict__ Vt)
{
  const int t = blockIdx.x * 256 + threadIdx.x;
  const int bl = t >> 16;
  const int g  = (t >> 8) & 255;
  const int lq = t & 255;
  const int i = lq >> 3, j4 = (lq & 7) << 2;
  const float* xb = x + (((size_t)bl * 256 + g) << 12) + (2 * i) * 64 + 2 * j4;
  union { float4 v[2]; float f[8]; } xr0, xr1;
  xr0.v[0] = *(const float4*)(xb);
  xr0.v[1] = *(const float4*)(xb + 4);
  xr1.v[0] = *(const float4*)(xb + 64);
  xr1.v[1] = *(const float4*)(xb + 68);
  const int bhl = bl * 8 + (g >> 5);
  const int c2b = (g & 31) * 8;
  const int l0 = i * 32 + j4;
  #pragma unroll
  for (int h = 0; h < 8; ++h) {
    float4 w4 = *(const float4*)(Wq + g * 32 + h * 4);
    float bb = bq[g * 8 + h];
    union { ushort u[4]; uint2 q; } o;
    #pragma unroll
    for (int jj = 0; jj < 4; ++jj) {
      float v = xr0.f[2 * jj] * w4.x + xr0.f[2 * jj + 1] * w4.y
              + xr1.f[2 * jj] * w4.z + xr1.f[2 * jj + 1] * w4.w + bb;
      o.u[jj] = f2bf(v * 0.03125f);
    }
    *(uint2*)(Qc + (((size_t)bhl * 256 + c2b + h) << 10) + l0) = o.q;
  }
  #pragma unroll
  for (int h = 0; h < 8; ++h) {
    float4 w4 = *(const float4*)(Wk + g * 32 + h * 4);
    float bb = bk[g * 8 + h];
    union { ushort u[4]; uint2 q; } o;
    #pragma unroll
    for (int jj = 0; jj < 4; ++jj) {
      float v = xr0.f[2 * jj] * w4.x + xr0.f[2 * jj + 1] * w4.y
              + xr1.f[2 * jj] * w4.z + xr1.f[2 * jj + 1] * w4.w + bb;
      o.u[jj] = f2bf(v);
    }
    *(uint2*)(Kc + (((size_t)bhl * 256 + c2b + h) << 10) + l0) = o.q;
  }
  ushort vo[4][8];
  #pragma unroll
  for (int h = 0; h < 8; ++h) {
    float4 w4 = *(const float4*)(Wv + g * 32 + h * 4);
    float bb = bv[g * 8 + h];
    #pragma unroll
    for (int jj = 0; jj < 4; ++jj) {
      float v = xr0.f[2 * jj] * w4.x + xr0.f[2 * jj + 1] * w4.y
              + xr1.f[2 * jj] * w4.z + xr1.f[2 * jj + 1] * w4.w + bb;
      vo[jj][h] = f2bf(v);
    }
  }
  #pragma unroll
  for (int jj = 0; jj < 4; ++jj)
    *(uint4*)(Vt + ((size_t)bhl << 18) + (size_t)(l0 + jj) * 256 + c2b) =
        *(uint4*)&vo[jj][0];
}

// ------- C1: scores = qc @ kc^T, bf16 MFMA, K=1024 (half-batch) -------------
__global__ __launch_bounds__(256) void k_cha_scores_mfma(
    const ushort* __restrict__ Qc, const ushort* __restrict__ Kc,
    float* __restrict__ S)
{
  const int c0 = blockIdx.x * 128, d0 = blockIdx.y * 128, bhl = blockIdx.z;
  const int tid = threadIdx.x, lane = tid & 63, w = tid >> 6;
  __shared__ ushort As[128][32], Bs[128][32];
  const ushort* Ab = Qc + ((size_t)bhl * 256 + c0) * 1024;
  const ushort* Bb = Kc + ((size_t)bhl * 256 + d0) * 1024;
  const int wr = w >> 1, wc = w & 1;
  f32x4 acc[4][4];
  #pragma unroll
  for (int mi = 0; mi < 4; ++mi)
    #pragma unroll
    for (int ni = 0; ni < 4; ++ni) {
      f32x4 z = {0.f, 0.f, 0.f, 0.f};
      acc[mi][ni] = z;
    }
  for (int kc = 0; kc < 1024; kc += 32) {
    __syncthreads();
    #pragma unroll
    for (int q = 0; q < 2; ++q) {
      int idx = w * 128 + q * 64 + lane;
      int row = idx >> 2, seg = idx & 3;
      const ushort* srcA = Ab + (size_t)row * 1024 + kc + seg * 8;
      const ushort* srcB = Bb + (size_t)row * 1024 + kc + seg * 8;
      char* dstA = (char*)&As[0][0] + w * 2048 + q * 1024;
      char* dstB = (char*)&Bs[0][0] + w * 2048 + q * 1024;
      __builtin_amdgcn_global_load_lds(
          (const __attribute__((address_space(1))) unsigned*)srcA,
          (__attribute__((address_space(3))) unsigned*)dstA, 16, 0, 0);
      __builtin_amdgcn_global_load_lds(
          (const __attribute__((address_space(1))) unsigned*)srcB,
          (__attribute__((address_space(3))) unsigned*)dstB, 16, 0, 0);
    }
    __syncthreads();
    bf16x8 af[4], bfv[4];
    #pragma unroll
    for (int mi = 0; mi < 4; ++mi)
      af[mi] = *(const bf16x8*)&As[wr * 64 + mi * 16 + (lane & 15)][(lane >> 4) * 8];
    #pragma unroll
    for (int ni = 0; ni < 4; ++ni)
      bfv[ni] = *(const bf16x8*)&Bs[wc * 64 + ni * 16 + (lane & 15)][(lane >> 4) * 8];
    #pragma unroll
    for (int mi = 0; mi < 4; ++mi)
      #pragma unroll
      for (int ni = 0; ni < 4; ++ni)
        acc[mi][ni] = __builtin_amdgcn_mfma_f32_16x16x32_bf16(
            af[mi], bfv[ni], acc[mi][ni], 0, 0, 0);
  }
  float* Sb = S + ((size_t)bhl << 16);
  #pragma unroll
  for (int mi = 0; mi < 4; ++mi)
    #pragma unroll
    for (int r = 0; r < 4; ++r) {
      int c = c0 + wr * 64 + mi * 16 + (lane >> 4) * 4 + r;
      #pragma unroll
      for (int ni = 0; ni < 4; ++ni) {
        int d = d0 + wc * 64 + ni * 16 + (lane & 15);
        Sb[(size_t)c * 256 + d] = acc[mi][ni][r];
      }
    }
}

// ------- C2: row softmax over 256 -> bf16 P ---------------------------------
__global__ __launch_bounds__(256) void k_softmax_p(
    const float* __restrict__ S, ushort* __restrict__ P)
{
  const int row = blockIdx.x * 4 + (threadIdx.x >> 6);
  const int lane = threadIdx.x & 63;
  const float* r = S + (size_t)row * 256;
  float4 v = *(const float4*)(r + lane * 4);
  float m = fmaxf(fmaxf(v.x, v.y), fmaxf(v.z, v.w));
  #pragma unroll
  for (int off = 32; off; off >>= 1) m = fmaxf(m, __shfl_xor(m, off, 64));
  v.x = __expf(v.x - m); v.y = __expf(v.y - m);
  v.z = __expf(v.z - m); v.w = __expf(v.w - m);
  float s = v.x + v.y + v.z + v.w;
  #pragma unroll
  for (int off = 32; off; off >>= 1) s += __shfl_xor(s, off, 64);
  const float inv = 1.f / s;
  union { ushort u[4]; uint2 q; } o;
  o.u[0] = f2bf(v.x * inv); o.u[1] = f2bf(v.y * inv);
  o.u[2] = f2bf(v.z * inv); o.u[3] = f2bf(v.w * inv);
  *(uint2*)(P + (size_t)row * 256 + lane * 4) = o.q;
}

// -- C3: oc = P @ vcT (MFMA) + grouped ConvT + residual -> fused_pad NHWC ----
__global__ __launch_bounds__(256) void k_cha_pv(
    const ushort* __restrict__ P, const ushort* __restrict__ Vt,
    const float* __restrict__ x,
    const float* __restrict__ Wt, const float* __restrict__ bt,
    const float* __restrict__ gamma, ushort* __restrict__ fused, int bbase)
{
  const int n0 = blockIdx.x * 128, c0 = blockIdx.y * 128, bhl = blockIdx.z;
  const int b = bbase + (bhl >> 3), h = bhl & 7;
  const int tid = threadIdx.x, lane = tid & 63, w = tid >> 6;
  __shared__ ushort As[128][32], Bs[128][32];
  __shared__ ushort Ot[512][16];
  __shared__ float wt_s[16][32];
  __shared__ float bt_s[16];
  const int gp_base = h * 32 + (c0 >> 3);
  {
    int e = tid;
    wt_s[e >> 5][e & 31] = Wt[(size_t)gp_base * 32 + e];
    e += 256;
    wt_s[e >> 5][e & 31] = Wt[(size_t)gp_base * 32 + e];
    if (tid < 16) bt_s[tid] = bt[gp_base + tid];
  }
  const ushort* Ab = P + (((size_t)bhl << 8) + c0) * 256;
  const ushort* Bb = Vt + ((size_t)bhl << 18) + (size_t)n0 * 256;
  const int wr = w >> 1, wc = w & 1;
  f32x4 acc[4][4];
  #pragma unroll
  for (int mi = 0; mi < 4; ++mi)
    #pragma unroll
    for (int ni = 0; ni < 4; ++ni) {
      f32x4 z = {0.f, 0.f, 0.f, 0.f};
      acc[mi][ni] = z;
    }
  for (int kc = 0; kc < 256; kc += 32) {
    __syncthreads();
    #pragma unroll
    for (int q = 0; q < 2; ++q) {
      int idx = w * 128 + q * 64 + lane;
      int row = idx >> 2, seg = idx & 3;
      const ushort* srcA = Ab + (size_t)row * 256 + kc + seg * 8;
      const ushort* srcB = Bb + (size_t)row * 256 + kc + seg * 8;
      char* dstA = (char*)&As[0][0] + w * 2048 + q * 1024;
      char* dstB = (char*)&Bs[0][0] + w * 2048 + q * 1024;
      __builtin_amdgcn_global_load_lds(
          (const __attribute__((address_space(1))) unsigned*)srcA,
          (__attribute__((address_space(3))) unsigned*)dstA, 16, 0, 0);
      __builtin_amdgcn_global_load_lds(
          (const __attribute__((address_space(1))) unsigned*)srcB,
          (__attribute__((address_space(3))) unsigned*)dstB, 16, 0, 0);
    }
    __syncthreads();
    bf16x8 af[4], bfv[4];
    #pragma unroll
    for (int mi = 0; mi < 4; ++mi)
      af[mi] = *(const bf16x8*)&As[wr * 64 + mi * 16 + (lane & 15)][(lane >> 4) * 8];
    #pragma unroll
    for (int ni = 0; ni < 4; ++ni)
      bfv[ni] = *(const bf16x8*)&Bs[wc * 64 + ni * 16 + (lane & 15)][(lane >> 4) * 8];
    #pragma unroll
    for (int mi = 0; mi < 4; ++mi)
      #pragma unroll
      for (int ni = 0; ni < 4; ++ni)
        acc[mi][ni] = __builtin_amdgcn_mfma_f32_16x16x32_bf16(
            af[mi], bfv[ni], acc[mi][ni], 0, 0, 0);
  }
  const float gm = gamma[0];
  const int col = lane & 15, q = lane >> 4;
  #pragma unroll
  for (int mi = 0; mi < 4; ++mi) {
    const int gloc = wr * 8 + mi * 2 + (q >> 1);
    const int gp = gp_base + gloc;
    const float btv = bt_s[gloc];
    #pragma unroll
    for (int ni = 0; ni < 4; ++ni) {
      float pa[4] = {0.f, 0.f, 0.f, 0.f};
      #pragma unroll
      for (int r = 0; r < 4; ++r) {
        const int i2 = (q & 1) * 4 + r;
        const float a = acc[mi][ni][r];
        pa[0] += a * wt_s[gloc][i2 * 4 + 0];
        pa[1] += a * wt_s[gloc][i2 * 4 + 1];
        pa[2] += a * wt_s[gloc][i2 * 4 + 2];
        pa[3] += a * wt_s[gloc][i2 * 4 + 3];
      }
      float v0 = pa[0] + __shfl_xor(pa[0], 16, 64);
      float v1 = pa[1] + __shfl_xor(pa[1], 16, 64);
      float v2 = pa[2] + __shfl_xor(pa[2], 16, 64);
      float v3 = pa[3] + __shfl_xor(pa[3], 16, 64);
      const int lloc = wc * 64 + ni * 16 + col;
      const int l = n0 + lloc;
      const int p = l >> 5, j = l & 31;
      const int y = 2 * p + (q & 1);
      const float va = (q & 1) ? v2 : v0;
      const float vb = (q & 1) ? v3 : v1;
      const float* xc = x + (((size_t)b * 256 + gp) << 12) + (y << 6) + 2 * j;
      const int lp = (lloc << 2) + (q & 1) * 2;
      Ot[lp][gloc]     = f2bf(xc[0] + gm * (va + btv));
      Ot[lp + 1][gloc] = f2bf(xc[1] + gm * (vb + btv));
    }
  }
  __syncthreads();
  #pragma unroll
  for (int pp2 = 0; pp2 < 2; ++pp2) {
    const int pixl = tid * 2 + pp2;
    const int lloc = pixl >> 2;
    const int l = n0 + lloc;
    const int p = l >> 5, j = l & 31;
    const int yy = 2 * p + ((pixl >> 1) & 1) + 1;
    const int xx = 2 * j + (pixl & 1) + 1;
    const uint4* src = (const uint4*)&Ot[pixl][0];
    uint4* dst = (uint4*)(fused + ((size_t)b * 4356 + yy * 66 + xx) * 512 + 256 + gp_base);
    dst[0] = src[0];
    dst[1] = src[1];
  }
}

extern "C" void kernel_launch(void* const* d_in, const int* in_sizes, int n_in,
                              void* d_out, int out_size, void* d_ws, size_t ws_size,
                              hipStream_t stream)
{
  (void)in_sizes; (void)n_in; (void)out_size; (void)ws_size;
  const float* qkv_pos   = (const float*)d_in[0];
  const float* qkv_cha   = (const float*)d_in[1];
  const float* Wq_pos    = (const float*)d_in[2];
  const float* bq_pos    = (const float*)d_in[3];
  const float* Wk_pos    = (const float*)d_in[4];
  const float* bk_pos    = (const float*)d_in[5];
  const float* Wv_pos    = (const float*)d_in[6];
  const float* bv_pos    = (const float*)d_in[7];
  const float* Wo_pos    = (const float*)d_in[8];
  const float* bo_pos    = (const float*)d_in[9];
  const float* gamma_pos = (const float*)d_in[10];
  const float* Wq_cha    = (const float*)d_in[11];
  const float* bq_cha    = (const float*)d_in[12];
  const float* Wk_cha    = (const float*)d_in[13];
  const float* bk_cha    = (const float*)d_in[14];
  const float* Wv_cha    = (const float*)d_in[15];
  const float* bv_cha    = (const float*)d_in[16];
  const float* Wt_cha    = (const float*)d_in[17];
  const float* bt_cha    = (const float*)d_in[18];
  const float* gamma_cha = (const float*)d_in[19];
  const float* Wf        = (const float*)d_in[20];
  const float* bf        = (const float*)d_in[21];
  float* out = (float*)d_out;

  float* ws = (float*)d_ws;
  ushort* Wpf9    = (ushort*)ws;
  ushort* Wpo9    = (ushort*)(ws + 589824);
  // POS scratch
  ushort* Qb      = (ushort*)(ws + 884736);    // [64][1024][32] bf16
  ushort* Kb      = (ushort*)(ws + 1933312);   // [64][1024][32] bf16
  ushort* Vtb     = (ushort*)(ws + 2981888);   // [64][32][1024] bf16
  ushort* op_pad  = (ushort*)(ws + 4030464);   // 2367488 ushorts
  float*  op_conv = ws + 5214208;              // NHWC fp32 [8][1024][256]
  ushort* Ap      = (ushort*)(ws + 7311360);   // [8][1024][1024] bf16
  // CHA scratch (aliases POS region after it is consumed)
  ushort* qcb     = (ushort*)(ws + 884736);
  ushort* kcb     = (ushort*)(ws + 5079040);
  ushort* vcT     = (ushort*)(ws + 9273344);
  float*  attn_c  = ws + 13467648;
  ushort* Pb      = (ushort*)(ws + 15564800);
  ushort* fusedb  = (ushort*)(ws + 16613376);  // NHWC padded [8][66*66][512]
  ushort* Wqkvp   = (ushort*)(ws + 25534464);  // [384][1024] bf16

  // zero padded buffers (conv borders) and Qb (hd pad lanes 8..31 must be 0)
  hipMemsetAsync(op_pad, 0, (size_t)2367488 * 2, stream);
  hipMemsetAsync(Qb, 0, (size_t)2097152 * 2, stream);
  // fusedb: only the 66x66 border ring needs zero (interior fully written)
  k_zero_border<<<dim3(520), 256, 0, stream>>>(fusedb);
  // weight pre-packs
  k_prepack9<512><<<dim3(4608), 256, 0, stream>>>(Wf, Wpf9);
  k_prepack9<256><<<dim3(2304), 256, 0, stream>>>(Wo_pos, Wpo9);
  k_cast_wqkv<<<dim3(1536), 256, 0, stream>>>(Wq_pos, Wk_pos, Wv_pos, Wqkvp);
  // POS branch
  k_pack_pos<<<dim3(2048), 256, 0, stream>>>(qkv_pos, Ap);
  k_pos_qkv_mfma<<<dim3(8, 3, 8), 256, 0, stream>>>(Ap, Wqkvp,
      bq_pos, bk_pos, bv_pos, Qb, Kb, Vtb);
  k_pos_flash<<<dim3(8, 8, 8), 256, 0, stream>>>(Qb, Kb, Vtb, op_pad);
  k_conv9_mfma<256, 32, 34, 1><<<dim3(8, 2, 8), 256, 0, stream>>>(
      op_pad, Wpo9, bo_pos, op_conv);
  k_upsample_nhwc<<<dim3(8192), 256, 0, stream>>>(qkv_pos, op_conv, gamma_pos, fusedb);
  // CHA branch, two half-batches
  for (int half = 0; half < 2; ++half) {
    const float* xh = qkv_cha + (size_t)half * 4 * 256 * 4096;
    k_cha_proj<<<dim3(1024), 256, 0, stream>>>(xh, Wq_cha, bq_cha,
        Wk_cha, bk_cha, Wv_cha, bv_cha, qcb, kcb, vcT);
    k_cha_scores_mfma<<<dim3(2, 2, 32), 256, 0, stream>>>(qcb, kcb, attn_c);
    k_softmax_p<<<dim3(2048), 256, 0, stream>>>(attn_c, Pb);
    k_cha_pv<<<dim3(8, 2, 32), 256, 0, stream>>>(Pb, vcT, qkv_cha,
        Wt_cha, bt_cha, gamma_cha, fusedb, half * 4);
  }
  // fusion conv: pipelined 128x256 tile, reg-dbuf frags (loads pinned first)
  k_conv9_pipe<<<dim3(16, 2, 8), 512, 0, stream>>>(fusedb, Wpf9, bf, out);
}

// Round 5
// 520.028 us; speedup vs baseline: 1.1104x; 1.0360x over previous
//
#include <hip/hip_runtime.h>
#include <math.h>

// Shapes: B=8, C=256, H=W=64, HQ=WQ=32, L=1024, NH=8, hd=8, dv=32
//
// Workspace (float units):
//   Wpf9 bf16[9][256][512] @ 0        (589824 f)
//   Wpo9 bf16[9][256][256] @ 589824   (294912 f)
//   region2 @ 884736 (POS scratch, later aliased by CHA scratch)
//   fused_pad bf16[8][66*66][512] @ 16613376 (8921088 f)
//   Wqkv_p bf16[384][1024] @ 25534464 (196608 f)

typedef __attribute__((ext_vector_type(8))) short bf16x8;
typedef __attribute__((ext_vector_type(4))) float f32x4;

__device__ __forceinline__ ushort f2bf(float f) {
  union { float f; unsigned u; } v; v.f = f;
  unsigned r = (v.u + 0x7FFFu + ((v.u >> 16) & 1u)) >> 16;
  return (ushort)r;
}

// -------- merged weight pre-pack (one launch) -------------------------------
// range 0: Wf[oc][512][3][3] -> Wpf9[t][oc][512]      (1179648 el)
// range 1: Wo[oc][256][3][3] -> Wpo9[t][oc][256]      (589824 el)
// range 2: concat Wq/Wk/Wv   -> Wqkvp[384][1024]      (393216 el)
__global__ __launch_bounds__(256) void k_prep_all(
    const float* __restrict__ Wf, const float* __restrict__ Wo,
    const float* __restrict__ Wq, const float* __restrict__ Wk,
    const float* __restrict__ Wv,
    ushort* __restrict__ Wpf9, ushort* __restrict__ Wpo9,
    ushort* __restrict__ Wqkvp)
{
  const int i = blockIdx.x * 256 + threadIdx.x;   // 8448*256 = 2162688
  if (i < 1179648) {
    const int t = i / 131072;
    const int r = i - t * 131072;
    const int oc = r >> 9, c = r & 511;
    Wpf9[i] = f2bf(Wf[((size_t)oc * 512 + c) * 9 + t]);
  } else if (i < 1179648 + 589824) {
    const int j = i - 1179648;
    const int t = j / 65536;
    const int r = j - t * 65536;
    const int oc = r >> 8, c = r & 255;
    Wpo9[j] = f2bf(Wo[((size_t)oc * 256 + c) * 9 + t]);
  } else {
    const int j = i - 1769472;                    // 384*1024
    const int o = j >> 10, k = j & 1023;
    float v;
    if (o < 64)       v = Wq[(size_t)o * 1024 + k];
    else if (o < 128) v = Wk[(size_t)(o - 64) * 1024 + k];
    else              v = Wv[(size_t)(o - 128) * 1024 + k];
    Wqkvp[j] = f2bf(v);
  }
}

// -------- merged zero-init (one launch, replaces 2 memsets + border kernel) -
// range 0: fused_pad 66x66 border ring            (133120 uint4)
// range 1: op_pad 34x34 border ring               (33792 uint4)
// range 2: Qb full region (pad lanes must be 0)   (262144 uint4)
__global__ __launch_bounds__(256) void k_zero_init(
    ushort* __restrict__ fused, ushort* __restrict__ op_pad,
    ushort* __restrict__ Qb)
{
  const int t = blockIdx.x * 256 + threadIdx.x;   // 1676*256 = 429056
  uint4 z = {0u, 0u, 0u, 0u};
  if (t < 133120) {
    const int e = t & 63;
    const int pi = (t >> 6) % 260;
    const int b = t / 16640;
    int y, x;
    if (pi < 66)       { y = 0;            x = pi; }
    else if (pi < 132) { y = 65;           x = pi - 66; }
    else if (pi < 196) { y = pi - 132 + 1; x = 0; }
    else               { y = pi - 196 + 1; x = 65; }
    *(uint4*)(fused + ((size_t)b * 4356 + y * 66 + x) * 512 + e * 8) = z;
  } else if (t < 133120 + 33792) {
    const int j = t - 133120;
    const int e = j & 31;
    const int pi = (j >> 5) % 132;
    const int b = j / 4224;
    int y, x;
    if (pi < 34)       { y = 0;            x = pi; }
    else if (pi < 68)  { y = 33;           x = pi - 34; }
    else if (pi < 100) { y = pi - 68 + 1;  x = 0; }
    else               { y = pi - 100 + 1; x = 33; }
    *(uint4*)(op_pad + ((size_t)b * 1156 + y * 34 + x) * 256 + e * 8) = z;
  } else {
    const int j = t - 166912;
    *(uint4*)(Qb + (size_t)j * 8) = z;
  }
}

// -------- patchify x (2x2 stride-2 im2col) -> bf16 Ap[b][l][1024] -----------
__global__ __launch_bounds__(256) void k_pack_pos(
    const float* __restrict__ x, ushort* __restrict__ Ap)
{
  const int t = blockIdx.x * 256 + threadIdx.x;   // 524288 threads
  const int j4 = t & 7;          // group of 4 output cols
  const int i  = (t >> 3) & 31;  // output row
  const int c  = (t >> 8) & 255;
  const int b  = t >> 16;
  const float* xb = x + (((size_t)b * 256 + c) << 12) + (2 * i) * 64 + 8 * j4;
  union { float4 v[2]; float f[8]; } r0, r1;
  r0.v[0] = *(const float4*)(xb);
  r0.v[1] = *(const float4*)(xb + 4);
  r1.v[0] = *(const float4*)(xb + 64);
  r1.v[1] = *(const float4*)(xb + 68);
  #pragma unroll
  for (int jj = 0; jj < 4; ++jj) {
    const int l = i * 32 + j4 * 4 + jj;
    union { ushort u[4]; uint2 d; } pk;
    pk.u[0] = f2bf(r0.f[2 * jj]);
    pk.u[1] = f2bf(r0.f[2 * jj + 1]);
    pk.u[2] = f2bf(r1.f[2 * jj]);
    pk.u[3] = f2bf(r1.f[2 * jj + 1]);
    *(uint2*)(Ap + ((((size_t)b << 10) + l) << 10) + c * 4) = pk.d;
  }
}

// ---- P1: POS q/k/v projection as bf16 MFMA GEMM [384x1024]x[1024xL] --------
__global__ __launch_bounds__(256) void k_pos_qkv_mfma(
    const ushort* __restrict__ Ap, const ushort* __restrict__ Wqkv,
    const float* __restrict__ bq, const float* __restrict__ bk,
    const float* __restrict__ bv,
    ushort* __restrict__ Qb, ushort* __restrict__ Kb, ushort* __restrict__ Vtb)
{
  const int n0 = blockIdx.x * 128, oc0 = blockIdx.y * 128, b = blockIdx.z;
  const int tid = threadIdx.x, lane = tid & 63, w = tid >> 6;
  __shared__ ushort As[128][32], Bs[128][32];
  const ushort* Abw = Wqkv + (size_t)oc0 * 1024;
  const ushort* Bb  = Ap + (((size_t)b << 10) + n0) * 1024;
  const int wr = w >> 1, wc = w & 1;
  f32x4 acc[4][4];
  #pragma unroll
  for (int mi = 0; mi < 4; ++mi)
    #pragma unroll
    for (int ni = 0; ni < 4; ++ni) {
      f32x4 z = {0.f, 0.f, 0.f, 0.f};
      acc[mi][ni] = z;
    }
  for (int kc = 0; kc < 1024; kc += 32) {
    __syncthreads();
    #pragma unroll
    for (int q = 0; q < 2; ++q) {
      int idx = w * 128 + q * 64 + lane;
      int row = idx >> 2, seg = idx & 3;
      const ushort* srcA = Abw + (size_t)row * 1024 + kc + seg * 8;
      const ushort* srcB = Bb + (size_t)row * 1024 + kc + seg * 8;
      char* dstA = (char*)&As[0][0] + w * 2048 + q * 1024;
      char* dstB = (char*)&Bs[0][0] + w * 2048 + q * 1024;
      __builtin_amdgcn_global_load_lds(
          (const __attribute__((address_space(1))) unsigned*)srcA,
          (__attribute__((address_space(3))) unsigned*)dstA, 16, 0, 0);
      __builtin_amdgcn_global_load_lds(
          (const __attribute__((address_space(1))) unsigned*)srcB,
          (__attribute__((address_space(3))) unsigned*)dstB, 16, 0, 0);
    }
    __syncthreads();
    bf16x8 af[4], bfv[4];
    #pragma unroll
    for (int mi = 0; mi < 4; ++mi)
      af[mi] = *(const bf16x8*)&As[wr * 64 + mi * 16 + (lane & 15)][(lane >> 4) * 8];
    #pragma unroll
    for (int ni = 0; ni < 4; ++ni)
      bfv[ni] = *(const bf16x8*)&Bs[wc * 64 + ni * 16 + (lane & 15)][(lane >> 4) * 8];
    #pragma unroll
    for (int mi = 0; mi < 4; ++mi)
      #pragma unroll
      for (int ni = 0; ni < 4; ++ni)
        acc[mi][ni] = __builtin_amdgcn_mfma_f32_16x16x32_bf16(
            af[mi], bfv[ni], acc[mi][ni], 0, 0, 0);
  }
  // epilogue: scatter into flash layouts (Q scaled, bias added)
  #pragma unroll
  for (int mi = 0; mi < 4; ++mi) {
    const int oc = oc0 + wr * 64 + mi * 16 + (lane >> 4) * 4;  // mult of 4
    if (oc >= 384) continue;
    if (oc < 64) {
      const int hh = oc >> 3, e = oc & 7;
      float4 bb = *(const float4*)(bq + oc);
      #pragma unroll
      for (int ni = 0; ni < 4; ++ni) {
        const int l = n0 + wc * 64 + ni * 16 + (lane & 15);
        union { ushort u[4]; uint2 d; } pk;
        pk.u[0] = f2bf((acc[mi][ni][0] + bb.x) * 0.35355339059327373f);
        pk.u[1] = f2bf((acc[mi][ni][1] + bb.y) * 0.35355339059327373f);
        pk.u[2] = f2bf((acc[mi][ni][2] + bb.z) * 0.35355339059327373f);
        pk.u[3] = f2bf((acc[mi][ni][3] + bb.w) * 0.35355339059327373f);
        *(uint2*)(Qb + (((((size_t)b * 8 + hh) << 10) + l) << 5) + e) = pk.d;
      }
    } else if (oc < 128) {
      const int o2 = oc - 64, hh = o2 >> 3, e = o2 & 7;
      float4 bb = *(const float4*)(bk + o2);
      #pragma unroll
      for (int ni = 0; ni < 4; ++ni) {
        const int l = n0 + wc * 64 + ni * 16 + (lane & 15);
        union { ushort u[4]; uint2 d; } pk;
        pk.u[0] = f2bf(acc[mi][ni][0] + bb.x);
        pk.u[1] = f2bf(acc[mi][ni][1] + bb.y);
        pk.u[2] = f2bf(acc[mi][ni][2] + bb.z);
        pk.u[3] = f2bf(acc[mi][ni][3] + bb.w);
        *(uint2*)(Kb + (((((size_t)b * 8 + hh) << 10) + l) << 5) + e) = pk.d;
      }
    } else {
      const int o2 = oc - 128, hh = o2 >> 5, dd = o2 & 31;
      float4 bb = *(const float4*)(bv + o2);
      #pragma unroll
      for (int ni = 0; ni < 4; ++ni) {
        const int l = n0 + wc * 64 + ni * 16 + (lane & 15);
        ushort* vb = Vtb + ((((size_t)b * 8 + hh) * 32 + dd) << 10) + l;
        vb[0]      = f2bf(acc[mi][ni][0] + bb.x);
        vb[1024]   = f2bf(acc[mi][ni][1] + bb.y);
        vb[2048]   = f2bf(acc[mi][ni][2] + bb.z);
        vb[3072]   = f2bf(acc[mi][ni][3] + bb.w);
      }
    }
  }
}

// ---- P2: flash POS attention, bf16 MFMA, no barriers -----------------------
__global__ __launch_bounds__(256) void k_pos_flash(
    const ushort* __restrict__ Qb, const ushort* __restrict__ Kb,
    const ushort* __restrict__ Vtb, ushort* __restrict__ op_pad)
{
  const int qt = blockIdx.x, h = blockIdx.y, b = blockIdx.z;
  const int bh = b * 8 + h;
  const int tid = threadIdx.x, lane = tid & 63, wq = tid >> 6;
  const int c = lane & 15, g = lane >> 4;
  __shared__ __align__(16) ushort Ps[4][32][72];   // wave-private P tiles
  const int qbase = qt * 128 + wq * 32;
  bf16x8 qf[2];
  #pragma unroll
  for (int nt = 0; nt < 2; ++nt)
    qf[nt] = *(const bf16x8*)(Qb + (((size_t)bh << 10) + qbase + nt * 16 + c) * 32 + g * 8);
  f32x4 o[2][2];
  #pragma unroll
  for (int mt = 0; mt < 2; ++mt)
    #pragma unroll
    for (int nt = 0; nt < 2; ++nt) {
      f32x4 z = {0.f, 0.f, 0.f, 0.f};
      o[mt][nt] = z;
    }
  float m[2] = {-1e30f, -1e30f}, l[2] = {0.f, 0.f};
  const ushort* Kbh = Kb + ((size_t)bh << 15);
  const ushort* Vbh = Vtb + ((size_t)bh << 15);

  for (int kt = 0; kt < 16; ++kt) {
    const int kb0 = kt * 64;
    bf16x8 kf[4];
    #pragma unroll
    for (int mt = 0; mt < 4; ++mt)
      kf[mt] = *(const bf16x8*)(Kbh + (size_t)(kb0 + mt * 16 + c) * 32 + g * 8);
    f32x4 s[4][2];
    #pragma unroll
    for (int mt = 0; mt < 4; ++mt)
      #pragma unroll
      for (int nt = 0; nt < 2; ++nt) {
        f32x4 z = {0.f, 0.f, 0.f, 0.f};
        s[mt][nt] = __builtin_amdgcn_mfma_f32_16x16x32_bf16(kf[mt], qf[nt], z, 0, 0, 0);
      }
    #pragma unroll
    for (int nt = 0; nt < 2; ++nt) {
      float tmax = -1e30f;
      #pragma unroll
      for (int mt = 0; mt < 4; ++mt)
        #pragma unroll
        for (int r = 0; r < 4; ++r)
          tmax = fmaxf(tmax, s[mt][nt][r]);
      tmax = fmaxf(tmax, __shfl_xor(tmax, 16, 64));
      tmax = fmaxf(tmax, __shfl_xor(tmax, 32, 64));
      const float mn = fmaxf(m[nt], tmax);
      const float alpha = __expf(m[nt] - mn);
      m[nt] = mn;
      float rs = 0.f;
      #pragma unroll
      for (int mt = 0; mt < 4; ++mt) {
        union { ushort u[4]; uint2 d; } pk;
        #pragma unroll
        for (int r = 0; r < 4; ++r) {
          float p = __expf(s[mt][nt][r] - mn);
          rs += p;
          pk.u[r] = f2bf(p);
        }
        *(uint2*)&Ps[wq][nt * 16 + c][mt * 16 + g * 4] = pk.d;
      }
      rs += __shfl_xor(rs, 16, 64);
      rs += __shfl_xor(rs, 32, 64);
      l[nt] = l[nt] * alpha + rs;
      #pragma unroll
      for (int mt = 0; mt < 2; ++mt)
        #pragma unroll
        for (int r = 0; r < 4; ++r)
          o[mt][nt][r] *= alpha;
    }
    #pragma unroll
    for (int kc = 0; kc < 2; ++kc) {
      bf16x8 vf[2], pf[2];
      #pragma unroll
      for (int mt = 0; mt < 2; ++mt)
        vf[mt] = *(const bf16x8*)(Vbh + (size_t)(mt * 16 + c) * 1024 + kb0 + kc * 32 + g * 8);
      #pragma unroll
      for (int nt = 0; nt < 2; ++nt)
        pf[nt] = *(const bf16x8*)&Ps[wq][nt * 16 + c][kc * 32 + g * 8];
      #pragma unroll
      for (int mt = 0; mt < 2; ++mt)
        #pragma unroll
        for (int nt = 0; nt < 2; ++nt)
          o[mt][nt] = __builtin_amdgcn_mfma_f32_16x16x32_bf16(vf[mt], pf[nt], o[mt][nt], 0, 0, 0);
    }
  }
  #pragma unroll
  for (int nt = 0; nt < 2; ++nt) {
    const float linv = 1.f / l[nt];
    const int q = qbase + nt * 16 + c;
    const int y = q >> 5, x = q & 31;
    ushort* dst = op_pad + ((size_t)b * 1156 + (y + 1) * 34 + (x + 1)) * 256 + h * 32;
    #pragma unroll
    for (int mt = 0; mt < 2; ++mt) {
      union { ushort u[4]; uint2 d; } pk;
      #pragma unroll
      for (int r = 0; r < 4; ++r)
        pk.u[r] = f2bf(o[mt][nt][r] * linv);
      *(uint2*)(dst + mt * 16 + g * 4) = pk.d;
    }
  }
}

// ------ 3x3 conv as 9 shifted GEMMs over padded NHWC, bf16 MFMA -------------
// BN = B-tile rows (output pixels per block): 128 (orig) or 64 (2x grid).
template <int CIN, int S, int PW, int OUT_NHWC, int BN>
__global__ __launch_bounds__(256) void k_conv9_mfma(
    const ushort* __restrict__ in, const ushort* __restrict__ W9,
    const float* __restrict__ bias, float* __restrict__ out)
{
  constexpr int BQ = BN / 64;     // B staging issues (128->2, 64->1)
  constexpr int NI = BN / 32;     // per-wave ni count (128->4, 64->2)
  const int n0 = blockIdx.x * BN, oc0 = blockIdx.y * 128, b = blockIdx.z;
  const int tid = threadIdx.x, lane = tid & 63, w = tid >> 6;
  __shared__ ushort As[128][32], Bs[BN][32];
  const int wr = w >> 1, wc = w & 1;
  f32x4 acc[4][NI];
  #pragma unroll
  for (int mi = 0; mi < 4; ++mi)
    #pragma unroll
    for (int ni = 0; ni < NI; ++ni) {
      f32x4 z = {0.f, 0.f, 0.f, 0.f};
      acc[mi][ni] = z;
    }
  int rowqA[2], segqA[2];
  #pragma unroll
  for (int q = 0; q < 2; ++q) {
    int idx = w * 128 + q * 64 + lane;
    rowqA[q] = idx >> 2;
    segqA[q] = (idx & 3) * 8;
  }
  int rowqB[BQ], segqB[BQ], basep[BQ];
  #pragma unroll
  for (int q = 0; q < BQ; ++q) {
    int idx = (BQ == 2) ? (w * 128 + q * 64 + lane) : tid;
    rowqB[q] = idx >> 2;
    segqB[q] = (idx & 3) * 8;
    int n = n0 + rowqB[q];
    int y = n / S, x = n % S;
    basep[q] = y * PW + x;
  }
  const ushort* inb = in + (size_t)b * (PW * PW) * CIN;

  for (int t = 0; t < 9; ++t) {
    const int offp = (t / 3) * PW + (t % 3);
    const ushort* wt = W9 + (size_t)t * 256 * CIN;
    for (int kc = 0; kc < CIN; kc += 32) {
      __syncthreads();
      #pragma unroll
      for (int q = 0; q < 2; ++q) {
        const ushort* srcA = wt + (size_t)(oc0 + rowqA[q]) * CIN + kc + segqA[q];
        char* dstA = (char*)&As[0][0] + w * 2048 + q * 1024;
        __builtin_amdgcn_global_load_lds(
            (const __attribute__((address_space(1))) unsigned*)srcA,
            (__attribute__((address_space(3))) unsigned*)dstA, 16, 0, 0);
      }
      #pragma unroll
      for (int q = 0; q < BQ; ++q) {
        const ushort* srcB = inb + (size_t)(basep[q] + offp) * CIN + kc + segqB[q];
        char* dstB = (char*)&Bs[0][0] + w * (BQ * 1024) + q * 1024;
        __builtin_amdgcn_global_load_lds(
            (const __attribute__((address_space(1))) unsigned*)srcB,
            (__attribute__((address_space(3))) unsigned*)dstB, 16, 0, 0);
      }
      __syncthreads();
      bf16x8 af[4], bfv[NI];
      #pragma unroll
      for (int mi = 0; mi < 4; ++mi)
        af[mi] = *(const bf16x8*)&As[wr * 64 + mi * 16 + (lane & 15)][(lane >> 4) * 8];
      #pragma unroll
      for (int ni = 0; ni < NI; ++ni)
        bfv[ni] = *(const bf16x8*)&Bs[wc * (BN / 2) + ni * 16 + (lane & 15)][(lane >> 4) * 8];
      #pragma unroll
      for (int mi = 0; mi < 4; ++mi)
        #pragma unroll
        for (int ni = 0; ni < NI; ++ni)
          acc[mi][ni] = __builtin_amdgcn_mfma_f32_16x16x32_bf16(
              af[mi], bfv[ni], acc[mi][ni], 0, 0, 0);
    }
  }
  if (OUT_NHWC) {
    float* outb = out + (size_t)b * (S * S) * 256;
    #pragma unroll
    for (int mi = 0; mi < 4; ++mi) {
      const int oc = oc0 + wr * 64 + mi * 16 + (lane >> 4) * 4;
      float4 bb = *(const float4*)(bias + oc);
      #pragma unroll
      for (int ni = 0; ni < NI; ++ni) {
        const int n = n0 + wc * (BN / 2) + ni * 16 + (lane & 15);
        float4 v;
        v.x = acc[mi][ni][0] + bb.x;
        v.y = acc[mi][ni][1] + bb.y;
        v.z = acc[mi][ni][2] + bb.z;
        v.w = acc[mi][ni][3] + bb.w;
        *(float4*)(outb + (size_t)n * 256 + oc) = v;
      }
    }
  } else {
    float* outb = out + (size_t)b * 256 * (S * S);
    #pragma unroll
    for (int mi = 0; mi < 4; ++mi) {
      #pragma unroll
      for (int r = 0; r < 4; ++r) {
        int oc = oc0 + wr * 64 + mi * 16 + (lane >> 4) * 4 + r;
        float bb = bias[oc];
        #pragma unroll
        for (int ni = 0; ni < NI; ++ni) {
          int n = n0 + wc * (BN / 2) + ni * 16 + (lane & 15);
          outb[(size_t)oc * (S * S) + n] = acc[mi][ni][r] + bb;
        }
      }
    }
  }
}

// ------ fusion 3x3 conv, CIN=512: pipelined 128x256 tile, BK=64 -------------
// T3+T4: triple-buffered LDS, counted vmcnt (never 0 in steady state).
// T2: XOR swizzle via pre-swizzled global src into linear-dest
// global_load_lds; same XOR on ds_read. T5: setprio around MFMA cluster.
// r3 form (best measured 76.2us): reg-dbuf frags, sched_barrier only at
// phase end. r4's extra LOADS_FIRST pin regressed -> removed.
#define STAGE_CONV(s_, bi_)                                                    \
  {                                                                            \
    const int t_ = (s_) >> 3, kc_ = ((s_) & 7) << 6;                           \
    const ushort* wt_ = W9 + t_ * 131072 + kc_;                                \
    const ushort* ib_ = inb + ((t_ / 3) * 66 + (t_ % 3)) * 512 + kc_;          \
    _Pragma("unroll")                                                          \
    for (int q_ = 0; q_ < 2; ++q_) {                                           \
      __builtin_amdgcn_global_load_lds(                                        \
          (const __attribute__((address_space(1))) unsigned*)(wt_ + aInv[q_]), \
          (__attribute__((address_space(3))) unsigned*)                        \
              ((char*)lds + (bi_) * 16384 + (w * 16 + q_ * 8) * 128),          \
          16, 0, 0);                                                           \
    }                                                                          \
    _Pragma("unroll")                                                          \
    for (int q_ = 0; q_ < 4; ++q_) {                                           \
      __builtin_amdgcn_global_load_lds(                                        \
          (const __attribute__((address_space(1))) unsigned*)(ib_ + bInv[q_]), \
          (__attribute__((address_space(3))) unsigned*)                        \
              ((char*)lds + 49152 + (bi_) * 32768 + (w * 32 + q_ * 8) * 128),  \
          16, 0, 0);                                                           \
    }                                                                          \
  }

#define READ_FRAGS(rb_, AF_, BF_)                                              \
  {                                                                            \
    const ushort* As_ = lds + (rb_) * 8192 + (wm * 64 + c) * 64;               \
    const ushort* Bs_ = lds + 24576 + (rb_) * 16384 + (wn * 64 + c) * 64;      \
    _Pragma("unroll")                                                          \
    for (int mi_ = 0; mi_ < 4; ++mi_) {                                        \
      AF_[mi_][0] = *(const bf16x8*)(As_ + mi_ * 1024 + okh0);                 \
      AF_[mi_][1] = *(const bf16x8*)(As_ + mi_ * 1024 + okh1);                 \
    }                                                                          \
    _Pragma("unroll")                                                          \
    for (int ni_ = 0; ni_ < 4; ++ni_) {                                        \
      BF_[ni_][0] = *(const bf16x8*)(Bs_ + ni_ * 1024 + okh0);                 \
      BF_[ni_][1] = *(const bf16x8*)(Bs_ + ni_ * 1024 + okh1);                 \
    }                                                                          \
  }

#define MFMA_SET(AF_, BF_)                                                     \
  {                                                                            \
    __builtin_amdgcn_s_setprio(1);                                             \
    _Pragma("unroll")                                                          \
    for (int mi_ = 0; mi_ < 4; ++mi_)                                          \
      _Pragma("unroll")                                                        \
      for (int ni_ = 0; ni_ < 4; ++ni_) {                                      \
        acc[mi_][ni_] = __builtin_amdgcn_mfma_f32_16x16x32_bf16(               \
            AF_[mi_][0], BF_[ni_][0], acc[mi_][ni_], 0, 0, 0);                 \
        acc[mi_][ni_] = __builtin_amdgcn_mfma_f32_16x16x32_bf16(               \
            AF_[mi_][1], BF_[ni_][1], acc[mi_][ni_], 0, 0, 0);                 \
      }                                                                        \
    __builtin_amdgcn_s_setprio(0);                                             \
  }

#define PHASE_END(vm_)                                                         \
  {                                                                            \
    asm volatile("s_waitcnt lgkmcnt(0)" ::: "memory");                         \
    asm volatile("s_waitcnt vmcnt(" #vm_ ")" ::: "memory");                    \
    __builtin_amdgcn_sched_barrier(0);                                         \
    __builtin_amdgcn_s_barrier();                                              \
  }

__global__ __launch_bounds__(512, 2) void k_conv9_pipe(
    const ushort* __restrict__ in, const ushort* __restrict__ W9,
    const float* __restrict__ bias, float* __restrict__ out)
{
  const int n0 = blockIdx.x * 256, oc0 = blockIdx.y * 128, b = blockIdx.z;
  const int tid = threadIdx.x, lane = tid & 63, w = tid >> 6;
  const int wm = w >> 2, wn = w & 3;            // 2M x 4N waves, 64x64 each
  const int g = lane >> 4, c = lane & 15;
  // A bufs: 3 x [128][64] bf16 @ byte 0 ; B bufs: 3 x [256][64] bf16 @ 49152
  __shared__ __align__(16) ushort lds[73728];   // 144 KiB
  const ushort* inb = in + (size_t)b * 4356 * 512;

  // per-lane staging invariants (row owned by this lane per issue; source
  // column pre-XORed so linear LDS dest + XORed ds_read = conflict-free)
  const int l8 = lane >> 3, lx = lane & 7;
  int aInv[2], bInv[4];
  #pragma unroll
  for (int q = 0; q < 2; ++q) {
    const int row = w * 16 + q * 8 + l8;
    const int cx = (((lx << 4) ^ ((row & 7) << 4)) >> 1);
    aInv[q] = (oc0 + row) * 512 + cx;
  }
  #pragma unroll
  for (int q = 0; q < 4; ++q) {
    const int row = w * 32 + q * 8 + l8;
    const int n = n0 + row;
    const int y = n >> 6, x = n & 63;
    const int cx = (((lx << 4) ^ ((row & 7) << 4)) >> 1);
    bInv[q] = (y * 66 + x) * 512 + cx;
  }

  // fragment-read column terms: row&7 == c&7 for every mi/ni (mi*16, w*64
  // are 0 mod 8) -> single XOR term shared by all fragment reads
  const int sx = (c & 7) << 3;
  const int okh0 = (g * 8) ^ sx;
  const int okh1 = (32 + g * 8) ^ sx;

  f32x4 acc[4][4];
  #pragma unroll
  for (int mi = 0; mi < 4; ++mi)
    #pragma unroll
    for (int ni = 0; ni < 4; ++ni) {
      f32x4 z = {0.f, 0.f, 0.f, 0.f};
      acc[mi][ni] = z;
    }

  bf16x8 afE[4][2], bfE[4][2], afO[4][2], bfO[4][2];

  // prologue: stage 3 buffers; read frags(0) into E-set
  STAGE_CONV(0, 0);
  STAGE_CONV(1, 1);
  STAGE_CONV(2, 2);
  asm volatile("s_waitcnt vmcnt(12)" ::: "memory");   // stage(0) done
  __builtin_amdgcn_sched_barrier(0);
  __builtin_amdgcn_s_barrier();
  READ_FRAGS(0, afE, bfE);
  PHASE_END(6);                                       // stage(1) done

  int rb = 1;   // buffer holding frags for the NEXT phase
  for (int p = 0; p < 68; p += 2) {
    // phase p (even): load O-set for p+1, stage p+3, compute E-set
    READ_FRAGS(rb, afO, bfO);
    { int sb = rb + 2; if (sb >= 3) sb -= 3; STAGE_CONV(p + 3, sb); }
    MFMA_SET(afE, bfE);
    PHASE_END(6);
    ++rb; if (rb == 3) rb = 0;
    // phase p+1 (odd): load E-set for p+2, stage p+4, compute O-set
    READ_FRAGS(rb, afE, bfE);
    { int sb = rb + 2; if (sb >= 3) sb -= 3; STAGE_CONV(p + 4, sb); }
    MFMA_SET(afO, bfO);
    PHASE_END(6);
    ++rb; if (rb == 3) rb = 0;
  }
  // phase 68: read 69, stage 71, compute E
  READ_FRAGS(rb, afO, bfO);
  { int sb = rb + 2; if (sb >= 3) sb -= 3; STAGE_CONV(71, sb); }
  MFMA_SET(afE, bfE);
  PHASE_END(6);                                       // stage(70) done
  ++rb; if (rb == 3) rb = 0;
  // phase 69: read 70, compute O
  READ_FRAGS(rb, afE, bfE);
  MFMA_SET(afO, bfO);
  PHASE_END(0);                                       // stage(71) done
  ++rb; if (rb == 3) rb = 0;
  // phase 70: read 71, compute E
  READ_FRAGS(rb, afO, bfO);
  MFMA_SET(afE, bfE);
  asm volatile("s_waitcnt lgkmcnt(0)" ::: "memory");
  __builtin_amdgcn_sched_barrier(0);
  __builtin_amdgcn_s_barrier();
  // phase 71: compute O
  MFMA_SET(afO, bfO);

  // epilogue: NCHW fp32 + bias
  float* outb = out + (size_t)b * 1048576;
  #pragma unroll
  for (int mi = 0; mi < 4; ++mi) {
    const int oc = oc0 + wm * 64 + mi * 16 + g * 4;
    float4 bb = *(const float4*)(bias + oc);
    #pragma unroll
    for (int ni = 0; ni < 4; ++ni) {
      const int n = n0 + wn * 64 + ni * 16 + c;
      outb[(size_t)(oc + 0) * 4096 + n] = acc[mi][ni][0] + bb.x;
      outb[(size_t)(oc + 1) * 4096 + n] = acc[mi][ni][1] + bb.y;
      outb[(size_t)(oc + 2) * 4096 + n] = acc[mi][ni][2] + bb.z;
      outb[(size_t)(oc + 3) * 4096 + n] = acc[mi][ni][3] + bb.w;
    }
  }
}

// ---- P4: bilinear x2 upsample + residual -> fused_pad[.., ch 0:256] --------
__global__ __launch_bounds__(256) void k_upsample_nhwc(
    const float* __restrict__ xpos, const float* __restrict__ opc,
    const float* __restrict__ gamma, ushort* __restrict__ fused)
{
  const int t = blockIdx.x * 256 + threadIdx.x;  // 8*4096*64
  const int c = (t & 63) * 4;
  const int pix = (t >> 6) & 4095;
  const int b = t >> 18;
  const int y = pix >> 6, xx = pix & 63;
  const int my = y >> 1;
  const int y0 = (y & 1) ? my : my - 1;
  const float fy = (y & 1) ? 0.25f : 0.75f;
  const int mx = xx >> 1;
  const int x0 = (xx & 1) ? mx : mx - 1;
  const float fx = (xx & 1) ? 0.25f : 0.75f;
  const int y0c = max(y0, 0), y1c = min(y0 + 1, 31);
  const int x0c = max(x0, 0), x1c = min(x0 + 1, 31);
  const float* base = opc + (size_t)b * 1024 * 256 + c;
  float4 v00 = *(const float4*)(base + (size_t)(y0c * 32 + x0c) * 256);
  float4 v01 = *(const float4*)(base + (size_t)(y0c * 32 + x1c) * 256);
  float4 v10 = *(const float4*)(base + (size_t)(y1c * 32 + x0c) * 256);
  float4 v11 = *(const float4*)(base + (size_t)(y1c * 32 + x1c) * 256);
  const float w00 = (1.f - fy) * (1.f - fx), w01 = (1.f - fy) * fx;
  const float w10 = fy * (1.f - fx), w11 = fy * fx;
  const float g = gamma[0];
  const float* xr = xpos + ((size_t)b * 256 + c) * 4096 + pix;
  union { ushort u[4]; uint2 q; } o;
  o.u[0] = f2bf(xr[0]          + g * (w00 * v00.x + w01 * v01.x + w10 * v10.x + w11 * v11.x));
  o.u[1] = f2bf(xr[4096]       + g * (w00 * v00.y + w01 * v01.y + w10 * v10.y + w11 * v11.y));
  o.u[2] = f2bf(xr[2 * 4096]   + g * (w00 * v00.z + w01 * v01.z + w10 * v10.z + w11 * v11.z));
  o.u[3] = f2bf(xr[3 * 4096]   + g * (w00 * v00.w + w01 * v01.w + w10 * v10.w + w11 * v11.w));
  *(uint2*)(fused + ((size_t)b * 4356 + (y + 1) * 66 + (xx + 1)) * 512 + c) = o.q;
}

// ------- C0: CHA q/k/v grouped 2x2 projections -> bf16 (half-batch) ---------
__global__ __launch_bounds__(256) void k_cha_proj(
    const float* __restrict__ x,
    const float* __restrict__ Wq, const float* __restrict__ bq,
    const float* __restrict__ Wk, const float* __restrict__ bk,
    const float* __restrict__ Wv, const float* __restrict__ bv,
    ushort* __restrict__ Qc, ushort* __restrict__ Kc, ushort* __restrict__ Vt)
{
  const int t = blockIdx.x * 256 + threadIdx.x;
  const int bl = t >> 16;
  const int g  = (t >> 8) & 255;
  const int lq = t & 255;
  const int i = lq >> 3, j4 = (lq & 7) << 2;
  const float* xb = x + (((size_t)bl * 256 + g) << 12) + (2 * i) * 64 + 2 * j4;
  union { float4 v[2]; float f[8]; } xr0, xr1;
  xr0.v[0] = *(const float4*)(xb);
  xr0.v[1] = *(const float4*)(xb + 4);
  xr1.v[0] = *(const float4*)(xb + 64);
  xr1.v[1] = *(const float4*)(xb + 68);
  const int bhl = bl * 8 + (g >> 5);
  const int c2b = (g & 31) * 8;
  const int l0 = i * 32 + j4;
  #pragma unroll
  for (int h = 0; h < 8; ++h) {
    float4 w4 = *(const float4*)(Wq + g * 32 + h * 4);
    float bb = bq[g * 8 + h];
    union { ushort u[4]; uint2 q; } o;
    #pragma unroll
    for (int jj = 0; jj < 4; ++jj) {
      float v = xr0.f[2 * jj] * w4.x + xr0.f[2 * jj + 1] * w4.y
              + xr1.f[2 * jj] * w4.z + xr1.f[2 * jj + 1] * w4.w + bb;
      o.u[jj] = f2bf(v * 0.03125f);
    }
    *(uint2*)(Qc + (((size_t)bhl * 256 + c2b + h) << 10) + l0) = o.q;
  }
  #pragma unroll
  for (int h = 0; h < 8; ++h) {
    float4 w4 = *(const float4*)(Wk + g * 32 + h * 4);
    float bb = bk[g * 8 + h];
    union { ushort u[4]; uint2 q; } o;
    #pragma unroll
    for (int jj = 0; jj < 4; ++jj) {
      float v = xr0.f[2 * jj] * w4.x + xr0.f[2 * jj + 1] * w4.y
              + xr1.f[2 * jj] * w4.z + xr1.f[2 * jj + 1] * w4.w + bb;
      o.u[jj] = f2bf(v);
    }
    *(uint2*)(Kc + (((size_t)bhl * 256 + c2b + h) << 10) + l0) = o.q;
  }
  ushort vo[4][8];
  #pragma unroll
  for (int h = 0; h < 8; ++h) {
    float4 w4 = *(const float4*)(Wv + g * 32 + h * 4);
    float bb = bv[g * 8 + h];
    #pragma unroll
    for (int jj = 0; jj < 4; ++jj) {
      float v = xr0.f[2 * jj] * w4.x + xr0.f[2 * jj + 1] * w4.y
              + xr1.f[2 * jj] * w4.z + xr1.f[2 * jj + 1] * w4.w + bb;
      vo[jj][h] = f2bf(v);
    }
  }
  #pragma unroll
  for (int jj = 0; jj < 4; ++jj)
    *(uint4*)(Vt + ((size_t)bhl << 18) + (size_t)(l0 + jj) * 256 + c2b) =
        *(uint4*)&vo[jj][0];
}

// ------- C1: scores = qc @ kc^T, bf16 MFMA, K=1024 (half-batch) -------------
// d-tile 64 -> grid (2,4,32) = 256 blocks (was 128 = half GPU idle)
__global__ __launch_bounds__(256) void k_cha_scores_mfma(
    const ushort* __restrict__ Qc, const ushort* __restrict__ Kc,
    float* __restrict__ S)
{
  const int c0 = blockIdx.x * 128, d0 = blockIdx.y * 64, bhl = blockIdx.z;
  const int tid = threadIdx.x, lane = tid & 63, w = tid >> 6;
  __shared__ ushort As[128][32], Bs[64][32];
  const ushort* Ab = Qc + ((size_t)bhl * 256 + c0) * 1024;
  const ushort* Bb = Kc + ((size_t)bhl * 256 + d0) * 1024;
  const int wr = w >> 1, wc = w & 1;
  f32x4 acc[4][2];
  #pragma unroll
  for (int mi = 0; mi < 4; ++mi)
    #pragma unroll
    for (int ni = 0; ni < 2; ++ni) {
      f32x4 z = {0.f, 0.f, 0.f, 0.f};
      acc[mi][ni] = z;
    }
  for (int kc = 0; kc < 1024; kc += 32) {
    __syncthreads();
    #pragma unroll
    for (int q = 0; q < 2; ++q) {
      int idx = w * 128 + q * 64 + lane;
      int row = idx >> 2, seg = idx & 3;
      const ushort* srcA = Ab + (size_t)row * 1024 + kc + seg * 8;
      char* dstA = (char*)&As[0][0] + w * 2048 + q * 1024;
      __builtin_amdgcn_global_load_lds(
          (const __attribute__((address_space(1))) unsigned*)srcA,
          (__attribute__((address_space(3))) unsigned*)dstA, 16, 0, 0);
    }
    {
      int idx = tid;                 // 64 rows x 4 segs = 256
      int row = idx >> 2, seg = idx & 3;
      const ushort* srcB = Bb + (size_t)row * 1024 + kc + seg * 8;
      char* dstB = (char*)&Bs[0][0] + w * 1024;
      __builtin_amdgcn_global_load_lds(
          (const __attribute__((address_space(1))) unsigned*)srcB,
          (__attribute__((address_space(3))) unsigned*)dstB, 16, 0, 0);
    }
    __syncthreads();
    bf16x8 af[4], bfv[2];
    #pragma unroll
    for (int mi = 0; mi < 4; ++mi)
      af[mi] = *(const bf16x8*)&As[wr * 64 + mi * 16 + (lane & 15)][(lane >> 4) * 8];
    #pragma unroll
    for (int ni = 0; ni < 2; ++ni)
      bfv[ni] = *(const bf16x8*)&Bs[wc * 32 + ni * 16 + (lane & 15)][(lane >> 4) * 8];
    #pragma unroll
    for (int mi = 0; mi < 4; ++mi)
      #pragma unroll
      for (int ni = 0; ni < 2; ++ni)
        acc[mi][ni] = __builtin_amdgcn_mfma_f32_16x16x32_bf16(
            af[mi], bfv[ni], acc[mi][ni], 0, 0, 0);
  }
  float* Sb = S + ((size_t)bhl << 16);
  #pragma unroll
  for (int mi = 0; mi < 4; ++mi)
    #pragma unroll
    for (int r = 0; r < 4; ++r) {
      int c = c0 + wr * 64 + mi * 16 + (lane >> 4) * 4 + r;
      #pragma unroll
      for (int ni = 0; ni < 2; ++ni) {
        int d = d0 + wc * 32 + ni * 16 + (lane & 15);
        Sb[(size_t)c * 256 + d] = acc[mi][ni][r];
      }
    }
}

// ------- C2: row softmax over 256 -> bf16 P ---------------------------------
__global__ __launch_bounds__(256) void k_softmax_p(
    const float* __restrict__ S, ushort* __restrict__ P)
{
  const int row = blockIdx.x * 4 + (threadIdx.x >> 6);
  const int lane = threadIdx.x & 63;
  const float* r = S + (size_t)row * 256;
  float4 v = *(const float4*)(r + lane * 4);
  float m = fmaxf(fmaxf(v.x, v.y), fmaxf(v.z, v.w));
  #pragma unroll
  for (int off = 32; off; off >>= 1) m = fmaxf(m, __shfl_xor(m, off, 64));
  v.x = __expf(v.x - m); v.y = __expf(v.y - m);
  v.z = __expf(v.z - m); v.w = __expf(v.w - m);
  float s = v.x + v.y + v.z + v.w;
  #pragma unroll
  for (int off = 32; off; off >>= 1) s += __shfl_xor(s, off, 64);
  const float inv = 1.f / s;
  union { ushort u[4]; uint2 q; } o;
  o.u[0] = f2bf(v.x * inv); o.u[1] = f2bf(v.y * inv);
  o.u[2] = f2bf(v.z * inv); o.u[3] = f2bf(v.w * inv);
  *(uint2*)(P + (size_t)row * 256 + lane * 4) = o.q;
}

// -- C3: oc = P @ vcT (MFMA) + grouped ConvT + residual -> fused_pad NHWC ----
__global__ __launch_bounds__(256) void k_cha_pv(
    const ushort* __restrict__ P, const ushort* __restrict__ Vt,
    const float* __restrict__ x,
    const float* __restrict__ Wt, const float* __restrict__ bt,
    const float* __restrict__ gamma, ushort* __restrict__ fused, int bbase)
{
  const int n0 = blockIdx.x * 128, c0 = blockIdx.y * 128, bhl = blockIdx.z;
  const int b = bbase + (bhl >> 3), h = bhl & 7;
  const int tid = threadIdx.x, lane = tid & 63, w = tid >> 6;
  __shared__ ushort As[128][32], Bs[128][32];
  __shared__ ushort Ot[512][16];
  __shared__ float wt_s[16][32];
  __shared__ float bt_s[16];
  const int gp_base = h * 32 + (c0 >> 3);
  {
    int e = tid;
    wt_s[e >> 5][e & 31] = Wt[(size_t)gp_base * 32 + e];
    e += 256;
    wt_s[e >> 5][e & 31] = Wt[(size_t)gp_base * 32 + e];
    if (tid < 16) bt_s[tid] = bt[gp_base + tid];
  }
  const ushort* Ab = P + (((size_t)bhl << 8) + c0) * 256;
  const ushort* Bb = Vt + ((size_t)bhl << 18) + (size_t)n0 * 256;
  const int wr = w >> 1, wc = w & 1;
  f32x4 acc[4][4];
  #pragma unroll
  for (int mi = 0; mi < 4; ++mi)
    #pragma unroll
    for (int ni = 0; ni < 4; ++ni) {
      f32x4 z = {0.f, 0.f, 0.f, 0.f};
      acc[mi][ni] = z;
    }
  for (int kc = 0; kc < 256; kc += 32) {
    __syncthreads();
    #pragma unroll
    for (int q = 0; q < 2; ++q) {
      int idx = w * 128 + q * 64 + lane;
      int row = idx >> 2, seg = idx & 3;
      const ushort* srcA = Ab + (size_t)row * 256 + kc + seg * 8;
      const ushort* srcB = Bb + (size_t)row * 256 + kc + seg * 8;
      char* dstA = (char*)&As[0][0] + w * 2048 + q * 1024;
      char* dstB = (char*)&Bs[0][0] + w * 2048 + q * 1024;
      __builtin_amdgcn_global_load_lds(
          (const __attribute__((address_space(1))) unsigned*)srcA,
          (__attribute__((address_space(3))) unsigned*)dstA, 16, 0, 0);
      __builtin_amdgcn_global_load_lds(
          (const __attribute__((address_space(1))) unsigned*)srcB,
          (__attribute__((address_space(3))) unsigned*)dstB, 16, 0, 0);
    }
    __syncthreads();
    bf16x8 af[4], bfv[4];
    #pragma unroll
    for (int mi = 0; mi < 4; ++mi)
      af[mi] = *(const bf16x8*)&As[wr * 64 + mi * 16 + (lane & 15)][(lane >> 4) * 8];
    #pragma unroll
    for (int ni = 0; ni < 4; ++ni)
      bfv[ni] = *(const bf16x8*)&Bs[wc * 64 + ni * 16 + (lane & 15)][(lane >> 4) * 8];
    #pragma unroll
    for (int mi = 0; mi < 4; ++mi)
      #pragma unroll
      for (int ni = 0; ni < 4; ++ni)
        acc[mi][ni] = __builtin_amdgcn_mfma_f32_16x16x32_bf16(
            af[mi], bfv[ni], acc[mi][ni], 0, 0, 0);
  }
  const float gm = gamma[0];
  const int col = lane & 15, q = lane >> 4;
  #pragma unroll
  for (int mi = 0; mi < 4; ++mi) {
    const int gloc = wr * 8 + mi * 2 + (q >> 1);
    const int gp = gp_base + gloc;
    const float btv = bt_s[gloc];
    #pragma unroll
    for (int ni = 0; ni < 4; ++ni) {
      float pa[4] = {0.f, 0.f, 0.f, 0.f};
      #pragma unroll
      for (int r = 0; r < 4; ++r) {
        const int i2 = (q & 1) * 4 + r;
        const float a = acc[mi][ni][r];
        pa[0] += a * wt_s[gloc][i2 * 4 + 0];
        pa[1] += a * wt_s[gloc][i2 * 4 + 1];
        pa[2] += a * wt_s[gloc][i2 * 4 + 2];
        pa[3] += a * wt_s[gloc][i2 * 4 + 3];
      }
      float v0 = pa[0] + __shfl_xor(pa[0], 16, 64);
      float v1 = pa[1] + __shfl_xor(pa[1], 16, 64);
      float v2 = pa[2] + __shfl_xor(pa[2], 16, 64);
      float v3 = pa[3] + __shfl_xor(pa[3], 16, 64);
      const int lloc = wc * 64 + ni * 16 + col;
      const int l = n0 + lloc;
      const int p = l >> 5, j = l & 31;
      const int y = 2 * p + (q & 1);
      const float va = (q & 1) ? v2 : v0;
      const float vb = (q & 1) ? v3 : v1;
      const float* xc = x + (((size_t)b * 256 + gp) << 12) + (y << 6) + 2 * j;
      const int lp = (lloc << 2) + (q & 1) * 2;
      Ot[lp][gloc]     = f2bf(xc[0] + gm * (va + btv));
      Ot[lp + 1][gloc] = f2bf(xc[1] + gm * (vb + btv));
    }
  }
  __syncthreads();
  #pragma unroll
  for (int pp2 = 0; pp2 < 2; ++pp2) {
    const int pixl = tid * 2 + pp2;
    const int lloc = pixl >> 2;
    const int l = n0 + lloc;
    const int p = l >> 5, j = l & 31;
    const int yy = 2 * p + ((pixl >> 1) & 1) + 1;
    const int xx = 2 * j + (pixl & 1) + 1;
    const uint4* src = (const uint4*)&Ot[pixl][0];
    uint4* dst = (uint4*)(fused + ((size_t)b * 4356 + yy * 66 + xx) * 512 + 256 + gp_base);
    dst[0] = src[0];
    dst[1] = src[1];
  }
}

extern "C" void kernel_launch(void* const* d_in, const int* in_sizes, int n_in,
                              void* d_out, int out_size, void* d_ws, size_t ws_size,
                              hipStream_t stream)
{
  (void)in_sizes; (void)n_in; (void)out_size; (void)ws_size;
  const float* qkv_pos   = (const float*)d_in[0];
  const float* qkv_cha   = (const float*)d_in[1];
  const float* Wq_pos    = (const float*)d_in[2];
  const float* bq_pos    = (const float*)d_in[3];
  const float* Wk_pos    = (const float*)d_in[4];
  const float* bk_pos    = (const float*)d_in[5];
  const float* Wv_pos    = (const float*)d_in[6];
  const float* bv_pos    = (const float*)d_in[7];
  const float* Wo_pos    = (const float*)d_in[8];
  const float* bo_pos    = (const float*)d_in[9];
  const float* gamma_pos = (const float*)d_in[10];
  const float* Wq_cha    = (const float*)d_in[11];
  const float* bq_cha    = (const float*)d_in[12];
  const float* Wk_cha    = (const float*)d_in[13];
  const float* bk_cha    = (const float*)d_in[14];
  const float* Wv_cha    = (const float*)d_in[15];
  const float* bv_cha    = (const float*)d_in[16];
  const float* Wt_cha    = (const float*)d_in[17];
  const float* bt_cha    = (const float*)d_in[18];
  const float* gamma_cha = (const float*)d_in[19];
  const float* Wf        = (const float*)d_in[20];
  const float* bf        = (const float*)d_in[21];
  float* out = (float*)d_out;

  float* ws = (float*)d_ws;
  ushort* Wpf9    = (ushort*)ws;
  ushort* Wpo9    = (ushort*)(ws + 589824);
  // POS scratch
  ushort* Qb      = (ushort*)(ws + 884736);    // [64][1024][32] bf16
  ushort* Kb      = (ushort*)(ws + 1933312);   // [64][1024][32] bf16
  ushort* Vtb     = (ushort*)(ws + 2981888);   // [64][32][1024] bf16
  ushort* op_pad  = (ushort*)(ws + 4030464);   // 2367488 ushorts
  float*  op_conv = ws + 5214208;              // NHWC fp32 [8][1024][256]
  ushort* Ap      = (ushort*)(ws + 7311360);   // [8][1024][1024] bf16
  // CHA scratch (aliases POS region after it is consumed)
  ushort* qcb     = (ushort*)(ws + 884736);
  ushort* kcb     = (ushort*)(ws + 5079040);
  ushort* vcT     = (ushort*)(ws + 9273344);
  float*  attn_c  = ws + 13467648;
  ushort* Pb      = (ushort*)(ws + 15564800);
  ushort* fusedb  = (ushort*)(ws + 16613376);  // NHWC padded [8][66*66][512]
  ushort* Wqkvp   = (ushort*)(ws + 25534464);  // [384][1024] bf16

  // merged zero-init: fusedb ring + op_pad ring + Qb (replaces 2 memsets)
  k_zero_init<<<dim3(1676), 256, 0, stream>>>(fusedb, op_pad, Qb);
  // merged weight pre-pack (one launch)
  k_prep_all<<<dim3(8448), 256, 0, stream>>>(Wf, Wo_pos, Wq_pos, Wk_pos,
      Wv_pos, Wpf9, Wpo9, Wqkvp);
  // POS branch
  k_pack_pos<<<dim3(2048), 256, 0, stream>>>(qkv_pos, Ap);
  k_pos_qkv_mfma<<<dim3(8, 3, 8), 256, 0, stream>>>(Ap, Wqkvp,
      bq_pos, bk_pos, bv_pos, Qb, Kb, Vtb);
  k_pos_flash<<<dim3(8, 8, 8), 256, 0, stream>>>(Qb, Kb, Vtb, op_pad);
  // Wo conv: BN=64 -> 256 blocks (full GPU; was 128)
  k_conv9_mfma<256, 32, 34, 1, 64><<<dim3(16, 2, 8), 256, 0, stream>>>(
      op_pad, Wpo9, bo_pos, op_conv);
  k_upsample_nhwc<<<dim3(8192), 256, 0, stream>>>(qkv_pos, op_conv, gamma_pos, fusedb);
  // CHA branch, two half-batches
  for (int half = 0; half < 2; ++half) {
    const float* xh = qkv_cha + (size_t)half * 4 * 256 * 4096;
    k_cha_proj<<<dim3(1024), 256, 0, stream>>>(xh, Wq_cha, bq_cha,
        Wk_cha, bk_cha, Wv_cha, bv_cha, qcb, kcb, vcT);
    k_cha_scores_mfma<<<dim3(2, 4, 32), 256, 0, stream>>>(qcb, kcb, attn_c);
    k_softmax_p<<<dim3(2048), 256, 0, stream>>>(attn_c, Pb);
    k_cha_pv<<<dim3(8, 2, 32), 256, 0, stream>>>(Pb, vcT, qkv_cha,
        Wt_cha, bt_cha, gamma_cha, fusedb, half * 4);
  }
  // fusion conv: pipelined 128x256 tile (r3 form), 256 blocks = 1/CU
  k_conv9_pipe<<<dim3(16, 2, 8), 512, 0, stream>>>(fusedb, Wpf9, bf, out);
}

// Round 6
// 459.359 us; speedup vs baseline: 1.2570x; 1.1321x over previous
//
#include <hip/hip_runtime.h>
#include <math.h>

// Shapes: B=8, C=256, H=W=64, HQ=WQ=32, L=1024, NH=8, hd=8, dv=32
//
// Workspace (float units):
//   Wpf9 bf16[9][256][512] @ 0        (589824 f)
//   Wpo9 bf16[9][256][256] @ 589824   (294912 f)
//   region2 @ 884736 (POS scratch, later aliased by CHA scratch)
//   fused_pad bf16[8][66*66][512] @ 16613376 (8921088 f)
//   Wqkv_p bf16[384][1024] @ 25534464 (196608 f)

typedef __attribute__((ext_vector_type(8))) short bf16x8;
typedef __attribute__((ext_vector_type(4))) float f32x4;

__device__ __forceinline__ ushort f2bf(float f) {
  union { float f; unsigned u; } v; v.f = f;
  unsigned r = (v.u + 0x7FFFu + ((v.u >> 16) & 1u)) >> 16;
  return (ushort)r;
}

// -------- merged init: zero rings/Qb + all weight pre-packs (one launch) ----
// zero range 0: fused_pad 66x66 border ring       (133120 uint4)
// zero range 1: op_pad 34x34 border ring          (33792 uint4)
// zero range 2: Qb full region (pad lanes = 0)    (262144 uint4)
// prep range 0: Wf -> Wpf9[t][oc][512]            (1179648 el)
// prep range 1: Wo -> Wpo9[t][oc][256]            (589824 el)
// prep range 2: Wq/Wk/Wv -> Wqkvp[384][1024]      (393216 el)
__global__ __launch_bounds__(256) void k_init_all(
    ushort* __restrict__ fused, ushort* __restrict__ op_pad,
    ushort* __restrict__ Qb,
    const float* __restrict__ Wf, const float* __restrict__ Wo,
    const float* __restrict__ Wq, const float* __restrict__ Wk,
    const float* __restrict__ Wv,
    ushort* __restrict__ Wpf9, ushort* __restrict__ Wpo9,
    ushort* __restrict__ Wqkvp)
{
  const int t = blockIdx.x * 256 + threadIdx.x;   // 10124*256 = 2591744
  uint4 z = {0u, 0u, 0u, 0u};
  if (t < 133120) {
    const int e = t & 63;
    const int pi = (t >> 6) % 260;
    const int b = t / 16640;
    int y, x;
    if (pi < 66)       { y = 0;            x = pi; }
    else if (pi < 132) { y = 65;           x = pi - 66; }
    else if (pi < 196) { y = pi - 132 + 1; x = 0; }
    else               { y = pi - 196 + 1; x = 65; }
    *(uint4*)(fused + ((size_t)b * 4356 + y * 66 + x) * 512 + e * 8) = z;
  } else if (t < 166912) {
    const int j = t - 133120;
    const int e = j & 31;
    const int pi = (j >> 5) % 132;
    const int b = j / 4224;
    int y, x;
    if (pi < 34)       { y = 0;            x = pi; }
    else if (pi < 68)  { y = 33;           x = pi - 34; }
    else if (pi < 100) { y = pi - 68 + 1;  x = 0; }
    else               { y = pi - 100 + 1; x = 33; }
    *(uint4*)(op_pad + ((size_t)b * 1156 + y * 34 + x) * 256 + e * 8) = z;
  } else if (t < 429056) {
    const int j = t - 166912;
    *(uint4*)(Qb + (size_t)j * 8) = z;
  } else {
    const int i = t - 429056;                     // over 2162688
    if (i < 1179648) {
      const int tt = i / 131072;
      const int r = i - tt * 131072;
      const int oc = r >> 9, c = r & 511;
      Wpf9[i] = f2bf(Wf[((size_t)oc * 512 + c) * 9 + tt]);
    } else if (i < 1769472) {
      const int j = i - 1179648;
      const int tt = j / 65536;
      const int r = j - tt * 65536;
      const int oc = r >> 8, c = r & 255;
      Wpo9[j] = f2bf(Wo[((size_t)oc * 256 + c) * 9 + tt]);
    } else {
      const int j = i - 1769472;                  // 384*1024
      const int o = j >> 10, k = j & 1023;
      float v;
      if (o < 64)       v = Wq[(size_t)o * 1024 + k];
      else if (o < 128) v = Wk[(size_t)(o - 64) * 1024 + k];
      else              v = Wv[(size_t)(o - 128) * 1024 + k];
      Wqkvp[j] = f2bf(v);
    }
  }
}

// -------- patchify x (2x2 stride-2 im2col) -> bf16 Ap[b][l][1024] -----------
// LDS-transposed: coalesced float4 reads (lanes along px), bf16 LDS tile,
// coalesced uint2 writes (lanes along c). Replaces the scattered-write
// version (64 lanes x 8B at 2KB stride).
__global__ __launch_bounds__(256) void k_pack_pos(
    const float* __restrict__ x, ushort* __restrict__ Ap)
{
  const int i = blockIdx.x, b = blockIdx.y;   // grid (32, 8)
  const int tid = threadIdx.x;
  __shared__ ushort xs[256][132];             // 264B rows (8B-aligned pad)
  #pragma unroll 4
  for (int it = 0; it < 32; ++it) {
    const int slot = it * 256 + tid;          // 8192 float4 slots
    const int px4 = slot & 15, r = (slot >> 4) & 1, c = slot >> 5;
    float4 v = *(const float4*)(x + (((size_t)b * 256 + c) << 12)
                                + (2 * i + r) * 64 + px4 * 4);
    union { ushort u[4]; uint2 d; } pk;
    pk.u[0] = f2bf(v.x); pk.u[1] = f2bf(v.y);
    pk.u[2] = f2bf(v.z); pk.u[3] = f2bf(v.w);
    *(uint2*)&xs[c][r * 64 + px4 * 4] = pk.d;
  }
  __syncthreads();
  ushort* dst = Ap + ((((size_t)b << 10) + i * 32) << 10);
  const int c = tid;
  #pragma unroll 4
  for (int j = 0; j < 32; ++j) {
    uint2 o;
    o.x = *(const uint*)&xs[c][2 * j];        // {x[2i][2j], x[2i][2j+1]}
    o.y = *(const uint*)&xs[c][64 + 2 * j];   // {x[2i+1][2j], x[2i+1][2j+1]}
    *(uint2*)(dst + (size_t)j * 1024 + c * 4) = o;
  }
}

// ---- P1: POS q/k/v projection as bf16 MFMA GEMM [384x1024]x[1024xL] --------
__global__ __launch_bounds__(256) void k_pos_qkv_mfma(
    const ushort* __restrict__ Ap, const ushort* __restrict__ Wqkv,
    const float* __restrict__ bq, const float* __restrict__ bk,
    const float* __restrict__ bv,
    ushort* __restrict__ Qb, ushort* __restrict__ Kb, ushort* __restrict__ Vtb)
{
  const int n0 = blockIdx.x * 128, oc0 = blockIdx.y * 128, b = blockIdx.z;
  const int tid = threadIdx.x, lane = tid & 63, w = tid >> 6;
  __shared__ ushort As[128][32], Bs[128][32];
  const ushort* Abw = Wqkv + (size_t)oc0 * 1024;
  const ushort* Bb  = Ap + (((size_t)b << 10) + n0) * 1024;
  const int wr = w >> 1, wc = w & 1;
  f32x4 acc[4][4];
  #pragma unroll
  for (int mi = 0; mi < 4; ++mi)
    #pragma unroll
    for (int ni = 0; ni < 4; ++ni) {
      f32x4 z = {0.f, 0.f, 0.f, 0.f};
      acc[mi][ni] = z;
    }
  for (int kc = 0; kc < 1024; kc += 32) {
    __syncthreads();
    #pragma unroll
    for (int q = 0; q < 2; ++q) {
      int idx = w * 128 + q * 64 + lane;
      int row = idx >> 2, seg = idx & 3;
      const ushort* srcA = Abw + (size_t)row * 1024 + kc + seg * 8;
      const ushort* srcB = Bb + (size_t)row * 1024 + kc + seg * 8;
      char* dstA = (char*)&As[0][0] + w * 2048 + q * 1024;
      char* dstB = (char*)&Bs[0][0] + w * 2048 + q * 1024;
      __builtin_amdgcn_global_load_lds(
          (const __attribute__((address_space(1))) unsigned*)srcA,
          (__attribute__((address_space(3))) unsigned*)dstA, 16, 0, 0);
      __builtin_amdgcn_global_load_lds(
          (const __attribute__((address_space(1))) unsigned*)srcB,
          (__attribute__((address_space(3))) unsigned*)dstB, 16, 0, 0);
    }
    __syncthreads();
    bf16x8 af[4], bfv[4];
    #pragma unroll
    for (int mi = 0; mi < 4; ++mi)
      af[mi] = *(const bf16x8*)&As[wr * 64 + mi * 16 + (lane & 15)][(lane >> 4) * 8];
    #pragma unroll
    for (int ni = 0; ni < 4; ++ni)
      bfv[ni] = *(const bf16x8*)&Bs[wc * 64 + ni * 16 + (lane & 15)][(lane >> 4) * 8];
    #pragma unroll
    for (int mi = 0; mi < 4; ++mi)
      #pragma unroll
      for (int ni = 0; ni < 4; ++ni)
        acc[mi][ni] = __builtin_amdgcn_mfma_f32_16x16x32_bf16(
            af[mi], bfv[ni], acc[mi][ni], 0, 0, 0);
  }
  // epilogue: scatter into flash layouts (Q scaled, bias added)
  #pragma unroll
  for (int mi = 0; mi < 4; ++mi) {
    const int oc = oc0 + wr * 64 + mi * 16 + (lane >> 4) * 4;  // mult of 4
    if (oc >= 384) continue;
    if (oc < 64) {
      const int hh = oc >> 3, e = oc & 7;
      float4 bb = *(const float4*)(bq + oc);
      #pragma unroll
      for (int ni = 0; ni < 4; ++ni) {
        const int l = n0 + wc * 64 + ni * 16 + (lane & 15);
        union { ushort u[4]; uint2 d; } pk;
        pk.u[0] = f2bf((acc[mi][ni][0] + bb.x) * 0.35355339059327373f);
        pk.u[1] = f2bf((acc[mi][ni][1] + bb.y) * 0.35355339059327373f);
        pk.u[2] = f2bf((acc[mi][ni][2] + bb.z) * 0.35355339059327373f);
        pk.u[3] = f2bf((acc[mi][ni][3] + bb.w) * 0.35355339059327373f);
        *(uint2*)(Qb + (((((size_t)b * 8 + hh) << 10) + l) << 5) + e) = pk.d;
      }
    } else if (oc < 128) {
      const int o2 = oc - 64, hh = o2 >> 3, e = o2 & 7;
      float4 bb = *(const float4*)(bk + o2);
      #pragma unroll
      for (int ni = 0; ni < 4; ++ni) {
        const int l = n0 + wc * 64 + ni * 16 + (lane & 15);
        union { ushort u[4]; uint2 d; } pk;
        pk.u[0] = f2bf(acc[mi][ni][0] + bb.x);
        pk.u[1] = f2bf(acc[mi][ni][1] + bb.y);
        pk.u[2] = f2bf(acc[mi][ni][2] + bb.z);
        pk.u[3] = f2bf(acc[mi][ni][3] + bb.w);
        *(uint2*)(Kb + (((((size_t)b * 8 + hh) << 10) + l) << 5) + e) = pk.d;
      }
    } else {
      const int o2 = oc - 128, hh = o2 >> 5, dd = o2 & 31;
      float4 bb = *(const float4*)(bv + o2);
      #pragma unroll
      for (int ni = 0; ni < 4; ++ni) {
        const int l = n0 + wc * 64 + ni * 16 + (lane & 15);
        ushort* vb = Vtb + ((((size_t)b * 8 + hh) * 32 + dd) << 10) + l;
        vb[0]      = f2bf(acc[mi][ni][0] + bb.x);
        vb[1024]   = f2bf(acc[mi][ni][1] + bb.y);
        vb[2048]   = f2bf(acc[mi][ni][2] + bb.z);
        vb[3072]   = f2bf(acc[mi][ni][3] + bb.w);
      }
    }
  }
}

// ---- P2: flash POS attention, bf16 MFMA, no barriers -----------------------
__global__ __launch_bounds__(256) void k_pos_flash(
    const ushort* __restrict__ Qb, const ushort* __restrict__ Kb,
    const ushort* __restrict__ Vtb, ushort* __restrict__ op_pad)
{
  const int qt = blockIdx.x, h = blockIdx.y, b = blockIdx.z;
  const int bh = b * 8 + h;
  const int tid = threadIdx.x, lane = tid & 63, wq = tid >> 6;
  const int c = lane & 15, g = lane >> 4;
  __shared__ __align__(16) ushort Ps[4][32][72];   // wave-private P tiles
  const int qbase = qt * 128 + wq * 32;
  bf16x8 qf[2];
  #pragma unroll
  for (int nt = 0; nt < 2; ++nt)
    qf[nt] = *(const bf16x8*)(Qb + (((size_t)bh << 10) + qbase + nt * 16 + c) * 32 + g * 8);
  f32x4 o[2][2];
  #pragma unroll
  for (int mt = 0; mt < 2; ++mt)
    #pragma unroll
    for (int nt = 0; nt < 2; ++nt) {
      f32x4 z = {0.f, 0.f, 0.f, 0.f};
      o[mt][nt] = z;
    }
  float m[2] = {-1e30f, -1e30f}, l[2] = {0.f, 0.f};
  const ushort* Kbh = Kb + ((size_t)bh << 15);
  const ushort* Vbh = Vtb + ((size_t)bh << 15);

  for (int kt = 0; kt < 16; ++kt) {
    const int kb0 = kt * 64;
    bf16x8 kf[4];
    #pragma unroll
    for (int mt = 0; mt < 4; ++mt)
      kf[mt] = *(const bf16x8*)(Kbh + (size_t)(kb0 + mt * 16 + c) * 32 + g * 8);
    f32x4 s[4][2];
    #pragma unroll
    for (int mt = 0; mt < 4; ++mt)
      #pragma unroll
      for (int nt = 0; nt < 2; ++nt) {
        f32x4 z = {0.f, 0.f, 0.f, 0.f};
        s[mt][nt] = __builtin_amdgcn_mfma_f32_16x16x32_bf16(kf[mt], qf[nt], z, 0, 0, 0);
      }
    #pragma unroll
    for (int nt = 0; nt < 2; ++nt) {
      float tmax = -1e30f;
      #pragma unroll
      for (int mt = 0; mt < 4; ++mt)
        #pragma unroll
        for (int r = 0; r < 4; ++r)
          tmax = fmaxf(tmax, s[mt][nt][r]);
      tmax = fmaxf(tmax, __shfl_xor(tmax, 16, 64));
      tmax = fmaxf(tmax, __shfl_xor(tmax, 32, 64));
      const float mn = fmaxf(m[nt], tmax);
      const float alpha = __expf(m[nt] - mn);
      m[nt] = mn;
      float rs = 0.f;
      #pragma unroll
      for (int mt = 0; mt < 4; ++mt) {
        union { ushort u[4]; uint2 d; } pk;
        #pragma unroll
        for (int r = 0; r < 4; ++r) {
          float p = __expf(s[mt][nt][r] - mn);
          rs += p;
          pk.u[r] = f2bf(p);
        }
        *(uint2*)&Ps[wq][nt * 16 + c][mt * 16 + g * 4] = pk.d;
      }
      rs += __shfl_xor(rs, 16, 64);
      rs += __shfl_xor(rs, 32, 64);
      l[nt] = l[nt] * alpha + rs;
      #pragma unroll
      for (int mt = 0; mt < 2; ++mt)
        #pragma unroll
        for (int r = 0; r < 4; ++r)
          o[mt][nt][r] *= alpha;
    }
    #pragma unroll
    for (int kc = 0; kc < 2; ++kc) {
      bf16x8 vf[2], pf[2];
      #pragma unroll
      for (int mt = 0; mt < 2; ++mt)
        vf[mt] = *(const bf16x8*)(Vbh + (size_t)(mt * 16 + c) * 1024 + kb0 + kc * 32 + g * 8);
      #pragma unroll
      for (int nt = 0; nt < 2; ++nt)
        pf[nt] = *(const bf16x8*)&Ps[wq][nt * 16 + c][kc * 32 + g * 8];
      #pragma unroll
      for (int mt = 0; mt < 2; ++mt)
        #pragma unroll
        for (int nt = 0; nt < 2; ++nt)
          o[mt][nt] = __builtin_amdgcn_mfma_f32_16x16x32_bf16(vf[mt], pf[nt], o[mt][nt], 0, 0, 0);
    }
  }
  #pragma unroll
  for (int nt = 0; nt < 2; ++nt) {
    const float linv = 1.f / l[nt];
    const int q = qbase + nt * 16 + c;
    const int y = q >> 5, x = q & 31;
    ushort* dst = op_pad + ((size_t)b * 1156 + (y + 1) * 34 + (x + 1)) * 256 + h * 32;
    #pragma unroll
    for (int mt = 0; mt < 2; ++mt) {
      union { ushort u[4]; uint2 d; } pk;
      #pragma unroll
      for (int r = 0; r < 4; ++r)
        pk.u[r] = f2bf(o[mt][nt][r] * linv);
      *(uint2*)(dst + mt * 16 + g * 4) = pk.d;
    }
  }
}

// ------ 3x3 conv as 9 shifted GEMMs over padded NHWC, bf16 MFMA -------------
// BN = B-tile rows (output pixels per block): 128 (orig) or 64 (2x grid).
template <int CIN, int S, int PW, int OUT_NHWC, int BN>
__global__ __launch_bounds__(256) void k_conv9_mfma(
    const ushort* __restrict__ in, const ushort* __restrict__ W9,
    const float* __restrict__ bias, float* __restrict__ out)
{
  constexpr int BQ = BN / 64;     // B staging issues (128->2, 64->1)
  constexpr int NI = BN / 32;     // per-wave ni count (128->4, 64->2)
  const int n0 = blockIdx.x * BN, oc0 = blockIdx.y * 128, b = blockIdx.z;
  const int tid = threadIdx.x, lane = tid & 63, w = tid >> 6;
  __shared__ ushort As[128][32], Bs[BN][32];
  const int wr = w >> 1, wc = w & 1;
  f32x4 acc[4][NI];
  #pragma unroll
  for (int mi = 0; mi < 4; ++mi)
    #pragma unroll
    for (int ni = 0; ni < NI; ++ni) {
      f32x4 z = {0.f, 0.f, 0.f, 0.f};
      acc[mi][ni] = z;
    }
  int rowqA[2], segqA[2];
  #pragma unroll
  for (int q = 0; q < 2; ++q) {
    int idx = w * 128 + q * 64 + lane;
    rowqA[q] = idx >> 2;
    segqA[q] = (idx & 3) * 8;
  }
  int rowqB[BQ], segqB[BQ], basep[BQ];
  #pragma unroll
  for (int q = 0; q < BQ; ++q) {
    int idx = (BQ == 2) ? (w * 128 + q * 64 + lane) : tid;
    rowqB[q] = idx >> 2;
    segqB[q] = (idx & 3) * 8;
    int n = n0 + rowqB[q];
    int y = n / S, x = n % S;
    basep[q] = y * PW + x;
  }
  const ushort* inb = in + (size_t)b * (PW * PW) * CIN;

  for (int t = 0; t < 9; ++t) {
    const int offp = (t / 3) * PW + (t % 3);
    const ushort* wt = W9 + (size_t)t * 256 * CIN;
    for (int kc = 0; kc < CIN; kc += 32) {
      __syncthreads();
      #pragma unroll
      for (int q = 0; q < 2; ++q) {
        const ushort* srcA = wt + (size_t)(oc0 + rowqA[q]) * CIN + kc + segqA[q];
        char* dstA = (char*)&As[0][0] + w * 2048 + q * 1024;
        __builtin_amdgcn_global_load_lds(
            (const __attribute__((address_space(1))) unsigned*)srcA,
            (__attribute__((address_space(3))) unsigned*)dstA, 16, 0, 0);
      }
      #pragma unroll
      for (int q = 0; q < BQ; ++q) {
        const ushort* srcB = inb + (size_t)(basep[q] + offp) * CIN + kc + segqB[q];
        char* dstB = (char*)&Bs[0][0] + w * (BQ * 1024) + q * 1024;
        __builtin_amdgcn_global_load_lds(
            (const __attribute__((address_space(1))) unsigned*)srcB,
            (__attribute__((address_space(3))) unsigned*)dstB, 16, 0, 0);
      }
      __syncthreads();
      bf16x8 af[4], bfv[NI];
      #pragma unroll
      for (int mi = 0; mi < 4; ++mi)
        af[mi] = *(const bf16x8*)&As[wr * 64 + mi * 16 + (lane & 15)][(lane >> 4) * 8];
      #pragma unroll
      for (int ni = 0; ni < NI; ++ni)
        bfv[ni] = *(const bf16x8*)&Bs[wc * (BN / 2) + ni * 16 + (lane & 15)][(lane >> 4) * 8];
      #pragma unroll
      for (int mi = 0; mi < 4; ++mi)
        #pragma unroll
        for (int ni = 0; ni < NI; ++ni)
          acc[mi][ni] = __builtin_amdgcn_mfma_f32_16x16x32_bf16(
              af[mi], bfv[ni], acc[mi][ni], 0, 0, 0);
    }
  }
  if (OUT_NHWC) {
    float* outb = out + (size_t)b * (S * S) * 256;
    #pragma unroll
    for (int mi = 0; mi < 4; ++mi) {
      const int oc = oc0 + wr * 64 + mi * 16 + (lane >> 4) * 4;
      float4 bb = *(const float4*)(bias + oc);
      #pragma unroll
      for (int ni = 0; ni < NI; ++ni) {
        const int n = n0 + wc * (BN / 2) + ni * 16 + (lane & 15);
        float4 v;
        v.x = acc[mi][ni][0] + bb.x;
        v.y = acc[mi][ni][1] + bb.y;
        v.z = acc[mi][ni][2] + bb.z;
        v.w = acc[mi][ni][3] + bb.w;
        *(float4*)(outb + (size_t)n * 256 + oc) = v;
      }
    }
  } else {
    float* outb = out + (size_t)b * 256 * (S * S);
    #pragma unroll
    for (int mi = 0; mi < 4; ++mi) {
      #pragma unroll
      for (int r = 0; r < 4; ++r) {
        int oc = oc0 + wr * 64 + mi * 16 + (lane >> 4) * 4 + r;
        float bb = bias[oc];
        #pragma unroll
        for (int ni = 0; ni < NI; ++ni) {
          int n = n0 + wc * (BN / 2) + ni * 16 + (lane & 15);
          outb[(size_t)oc * (S * S) + n] = acc[mi][ni][r] + bb;
        }
      }
    }
  }
}

// ------ fusion 3x3 conv, CIN=512: pipelined 128x256 tile, BK=64 -------------
// r3 form (best measured 76.2us): triple-buffered LDS, counted vmcnt, XOR
// swizzle via pre-swizzled global src, setprio, reg-dbuf frags,
// sched_barrier only at phase end.
#define STAGE_CONV(s_, bi_)                                                    \
  {                                                                            \
    const int t_ = (s_) >> 3, kc_ = ((s_) & 7) << 6;                           \
    const ushort* wt_ = W9 + t_ * 131072 + kc_;                                \
    const ushort* ib_ = inb + ((t_ / 3) * 66 + (t_ % 3)) * 512 + kc_;          \
    _Pragma("unroll")                                                          \
    for (int q_ = 0; q_ < 2; ++q_) {                                           \
      __builtin_amdgcn_global_load_lds(                                        \
          (const __attribute__((address_space(1))) unsigned*)(wt_ + aInv[q_]), \
          (__attribute__((address_space(3))) unsigned*)                        \
              ((char*)lds + (bi_) * 16384 + (w * 16 + q_ * 8) * 128),          \
          16, 0, 0);                                                           \
    }                                                                          \
    _Pragma("unroll")                                                          \
    for (int q_ = 0; q_ < 4; ++q_) {                                           \
      __builtin_amdgcn_global_load_lds(                                        \
          (const __attribute__((address_space(1))) unsigned*)(ib_ + bInv[q_]), \
          (__attribute__((address_space(3))) unsigned*)                        \
              ((char*)lds + 49152 + (bi_) * 32768 + (w * 32 + q_ * 8) * 128),  \
          16, 0, 0);                                                           \
    }                                                                          \
  }

#define READ_FRAGS(rb_, AF_, BF_)                                              \
  {                                                                            \
    const ushort* As_ = lds + (rb_) * 8192 + (wm * 64 + c) * 64;               \
    const ushort* Bs_ = lds + 24576 + (rb_) * 16384 + (wn * 64 + c) * 64;      \
    _Pragma("unroll")                                                          \
    for (int mi_ = 0; mi_ < 4; ++mi_) {                                        \
      AF_[mi_][0] = *(const bf16x8*)(As_ + mi_ * 1024 + okh0);                 \
      AF_[mi_][1] = *(const bf16x8*)(As_ + mi_ * 1024 + okh1);                 \
    }                                                                          \
    _Pragma("unroll")                                                          \
    for (int ni_ = 0; ni_ < 4; ++ni_) {                                        \
      BF_[ni_][0] = *(const bf16x8*)(Bs_ + ni_ * 1024 + okh0);                 \
      BF_[ni_][1] = *(const bf16x8*)(Bs_ + ni_ * 1024 + okh1);                 \
    }                                                                          \
  }

#define MFMA_SET(AF_, BF_)                                                     \
  {                                                                            \
    __builtin_amdgcn_s_setprio(1);                                             \
    _Pragma("unroll")                                                          \
    for (int mi_ = 0; mi_ < 4; ++mi_)                                          \
      _Pragma("unroll")                                                        \
      for (int ni_ = 0; ni_ < 4; ++ni_) {                                      \
        acc[mi_][ni_] = __builtin_amdgcn_mfma_f32_16x16x32_bf16(               \
            AF_[mi_][0], BF_[ni_][0], acc[mi_][ni_], 0, 0, 0);                 \
        acc[mi_][ni_] = __builtin_amdgcn_mfma_f32_16x16x32_bf16(               \
            AF_[mi_][1], BF_[ni_][1], acc[mi_][ni_], 0, 0, 0);                 \
      }                                                                        \
    __builtin_amdgcn_s_setprio(0);                                             \
  }

#define PHASE_END(vm_)                                                         \
  {                                                                            \
    asm volatile("s_waitcnt lgkmcnt(0)" ::: "memory");                         \
    asm volatile("s_waitcnt vmcnt(" #vm_ ")" ::: "memory");                    \
    __builtin_amdgcn_sched_barrier(0);                                         \
    __builtin_amdgcn_s_barrier();                                              \
  }

__global__ __launch_bounds__(512, 2) void k_conv9_pipe(
    const ushort* __restrict__ in, const ushort* __restrict__ W9,
    const float* __restrict__ bias, float* __restrict__ out)
{
  const int n0 = blockIdx.x * 256, oc0 = blockIdx.y * 128, b = blockIdx.z;
  const int tid = threadIdx.x, lane = tid & 63, w = tid >> 6;
  const int wm = w >> 2, wn = w & 3;            // 2M x 4N waves, 64x64 each
  const int g = lane >> 4, c = lane & 15;
  // A bufs: 3 x [128][64] bf16 @ byte 0 ; B bufs: 3 x [256][64] bf16 @ 49152
  __shared__ __align__(16) ushort lds[73728];   // 144 KiB
  const ushort* inb = in + (size_t)b * 4356 * 512;

  const int l8 = lane >> 3, lx = lane & 7;
  int aInv[2], bInv[4];
  #pragma unroll
  for (int q = 0; q < 2; ++q) {
    const int row = w * 16 + q * 8 + l8;
    const int cx = (((lx << 4) ^ ((row & 7) << 4)) >> 1);
    aInv[q] = (oc0 + row) * 512 + cx;
  }
  #pragma unroll
  for (int q = 0; q < 4; ++q) {
    const int row = w * 32 + q * 8 + l8;
    const int n = n0 + row;
    const int y = n >> 6, x = n & 63;
    const int cx = (((lx << 4) ^ ((row & 7) << 4)) >> 1);
    bInv[q] = (y * 66 + x) * 512 + cx;
  }

  const int sx = (c & 7) << 3;
  const int okh0 = (g * 8) ^ sx;
  const int okh1 = (32 + g * 8) ^ sx;

  f32x4 acc[4][4];
  #pragma unroll
  for (int mi = 0; mi < 4; ++mi)
    #pragma unroll
    for (int ni = 0; ni < 4; ++ni) {
      f32x4 z = {0.f, 0.f, 0.f, 0.f};
      acc[mi][ni] = z;
    }

  bf16x8 afE[4][2], bfE[4][2], afO[4][2], bfO[4][2];

  STAGE_CONV(0, 0);
  STAGE_CONV(1, 1);
  STAGE_CONV(2, 2);
  asm volatile("s_waitcnt vmcnt(12)" ::: "memory");   // stage(0) done
  __builtin_amdgcn_sched_barrier(0);
  __builtin_amdgcn_s_barrier();
  READ_FRAGS(0, afE, bfE);
  PHASE_END(6);                                       // stage(1) done

  int rb = 1;   // buffer holding frags for the NEXT phase
  for (int p = 0; p < 68; p += 2) {
    READ_FRAGS(rb, afO, bfO);
    { int sb = rb + 2; if (sb >= 3) sb -= 3; STAGE_CONV(p + 3, sb); }
    MFMA_SET(afE, bfE);
    PHASE_END(6);
    ++rb; if (rb == 3) rb = 0;
    READ_FRAGS(rb, afE, bfE);
    { int sb = rb + 2; if (sb >= 3) sb -= 3; STAGE_CONV(p + 4, sb); }
    MFMA_SET(afO, bfO);
    PHASE_END(6);
    ++rb; if (rb == 3) rb = 0;
  }
  READ_FRAGS(rb, afO, bfO);
  { int sb = rb + 2; if (sb >= 3) sb -= 3; STAGE_CONV(71, sb); }
  MFMA_SET(afE, bfE);
  PHASE_END(6);                                       // stage(70) done
  ++rb; if (rb == 3) rb = 0;
  READ_FRAGS(rb, afE, bfE);
  MFMA_SET(afO, bfO);
  PHASE_END(0);                                       // stage(71) done
  ++rb; if (rb == 3) rb = 0;
  READ_FRAGS(rb, afO, bfO);
  MFMA_SET(afE, bfE);
  asm volatile("s_waitcnt lgkmcnt(0)" ::: "memory");
  __builtin_amdgcn_sched_barrier(0);
  __builtin_amdgcn_s_barrier();
  MFMA_SET(afO, bfO);

  // epilogue: NCHW fp32 + bias
  float* outb = out + (size_t)b * 1048576;
  #pragma unroll
  for (int mi = 0; mi < 4; ++mi) {
    const int oc = oc0 + wm * 64 + mi * 16 + g * 4;
    float4 bb = *(const float4*)(bias + oc);
    #pragma unroll
    for (int ni = 0; ni < 4; ++ni) {
      const int n = n0 + wn * 64 + ni * 16 + c;
      outb[(size_t)(oc + 0) * 4096 + n] = acc[mi][ni][0] + bb.x;
      outb[(size_t)(oc + 1) * 4096 + n] = acc[mi][ni][1] + bb.y;
      outb[(size_t)(oc + 2) * 4096 + n] = acc[mi][ni][2] + bb.z;
      outb[(size_t)(oc + 3) * 4096 + n] = acc[mi][ni][3] + bb.w;
    }
  }
}

// ---- P4: bilinear x2 upsample + residual -> fused_pad[.., ch 0:256] --------
// LDS-staged rewrite: block = (y-row, 128-ch half, b). Coalesced float4
// reads of xpos (lanes along px) and opc (lanes along c); transposed LDS
// reads; coalesced uint2 writes (lanes along c). Replaces the scattered
// version (64 lanes x 4B at 16KB stride on xpos).
__global__ __launch_bounds__(256) void k_upsample_nhwc(
    const float* __restrict__ xpos, const float* __restrict__ opc,
    const float* __restrict__ gamma, ushort* __restrict__ fused)
{
  const int y = blockIdx.x, h0 = blockIdx.y * 128, b = blockIdx.z; // (64,2,8)
  const int tid = threadIdx.x;
  __shared__ float xs[128 * 65];     // [c'][px 0..63], row pad 65
  __shared__ float os[64 * 132];     // [pxe][c' 0..127], row pad 132
  const int my = y >> 1;
  const int y0 = (y & 1) ? my : my - 1;
  const float fy = (y & 1) ? 0.25f : 0.75f;
  const int y0c = max(y0, 0), y1c = min(y0 + 1, 31);
  // stage xpos row y (128 channels, coalesced)
  #pragma unroll
  for (int it = 0; it < 8; ++it) {
    const int slot = it * 256 + tid;       // 2048 float4 slots
    const int px4 = slot & 15, cp = slot >> 4;
    float4 v = *(const float4*)(xpos + (((size_t)b * 256 + h0 + cp) << 12)
                                + y * 64 + px4 * 4);
    xs[cp * 65 + px4 * 4 + 0] = v.x;
    xs[cp * 65 + px4 * 4 + 1] = v.y;
    xs[cp * 65 + px4 * 4 + 2] = v.z;
    xs[cp * 65 + px4 * 4 + 3] = v.w;
  }
  // stage opc rows y0c (pxe 0..31) and y1c (pxe 32..63), coalesced
  #pragma unroll
  for (int it = 0; it < 8; ++it) {
    const int slot = it * 256 + tid;       // 2048 float4 slots
    const int cc4 = slot & 31, pxe = slot >> 5;
    const int row = (pxe < 32) ? y0c : y1c;
    const int col = pxe & 31;
    float4 v = *(const float4*)(opc + ((size_t)b * 1024 + row * 32 + col) * 256
                                + h0 + cc4 * 4);
    *(float4*)&os[pxe * 132 + cc4 * 4] = v;
  }
  __syncthreads();
  const float g = gamma[0];
  #pragma unroll
  for (int it = 0; it < 8; ++it) {
    const int xx = it * 8 + (tid >> 5);
    const int c4 = tid & 31;
    const int mx = xx >> 1;
    const int x0 = (xx & 1) ? mx : mx - 1;
    const float fx = (xx & 1) ? 0.25f : 0.75f;
    const int x0c = max(x0, 0), x1c = min(x0 + 1, 31);
    float4 v00 = *(const float4*)&os[x0c * 132 + c4 * 4];
    float4 v01 = *(const float4*)&os[x1c * 132 + c4 * 4];
    float4 v10 = *(const float4*)&os[(32 + x0c) * 132 + c4 * 4];
    float4 v11 = *(const float4*)&os[(32 + x1c) * 132 + c4 * 4];
    const float w00 = (1.f - fy) * (1.f - fx), w01 = (1.f - fy) * fx;
    const float w10 = fy * (1.f - fx), w11 = fy * fx;
    union { ushort u[4]; uint2 q; } o;
    o.u[0] = f2bf(xs[(c4 * 4 + 0) * 65 + xx]
                  + g * (w00 * v00.x + w01 * v01.x + w10 * v10.x + w11 * v11.x));
    o.u[1] = f2bf(xs[(c4 * 4 + 1) * 65 + xx]
                  + g * (w00 * v00.y + w01 * v01.y + w10 * v10.y + w11 * v11.y));
    o.u[2] = f2bf(xs[(c4 * 4 + 2) * 65 + xx]
                  + g * (w00 * v00.z + w01 * v01.z + w10 * v10.z + w11 * v11.z));
    o.u[3] = f2bf(xs[(c4 * 4 + 3) * 65 + xx]
                  + g * (w00 * v00.w + w01 * v01.w + w10 * v10.w + w11 * v11.w));
    *(uint2*)(fused + ((size_t)b * 4356 + (y + 1) * 66 + (xx + 1)) * 512
              + h0 + c4 * 4) = o.q;
  }
}

// ------- C0: CHA q/k/v grouped 2x2 projections -> bf16 (half-batch) ---------
__global__ __launch_bounds__(256) void k_cha_proj(
    const float* __restrict__ x,
    const float* __restrict__ Wq, const float* __restrict__ bq,
    const float* __restrict__ Wk, const float* __restrict__ bk,
    const float* __restrict__ Wv, const float* __restrict__ bv,
    ushort* __restrict__ Qc, ushort* __restrict__ Kc, ushort* __restrict__ Vt)
{
  const int t = blockIdx.x * 256 + threadIdx.x;
  const int bl = t >> 16;
  const int g  = (t >> 8) & 255;
  const int lq = t & 255;
  const int i = lq >> 3, j4 = (lq & 7) << 2;
  const float* xb = x + (((size_t)bl * 256 + g) << 12) + (2 * i) * 64 + 2 * j4;
  union { float4 v[2]; float f[8]; } xr0, xr1;
  xr0.v[0] = *(const float4*)(xb);
  xr0.v[1] = *(const float4*)(xb + 4);
  xr1.v[0] = *(const float4*)(xb + 64);
  xr1.v[1] = *(const float4*)(xb + 68);
  const int bhl = bl * 8 + (g >> 5);
  const int c2b = (g & 31) * 8;
  const int l0 = i * 32 + j4;
  #pragma unroll
  for (int h = 0; h < 8; ++h) {
    float4 w4 = *(const float4*)(Wq + g * 32 + h * 4);
    float bb = bq[g * 8 + h];
    union { ushort u[4]; uint2 q; } o;
    #pragma unroll
    for (int jj = 0; jj < 4; ++jj) {
      float v = xr0.f[2 * jj] * w4.x + xr0.f[2 * jj + 1] * w4.y
              + xr1.f[2 * jj] * w4.z + xr1.f[2 * jj + 1] * w4.w + bb;
      o.u[jj] = f2bf(v * 0.03125f);
    }
    *(uint2*)(Qc + (((size_t)bhl * 256 + c2b + h) << 10) + l0) = o.q;
  }
  #pragma unroll
  for (int h = 0; h < 8; ++h) {
    float4 w4 = *(const float4*)(Wk + g * 32 + h * 4);
    float bb = bk[g * 8 + h];
    union { ushort u[4]; uint2 q; } o;
    #pragma unroll
    for (int jj = 0; jj < 4; ++jj) {
      float v = xr0.f[2 * jj] * w4.x + xr0.f[2 * jj + 1] * w4.y
              + xr1.f[2 * jj] * w4.z + xr1.f[2 * jj + 1] * w4.w + bb;
      o.u[jj] = f2bf(v);
    }
    *(uint2*)(Kc + (((size_t)bhl * 256 + c2b + h) << 10) + l0) = o.q;
  }
  ushort vo[4][8];
  #pragma unroll
  for (int h = 0; h < 8; ++h) {
    float4 w4 = *(const float4*)(Wv + g * 32 + h * 4);
    float bb = bv[g * 8 + h];
    #pragma unroll
    for (int jj = 0; jj < 4; ++jj) {
      float v = xr0.f[2 * jj] * w4.x + xr0.f[2 * jj + 1] * w4.y
              + xr1.f[2 * jj] * w4.z + xr1.f[2 * jj + 1] * w4.w + bb;
      vo[jj][h] = f2bf(v);
    }
  }
  #pragma unroll
  for (int jj = 0; jj < 4; ++jj)
    *(uint4*)(Vt + ((size_t)bhl << 18) + (size_t)(l0 + jj) * 256 + c2b) =
        *(uint4*)&vo[jj][0];
}

// ------- C1: scores = qc @ kc^T, bf16 MFMA, K=1024 (half-batch) -------------
// d-tile 64 -> grid (2,4,32) = 256 blocks
__global__ __launch_bounds__(256) void k_cha_scores_mfma(
    const ushort* __restrict__ Qc, const ushort* __restrict__ Kc,
    float* __restrict__ S)
{
  const int c0 = blockIdx.x * 128, d0 = blockIdx.y * 64, bhl = blockIdx.z;
  const int tid = threadIdx.x, lane = tid & 63, w = tid >> 6;
  __shared__ ushort As[128][32], Bs[64][32];
  const ushort* Ab = Qc + ((size_t)bhl * 256 + c0) * 1024;
  const ushort* Bb = Kc + ((size_t)bhl * 256 + d0) * 1024;
  const int wr = w >> 1, wc = w & 1;
  f32x4 acc[4][2];
  #pragma unroll
  for (int mi = 0; mi < 4; ++mi)
    #pragma unroll
    for (int ni = 0; ni < 2; ++ni) {
      f32x4 z = {0.f, 0.f, 0.f, 0.f};
      acc[mi][ni] = z;
    }
  for (int kc = 0; kc < 1024; kc += 32) {
    __syncthreads();
    #pragma unroll
    for (int q = 0; q < 2; ++q) {
      int idx = w * 128 + q * 64 + lane;
      int row = idx >> 2, seg = idx & 3;
      const ushort* srcA = Ab + (size_t)row * 1024 + kc + seg * 8;
      char* dstA = (char*)&As[0][0] + w * 2048 + q * 1024;
      __builtin_amdgcn_global_load_lds(
          (const __attribute__((address_space(1))) unsigned*)srcA,
          (__attribute__((address_space(3))) unsigned*)dstA, 16, 0, 0);
    }
    {
      int idx = tid;                 // 64 rows x 4 segs = 256
      int row = idx >> 2, seg = idx & 3;
      const ushort* srcB = Bb + (size_t)row * 1024 + kc + seg * 8;
      char* dstB = (char*)&Bs[0][0] + w * 1024;
      __builtin_amdgcn_global_load_lds(
          (const __attribute__((address_space(1))) unsigned*)srcB,
          (__attribute__((address_space(3))) unsigned*)dstB, 16, 0, 0);
    }
    __syncthreads();
    bf16x8 af[4], bfv[2];
    #pragma unroll
    for (int mi = 0; mi < 4; ++mi)
      af[mi] = *(const bf16x8*)&As[wr * 64 + mi * 16 + (lane & 15)][(lane >> 4) * 8];
    #pragma unroll
    for (int ni = 0; ni < 2; ++ni)
      bfv[ni] = *(const bf16x8*)&Bs[wc * 32 + ni * 16 + (lane & 15)][(lane >> 4) * 8];
    #pragma unroll
    for (int mi = 0; mi < 4; ++mi)
      #pragma unroll
      for (int ni = 0; ni < 2; ++ni)
        acc[mi][ni] = __builtin_amdgcn_mfma_f32_16x16x32_bf16(
            af[mi], bfv[ni], acc[mi][ni], 0, 0, 0);
  }
  float* Sb = S + ((size_t)bhl << 16);
  #pragma unroll
  for (int mi = 0; mi < 4; ++mi)
    #pragma unroll
    for (int r = 0; r < 4; ++r) {
      int c = c0 + wr * 64 + mi * 16 + (lane >> 4) * 4 + r;
      #pragma unroll
      for (int ni = 0; ni < 2; ++ni) {
        int d = d0 + wc * 32 + ni * 16 + (lane & 15);
        Sb[(size_t)c * 256 + d] = acc[mi][ni][r];
      }
    }
}

// ------- C2: row softmax over 256 -> bf16 P ---------------------------------
__global__ __launch_bounds__(256) void k_softmax_p(
    const float* __restrict__ S, ushort* __restrict__ P)
{
  const int row = blockIdx.x * 4 + (threadIdx.x >> 6);
  const int lane = threadIdx.x & 63;
  const float* r = S + (size_t)row * 256;
  float4 v = *(const float4*)(r + lane * 4);
  float m = fmaxf(fmaxf(v.x, v.y), fmaxf(v.z, v.w));
  #pragma unroll
  for (int off = 32; off; off >>= 1) m = fmaxf(m, __shfl_xor(m, off, 64));
  v.x = __expf(v.x - m); v.y = __expf(v.y - m);
  v.z = __expf(v.z - m); v.w = __expf(v.w - m);
  float s = v.x + v.y + v.z + v.w;
  #pragma unroll
  for (int off = 32; off; off >>= 1) s += __shfl_xor(s, off, 64);
  const float inv = 1.f / s;
  union { ushort u[4]; uint2 q; } o;
  o.u[0] = f2bf(v.x * inv); o.u[1] = f2bf(v.y * inv);
  o.u[2] = f2bf(v.z * inv); o.u[3] = f2bf(v.w * inv);
  *(uint2*)(P + (size_t)row * 256 + lane * 4) = o.q;
}

// -- C3: oc = P @ vcT (MFMA) + grouped ConvT + residual -> fused_pad NHWC ----
__global__ __launch_bounds__(256) void k_cha_pv(
    const ushort* __restrict__ P, const ushort* __restrict__ Vt,
    const float* __restrict__ x,
    const float* __restrict__ Wt, const float* __restrict__ bt,
    const float* __restrict__ gamma, ushort* __restrict__ fused, int bbase)
{
  const int n0 = blockIdx.x * 128, c0 = blockIdx.y * 128, bhl = blockIdx.z;
  const int b = bbase + (bhl >> 3), h = bhl & 7;
  const int tid = threadIdx.x, lane = tid & 63, w = tid >> 6;
  __shared__ ushort As[128][32], Bs[128][32];
  __shared__ ushort Ot[512][16];
  __shared__ float wt_s[16][32];
  __shared__ float bt_s[16];
  const int gp_base = h * 32 + (c0 >> 3);
  {
    int e = tid;
    wt_s[e >> 5][e & 31] = Wt[(size_t)gp_base * 32 + e];
    e += 256;
    wt_s[e >> 5][e & 31] = Wt[(size_t)gp_base * 32 + e];
    if (tid < 16) bt_s[tid] = bt[gp_base + tid];
  }
  const ushort* Ab = P + (((size_t)bhl << 8) + c0) * 256;
  const ushort* Bb = Vt + ((size_t)bhl << 18) + (size_t)n0 * 256;
  const int wr = w >> 1, wc = w & 1;
  f32x4 acc[4][4];
  #pragma unroll
  for (int mi = 0; mi < 4; ++mi)
    #pragma unroll
    for (int ni = 0; ni < 4; ++ni) {
      f32x4 z = {0.f, 0.f, 0.f, 0.f};
      acc[mi][ni] = z;
    }
  for (int kc = 0; kc < 256; kc += 32) {
    __syncthreads();
    #pragma unroll
    for (int q = 0; q < 2; ++q) {
      int idx = w * 128 + q * 64 + lane;
      int row = idx >> 2, seg = idx & 3;
      const ushort* srcA = Ab + (size_t)row * 256 + kc + seg * 8;
      const ushort* srcB = Bb + (size_t)row * 256 + kc + seg * 8;
      char* dstA = (char*)&As[0][0] + w * 2048 + q * 1024;
      char* dstB = (char*)&Bs[0][0] + w * 2048 + q * 1024;
      __builtin_amdgcn_global_load_lds(
          (const __attribute__((address_space(1))) unsigned*)srcA,
          (__attribute__((address_space(3))) unsigned*)dstA, 16, 0, 0);
      __builtin_amdgcn_global_load_lds(
          (const __attribute__((address_space(1))) unsigned*)srcB,
          (__attribute__((address_space(3))) unsigned*)dstB, 16, 0, 0);
    }
    __syncthreads();
    bf16x8 af[4], bfv[4];
    #pragma unroll
    for (int mi = 0; mi < 4; ++mi)
      af[mi] = *(const bf16x8*)&As[wr * 64 + mi * 16 + (lane & 15)][(lane >> 4) * 8];
    #pragma unroll
    for (int ni = 0; ni < 4; ++ni)
      bfv[ni] = *(const bf16x8*)&Bs[wc * 64 + ni * 16 + (lane & 15)][(lane >> 4) * 8];
    #pragma unroll
    for (int mi = 0; mi < 4; ++mi)
      #pragma unroll
      for (int ni = 0; ni < 4; ++ni)
        acc[mi][ni] = __builtin_amdgcn_mfma_f32_16x16x32_bf16(
            af[mi], bfv[ni], acc[mi][ni], 0, 0, 0);
  }
  const float gm = gamma[0];
  const int col = lane & 15, q = lane >> 4;
  #pragma unroll
  for (int mi = 0; mi < 4; ++mi) {
    const int gloc = wr * 8 + mi * 2 + (q >> 1);
    const int gp = gp_base + gloc;
    const float btv = bt_s[gloc];
    #pragma unroll
    for (int ni = 0; ni < 4; ++ni) {
      float pa[4] = {0.f, 0.f, 0.f, 0.f};
      #pragma unroll
      for (int r = 0; r < 4; ++r) {
        const int i2 = (q & 1) * 4 + r;
        const float a = acc[mi][ni][r];
        pa[0] += a * wt_s[gloc][i2 * 4 + 0];
        pa[1] += a * wt_s[gloc][i2 * 4 + 1];
        pa[2] += a * wt_s[gloc][i2 * 4 + 2];
        pa[3] += a * wt_s[gloc][i2 * 4 + 3];
      }
      float v0 = pa[0] + __shfl_xor(pa[0], 16, 64);
      float v1 = pa[1] + __shfl_xor(pa[1], 16, 64);
      float v2 = pa[2] + __shfl_xor(pa[2], 16, 64);
      float v3 = pa[3] + __shfl_xor(pa[3], 16, 64);
      const int lloc = wc * 64 + ni * 16 + col;
      const int l = n0 + lloc;
      const int p = l >> 5, j = l & 31;
      const int y = 2 * p + (q & 1);
      const float va = (q & 1) ? v2 : v0;
      const float vb = (q & 1) ? v3 : v1;
      const float* xc = x + (((size_t)b * 256 + gp) << 12) + (y << 6) + 2 * j;
      const int lp = (lloc << 2) + (q & 1) * 2;
      Ot[lp][gloc]     = f2bf(xc[0] + gm * (va + btv));
      Ot[lp + 1][gloc] = f2bf(xc[1] + gm * (vb + btv));
    }
  }
  __syncthreads();
  #pragma unroll
  for (int pp2 = 0; pp2 < 2; ++pp2) {
    const int pixl = tid * 2 + pp2;
    const int lloc = pixl >> 2;
    const int l = n0 + lloc;
    const int p = l >> 5, j = l & 31;
    const int yy = 2 * p + ((pixl >> 1) & 1) + 1;
    const int xx = 2 * j + (pixl & 1) + 1;
    const uint4* src = (const uint4*)&Ot[pixl][0];
    uint4* dst = (uint4*)(fused + ((size_t)b * 4356 + yy * 66 + xx) * 512 + 256 + gp_base);
    dst[0] = src[0];
    dst[1] = src[1];
  }
}

extern "C" void kernel_launch(void* const* d_in, const int* in_sizes, int n_in,
                              void* d_out, int out_size, void* d_ws, size_t ws_size,
                              hipStream_t stream)
{
  (void)in_sizes; (void)n_in; (void)out_size; (void)ws_size;
  const float* qkv_pos   = (const float*)d_in[0];
  const float* qkv_cha   = (const float*)d_in[1];
  const float* Wq_pos    = (const float*)d_in[2];
  const float* bq_pos    = (const float*)d_in[3];
  const float* Wk_pos    = (const float*)d_in[4];
  const float* bk_pos    = (const float*)d_in[5];
  const float* Wv_pos    = (const float*)d_in[6];
  const float* bv_pos    = (const float*)d_in[7];
  const float* Wo_pos    = (const float*)d_in[8];
  const float* bo_pos    = (const float*)d_in[9];
  const float* gamma_pos = (const float*)d_in[10];
  const float* Wq_cha    = (const float*)d_in[11];
  const float* bq_cha    = (const float*)d_in[12];
  const float* Wk_cha    = (const float*)d_in[13];
  const float* bk_cha    = (const float*)d_in[14];
  const float* Wv_cha    = (const float*)d_in[15];
  const float* bv_cha    = (const float*)d_in[16];
  const float* Wt_cha    = (const float*)d_in[17];
  const float* bt_cha    = (const float*)d_in[18];
  const float* gamma_cha = (const float*)d_in[19];
  const float* Wf        = (const float*)d_in[20];
  const float* bf        = (const float*)d_in[21];
  float* out = (float*)d_out;

  float* ws = (float*)d_ws;
  ushort* Wpf9    = (ushort*)ws;
  ushort* Wpo9    = (ushort*)(ws + 589824);
  // POS scratch
  ushort* Qb      = (ushort*)(ws + 884736);    // [64][1024][32] bf16
  ushort* Kb      = (ushort*)(ws + 1933312);   // [64][1024][32] bf16
  ushort* Vtb     = (ushort*)(ws + 2981888);   // [64][32][1024] bf16
  ushort* op_pad  = (ushort*)(ws + 4030464);   // 2367488 ushorts
  float*  op_conv = ws + 5214208;              // NHWC fp32 [8][1024][256]
  ushort* Ap      = (ushort*)(ws + 7311360);   // [8][1024][1024] bf16
  // CHA scratch (aliases POS region after it is consumed)
  ushort* qcb     = (ushort*)(ws + 884736);
  ushort* kcb     = (ushort*)(ws + 5079040);
  ushort* vcT     = (ushort*)(ws + 9273344);
  float*  attn_c  = ws + 13467648;
  ushort* Pb      = (ushort*)(ws + 15564800);
  ushort* fusedb  = (ushort*)(ws + 16613376);  // NHWC padded [8][66*66][512]
  ushort* Wqkvp   = (ushort*)(ws + 25534464);  // [384][1024] bf16

  // merged init: zero rings/Qb + all weight pre-packs (one launch)
  k_init_all<<<dim3(10124), 256, 0, stream>>>(fusedb, op_pad, Qb,
      Wf, Wo_pos, Wq_pos, Wk_pos, Wv_pos, Wpf9, Wpo9, Wqkvp);
  // POS branch
  k_pack_pos<<<dim3(32, 8), 256, 0, stream>>>(qkv_pos, Ap);
  k_pos_qkv_mfma<<<dim3(8, 3, 8), 256, 0, stream>>>(Ap, Wqkvp,
      bq_pos, bk_pos, bv_pos, Qb, Kb, Vtb);
  k_pos_flash<<<dim3(8, 8, 8), 256, 0, stream>>>(Qb, Kb, Vtb, op_pad);
  // Wo conv: BN=64 -> 256 blocks (full GPU)
  k_conv9_mfma<256, 32, 34, 1, 64><<<dim3(16, 2, 8), 256, 0, stream>>>(
      op_pad, Wpo9, bo_pos, op_conv);
  k_upsample_nhwc<<<dim3(64, 2, 8), 256, 0, stream>>>(qkv_pos, op_conv,
      gamma_pos, fusedb);
  // CHA branch, two half-batches
  for (int half = 0; half < 2; ++half) {
    const float* xh = qkv_cha + (size_t)half * 4 * 256 * 4096;
    k_cha_proj<<<dim3(1024), 256, 0, stream>>>(xh, Wq_cha, bq_cha,
        Wk_cha, bk_cha, Wv_cha, bv_cha, qcb, kcb, vcT);
    k_cha_scores_mfma<<<dim3(2, 4, 32), 256, 0, stream>>>(qcb, kcb, attn_c);
    k_softmax_p<<<dim3(2048), 256, 0, stream>>>(attn_c, Pb);
    k_cha_pv<<<dim3(8, 2, 32), 256, 0, stream>>>(Pb, vcT, qkv_cha,
        Wt_cha, bt_cha, gamma_cha, fusedb, half * 4);
  }
  // fusion conv: pipelined 128x256 tile (r3 form), 256 blocks = 1/CU
  k_conv9_pipe<<<dim3(16, 2, 8), 512, 0, stream>>>(fusedb, Wpf9, bf, out);
}